// Round 5
// baseline (1866.715 us; speedup 1.0000x reference)
//
#include <hip/hip_runtime.h>
#include <hip/hip_bf16.h>
#include <cmath>

#define HC 64
typedef __hip_bfloat16 bf16;
typedef unsigned int uint;

__device__ __forceinline__ uint pack_bf2(float a, float b) {
    __hip_bfloat162 h = __float22bfloat162_rn(make_float2(a, b));
    return *reinterpret_cast<uint*>(&h);
}

// ---------------- bucket histogram (dst>>7), LDS-aggregated ----------------

__global__ __launch_bounds__(512) void bucket_hist_k(const int* __restrict__ dst,
                                                     int* __restrict__ bcnt, int E, int nbk) {
    __shared__ int lh[512];
    int t = threadIdx.x;
    for (int i = t; i < nbk; i += 512) lh[i] = 0;
    __syncthreads();
    int base = blockIdx.x * 8192;
#pragma unroll
    for (int k = 0; k < 16; ++k) {
        int e = base + k * 512 + t;
        if (e < E) atomicAdd(&lh[dst[e] >> 7], 1);
    }
    __syncthreads();
    for (int i = t; i < nbk; i += 512) if (lh[i]) atomicAdd(&bcnt[i], lh[i]);
}

// ---------------- scan over nbk (<=512) buckets, writes bstart + bcur ----------------

__global__ __launch_bounds__(512) void bucket_scan_k(const int* __restrict__ bcnt,
                                                     int* __restrict__ bstart,
                                                     int* __restrict__ bcur, int nbk, int E) {
    __shared__ int tmp[512];
    int t = threadIdx.x;
    int v = (t < nbk) ? bcnt[t] : 0;
    tmp[t] = v;
    __syncthreads();
    for (int off = 1; off < 512; off <<= 1) {
        int a = (t >= off) ? tmp[t - off] : 0;
        __syncthreads();
        tmp[t] += a;
        __syncthreads();
    }
    if (t < nbk) { int ex = tmp[t] - v; bstart[t] = ex; bcur[t] = ex; }
    if (t == 0) bstart[nbk] = E;
}

// ---------------- grouping pass: append packed records into bucket regions ----------------

__global__ __launch_bounds__(1024) void bucketA_k(
        const int* __restrict__ src, const int* __restrict__ dst,
        const float4* __restrict__ eattr, int* __restrict__ bcur,
        uint* __restrict__ epk, uint2* __restrict__ eat, int E, int nbk) {
    __shared__ int lcnt[512];
    __shared__ int lbase[512];
    int t = threadIdx.x;
    for (int i = t; i < nbk; i += 1024) lcnt[i] = 0;
    __syncthreads();
    int base = blockIdx.x * 8192;
    int myb[8], mylp[8];
#pragma unroll
    for (int k = 0; k < 8; ++k) {
        int e = base + k * 1024 + t;
        if (e < E) {
            int b = dst[e] >> 7;
            myb[k] = b;
            mylp[k] = atomicAdd(&lcnt[b], 1);
        } else myb[k] = -1;
    }
    __syncthreads();
    for (int i = t; i < nbk; i += 1024) {
        int cc = lcnt[i];
        lbase[i] = cc ? atomicAdd(&bcur[i], cc) : 0;
    }
    __syncthreads();
#pragma unroll
    for (int k = 0; k < 8; ++k) {
        int e = base + k * 1024 + t;
        if (e >= E) continue;
        int b = myb[k];
        int pos = lbase[b] + mylp[k];
        int d = dst[e];
        epk[pos] = (uint)src[e] | ((uint)(d & 127) << 25);
        float4 ea = eattr[e];
        eat[pos] = make_uint2(pack_bf2(ea.x, ea.y), pack_bf2(ea.z, ea.w));
    }
}

// ---------------- layer-0 linear: din=128, 16 nodes/block (4/thread) ----------------

__global__ __launch_bounds__(256) void lin128_k(
        const float* __restrict__ x, int n,
        const float* __restrict__ Wl, const float* __restrict__ bl,
        const float* __restrict__ Wr, const float* __restrict__ br,
        bf16* __restrict__ xl, bf16* __restrict__ xr, int ngroups16) {
    __shared__ float2 sWl2[64 * 64];
    __shared__ float2 sWr2[64 * 64];
    __shared__ float sx[16 * 128];
    int t = threadIdx.x;
    for (int i = t; i < 64 * 64; i += 256) {
        int k2 = i >> 6, c = i & 63;
        sWl2[i] = make_float2(Wl[(2 * k2) * 64 + c], Wl[(2 * k2 + 1) * 64 + c]);
        sWr2[i] = make_float2(Wr[(2 * k2) * 64 + c], Wr[(2 * k2 + 1) * 64 + c]);
    }
    int c = t & 63, w = t >> 6;
    float blc = bl[c], brc = br[c];
    for (int gidx = blockIdx.x; gidx < ngroups16; gidx += gridDim.x) {
        int node0 = gidx * 16;
        __syncthreads();
        for (int i = t; i < 16 * 128; i += 256) {
            int r = node0 + (i >> 7);
            sx[i] = (r < n) ? x[(size_t)r * 128 + (i & 127)] : 0.f;
        }
        __syncthreads();
        float al0 = blc, al1 = blc, al2 = blc, al3 = blc;
        float ar0 = brc, ar1 = brc, ar2 = brc, ar3 = brc;
        const float* sx0 = sx + w * 4 * 128;
#pragma unroll 8
        for (int k2 = 0; k2 < 64; ++k2) {
            float2 wl = sWl2[k2 * 64 + c], wr = sWr2[k2 * 64 + c];
            float2 xa = *(const float2*)&sx0[k2 * 2];
            float2 xb = *(const float2*)&sx0[128 + k2 * 2];
            float2 xc = *(const float2*)&sx0[256 + k2 * 2];
            float2 xd = *(const float2*)&sx0[384 + k2 * 2];
            al0 = fmaf(xa.x, wl.x, al0); al0 = fmaf(xa.y, wl.y, al0);
            ar0 = fmaf(xa.x, wr.x, ar0); ar0 = fmaf(xa.y, wr.y, ar0);
            al1 = fmaf(xb.x, wl.x, al1); al1 = fmaf(xb.y, wl.y, al1);
            ar1 = fmaf(xb.x, wr.x, ar1); ar1 = fmaf(xb.y, wr.y, ar1);
            al2 = fmaf(xc.x, wl.x, al2); al2 = fmaf(xc.y, wl.y, al2);
            ar2 = fmaf(xc.x, wr.x, ar2); ar2 = fmaf(xc.y, wr.y, ar2);
            al3 = fmaf(xd.x, wl.x, al3); al3 = fmaf(xd.y, wl.y, al3);
            ar3 = fmaf(xd.x, wr.x, ar3); ar3 = fmaf(xd.y, wr.y, ar3);
        }
        int nb_ = node0 + w * 4;
        if (nb_ + 0 < n) { xl[(size_t)(nb_ + 0) * 64 + c] = __float2bfloat16(al0); xr[(size_t)(nb_ + 0) * 64 + c] = __float2bfloat16(ar0); }
        if (nb_ + 1 < n) { xl[(size_t)(nb_ + 1) * 64 + c] = __float2bfloat16(al1); xr[(size_t)(nb_ + 1) * 64 + c] = __float2bfloat16(ar1); }
        if (nb_ + 2 < n) { xl[(size_t)(nb_ + 2) * 64 + c] = __float2bfloat16(al2); xr[(size_t)(nb_ + 2) * 64 + c] = __float2bfloat16(ar2); }
        if (nb_ + 3 < n) { xl[(size_t)(nb_ + 3) * 64 + c] = __float2bfloat16(al3); xr[(size_t)(nb_ + 3) * 64 + c] = __float2bfloat16(ar3); }
    }
}

// ---------------- layer-1 linear: din=64, fused input BN+ELU ----------------

__global__ __launch_bounds__(256) void lin64bn_k(
        const float* __restrict__ x, int n,
        const float* __restrict__ sums, const float* __restrict__ sqs,
        const float* __restrict__ g, const float* __restrict__ be,
        const float* __restrict__ Wl, const float* __restrict__ bl,
        const float* __restrict__ Wr, const float* __restrict__ br,
        bf16* __restrict__ xl, bf16* __restrict__ xr, int ngroups16) {
    __shared__ float2 sWl2[32 * 64];
    __shared__ float2 sWr2[32 * 64];
    __shared__ float sx[16 * 64];
    __shared__ float ssc[64], ssh[64];
    int t = threadIdx.x;
    if (t < 64) {
        float inv_n = 1.f / n;
        float mu = sums[t] * inv_n;
        float var = sqs[t] * inv_n - mu * mu;
        float sc = rsqrtf(var + 1e-5f) * g[t];
        ssc[t] = sc; ssh[t] = be[t] - mu * sc;
    }
    for (int i = t; i < 32 * 64; i += 256) {
        int k2 = i >> 6, c = i & 63;
        sWl2[i] = make_float2(Wl[(2 * k2) * 64 + c], Wl[(2 * k2 + 1) * 64 + c]);
        sWr2[i] = make_float2(Wr[(2 * k2) * 64 + c], Wr[(2 * k2 + 1) * 64 + c]);
    }
    int c = t & 63, w = t >> 6;
    float blc = bl[c], brc = br[c];
    for (int gidx = blockIdx.x; gidx < ngroups16; gidx += gridDim.x) {
        int node0 = gidx * 16;
        __syncthreads();
        for (int i = t; i < 16 * 64; i += 256) {
            int r = node0 + (i >> 6);
            float v = (r < n) ? x[(size_t)r * 64 + (i & 63)] : 0.f;
            v = v * ssc[i & 63] + ssh[i & 63];
            sx[i] = v > 0.f ? v : __expf(v) - 1.f;
        }
        __syncthreads();
        float al0 = blc, al1 = blc, al2 = blc, al3 = blc;
        float ar0 = brc, ar1 = brc, ar2 = brc, ar3 = brc;
        const float* sx0 = sx + w * 4 * 64;
#pragma unroll 8
        for (int k2 = 0; k2 < 32; ++k2) {
            float2 wl = sWl2[k2 * 64 + c], wr = sWr2[k2 * 64 + c];
            float2 xa = *(const float2*)&sx0[k2 * 2];
            float2 xb = *(const float2*)&sx0[64 + k2 * 2];
            float2 xc = *(const float2*)&sx0[128 + k2 * 2];
            float2 xd = *(const float2*)&sx0[192 + k2 * 2];
            al0 = fmaf(xa.x, wl.x, al0); al0 = fmaf(xa.y, wl.y, al0);
            ar0 = fmaf(xa.x, wr.x, ar0); ar0 = fmaf(xa.y, wr.y, ar0);
            al1 = fmaf(xb.x, wl.x, al1); al1 = fmaf(xb.y, wl.y, al1);
            ar1 = fmaf(xb.x, wr.x, ar1); ar1 = fmaf(xb.y, wr.y, ar1);
            al2 = fmaf(xc.x, wl.x, al2); al2 = fmaf(xc.y, wl.y, al2);
            ar2 = fmaf(xc.x, wr.x, ar2); ar2 = fmaf(xc.y, wr.y, ar2);
            al3 = fmaf(xd.x, wl.x, al3); al3 = fmaf(xd.y, wl.y, al3);
            ar3 = fmaf(xd.x, wr.x, ar3); ar3 = fmaf(xd.y, wr.y, ar3);
        }
        int nb_ = node0 + w * 4;
        if (nb_ + 0 < n) { xl[(size_t)(nb_ + 0) * 64 + c] = __float2bfloat16(al0); xr[(size_t)(nb_ + 0) * 64 + c] = __float2bfloat16(ar0); }
        if (nb_ + 1 < n) { xl[(size_t)(nb_ + 1) * 64 + c] = __float2bfloat16(al1); xr[(size_t)(nb_ + 1) * 64 + c] = __float2bfloat16(ar1); }
        if (nb_ + 2 < n) { xl[(size_t)(nb_ + 2) * 64 + c] = __float2bfloat16(al2); xr[(size_t)(nb_ + 2) * 64 + c] = __float2bfloat16(ar2); }
        if (nb_ + 3 < n) { xl[(size_t)(nb_ + 3) * 64 + c] = __float2bfloat16(al3); xr[(size_t)(nb_ + 3) * 64 + c] = __float2bfloat16(ar3); }
    }
}

// ---------------- fused GAT: block per 128-node bucket, LDS accumulation ----------------

__global__ __launch_bounds__(512) void gat_bucket_k(
        const bf16* __restrict__ xl, const bf16* __restrict__ xr,
        const float* __restrict__ We, const float* __restrict__ att,
        const int* __restrict__ bstart, const uint* __restrict__ epk,
        const uint2* __restrict__ eat,
        float* __restrict__ out, float* __restrict__ sums, float* __restrict__ sqs, int n) {
    __shared__ float acc[128 * 64];   // 32 KB
    __shared__ float srun[128 * 4];   // 2 KB
    __shared__ bf16  xrt[128 * 64];   // 16 KB
    int t = threadIdx.x;
    int b = blockIdx.x;
    int node0 = b << 7;
    for (int i = t; i < 128 * 64; i += 512) acc[i] = 0.f;
    for (int i = t; i < 128 * 4; i += 512) srun[i] = 0.f;
    {
        size_t base = (size_t)node0 << 6;
        int lim = n * 64 - (int)base;
        if (lim > 8192) lim = 8192;
        for (int i = t; i < 8192; i += 512)
            xrt[i] = (i < lim) ? xr[base + i] : __float2bfloat16(0.f);
    }
    int w = t >> 6, c = t & 63;
    float w0 = We[c], w1 = We[64 + c], w2 = We[128 + c], w3 = We[192 + c];
    float ratt = att[c] * 1.44269504f;   // exp(a)=exp2(a*log2e)
    __syncthreads();

    int i0 = bstart[b], i1 = bstart[b + 1];

#define GPROC(U, EA, XV) { \
        int dl = (int)((U) >> 25); \
        float xrv = __bfloat162float(xrt[(dl << 6) + c]); \
        float2 e01 = __bfloat1622float2(*reinterpret_cast<const __hip_bfloat162*>(&(EA).x)); \
        float2 e23 = __bfloat1622float2(*reinterpret_cast<const __hip_bfloat162*>(&(EA).y)); \
        float m = (XV) + xrv; \
        m = fmaf(e01.x, w0, m); m = fmaf(e01.y, w1, m); \
        m = fmaf(e23.x, w2, m); m = fmaf(e23.y, w3, m); \
        m = fmaxf(m, 0.2f * m); \
        float v = m * ratt; \
        v += __shfl_xor(v, 1); v += __shfl_xor(v, 2); \
        v += __shfl_xor(v, 4); v += __shfl_xor(v, 8); \
        float p = exp2f(v); \
        atomicAdd(&acc[(dl << 6) + c], p * (XV)); \
        if ((c & 15) == 0) atomicAdd(&srun[(dl << 2) + (c >> 4)], p); \
    }

    int i = i0 + w;
    for (; i + 8 < i1; i += 16) {
        uint u0 = epk[i];     uint2 e0 = eat[i];
        uint u1 = epk[i + 8]; uint2 e1 = eat[i + 8];
        float xv0 = __bfloat162float(xl[((size_t)(u0 & 0x1FFFFFFu) << 6) + c]);
        float xv1 = __bfloat162float(xl[((size_t)(u1 & 0x1FFFFFFu) << 6) + c]);
        GPROC(u0, e0, xv0);
        GPROC(u1, e1, xv1);
    }
    for (; i < i1; i += 8) {
        uint u0 = epk[i]; uint2 e0 = eat[i];
        float xv0 = __bfloat162float(xl[((size_t)(u0 & 0x1FFFFFFu) << 6) + c]);
        GPROC(u0, e0, xv0);
    }
#undef GPROC

    __syncthreads();
    float s = 0.f, q = 0.f;
    for (int idx = t; idx < 128 * 64; idx += 512) {
        int row = idx >> 6;
        int node = node0 + row;
        float o = acc[idx] / (srun[(row << 2) + ((idx & 63) >> 4)] + 1e-16f);
        if (node < n) {
            out[(size_t)node * 64 + (idx & 63)] = o;
            s += o;
            q = fmaf(o, o, q);
        }
    }
    __syncthreads();
    acc[t] = s; acc[512 + t] = q;
    __syncthreads();
    if (t < 64) {
        float ss = 0.f, qq = 0.f;
#pragma unroll
        for (int k = 0; k < 8; ++k) { ss += acc[t + 64 * k]; qq += acc[512 + t + 64 * k]; }
        atomicAdd(&sums[t], ss);
        atomicAdd(&sqs[t], qq);
    }
}

// ---------------- head fc 64->64 (fused input BN+ELU, fused output stats) ----------------

__global__ __launch_bounds__(256) void lin1_k(
        const float* __restrict__ x, int n,
        const float* __restrict__ sums, const float* __restrict__ sqs,
        const float* __restrict__ g, const float* __restrict__ be,
        const float* __restrict__ W, const float* __restrict__ b,
        float* __restrict__ y, float* __restrict__ sums_o, float* __restrict__ sqs_o,
        int ngroups16) {
    __shared__ float2 sW2[32 * 64];
    __shared__ float sx[16 * 64];
    __shared__ float ssc[64], ssh[64];
    __shared__ float ls[256], lq[256];
    int t = threadIdx.x;
    if (t < 64) {
        float inv_n = 1.f / n;
        float mu = sums[t] * inv_n;
        float var = sqs[t] * inv_n - mu * mu;
        float sc = rsqrtf(var + 1e-5f) * g[t];
        ssc[t] = sc; ssh[t] = be[t] - mu * sc;
    }
    for (int i = t; i < 32 * 64; i += 256) {
        int k2 = i >> 6, c = i & 63;
        sW2[i] = make_float2(W[(2 * k2) * 64 + c], W[(2 * k2 + 1) * 64 + c]);
    }
    int c = t & 63, w = t >> 6;
    float bc = b[c];
    float s = 0.f, q = 0.f;
    for (int gidx = blockIdx.x; gidx < ngroups16; gidx += gridDim.x) {
        int node0 = gidx * 16;
        __syncthreads();
        for (int i = t; i < 16 * 64; i += 256) {
            int r = node0 + (i >> 6);
            float v = (r < n) ? x[(size_t)r * 64 + (i & 63)] : 0.f;
            v = v * ssc[i & 63] + ssh[i & 63];
            sx[i] = v > 0.f ? v : __expf(v) - 1.f;
        }
        __syncthreads();
        float a0 = bc, a1 = bc, a2 = bc, a3 = bc;
        const float* sx0 = sx + w * 4 * 64;
#pragma unroll 8
        for (int k2 = 0; k2 < 32; ++k2) {
            float2 wv = sW2[k2 * 64 + c];
            float2 xa = *(const float2*)&sx0[k2 * 2];
            float2 xb = *(const float2*)&sx0[64 + k2 * 2];
            float2 xc = *(const float2*)&sx0[128 + k2 * 2];
            float2 xd = *(const float2*)&sx0[192 + k2 * 2];
            a0 = fmaf(xa.x, wv.x, a0); a0 = fmaf(xa.y, wv.y, a0);
            a1 = fmaf(xb.x, wv.x, a1); a1 = fmaf(xb.y, wv.y, a1);
            a2 = fmaf(xc.x, wv.x, a2); a2 = fmaf(xc.y, wv.y, a2);
            a3 = fmaf(xd.x, wv.x, a3); a3 = fmaf(xd.y, wv.y, a3);
        }
        int nb_ = node0 + w * 4;
        if (nb_ + 0 < n) { y[(size_t)(nb_ + 0) * 64 + c] = a0; s += a0; q = fmaf(a0, a0, q); }
        if (nb_ + 1 < n) { y[(size_t)(nb_ + 1) * 64 + c] = a1; s += a1; q = fmaf(a1, a1, q); }
        if (nb_ + 2 < n) { y[(size_t)(nb_ + 2) * 64 + c] = a2; s += a2; q = fmaf(a2, a2, q); }
        if (nb_ + 3 < n) { y[(size_t)(nb_ + 3) * 64 + c] = a3; s += a3; q = fmaf(a3, a3, q); }
    }
    __syncthreads();
    ls[t] = s; lq[t] = q;
    __syncthreads();
    if (t < 64) {
        float ss = ls[t] + ls[t + 64] + ls[t + 128] + ls[t + 192];
        float qq = lq[t] + lq[t + 64] + lq[t + 128] + lq[t + 192];
        atomicAdd(&sums_o[t], ss);
        atomicAdd(&sqs_o[t], qq);
    }
}

// ---------------- final: fused BN+ELU + dot(64) + 5*tanh ----------------

__global__ void final_k(const float* __restrict__ z, int n,
                        const float* __restrict__ sums, const float* __restrict__ sqs,
                        const float* __restrict__ g, const float* __restrict__ be,
                        const float* __restrict__ W2, const float* __restrict__ b2,
                        float* __restrict__ out) {
    int t = blockIdx.x * blockDim.x + threadIdx.x;
    int node = t >> 6, c = t & 63;
    if (node >= n) return;
    float inv_n = 1.f / n;
    float mu = sums[c] * inv_n;
    float var = sqs[c] * inv_n - mu * mu;
    float scc = rsqrtf(var + 1e-5f) * g[c];
    float sh = be[c] - mu * scc;
    float v = z[(size_t)node * 64 + c] * scc + sh;
    v = v > 0.f ? v : __expf(v) - 1.f;
    v *= W2[c];
    v += __shfl_xor(v, 1);
    v += __shfl_xor(v, 2);
    v += __shfl_xor(v, 4);
    v += __shfl_xor(v, 8);
    v += __shfl_xor(v, 16);
    v += __shfl_xor(v, 32);
    if (c == 0) out[node] = 5.0f * tanhf(v + b2[0]);
}

// ---------------- launch ----------------

extern "C" void kernel_launch(void* const* d_in, const int* in_sizes, int n_in,
                              void* d_out, int out_size, void* d_ws, size_t ws_size,
                              hipStream_t stream) {
    const float* x0    = (const float*)d_in[0];
    const int*   eidx  = (const int*)d_in[1];
    const float* eattr = (const float*)d_in[2];

    const float* Wl[2]; const float* bl[2]; const float* Wr[2]; const float* br[2];
    const float* We[2]; const float* att[2]; const float* g[2]; const float* be[2];
    for (int l = 0; l < 2; ++l) {
        int base = 3 + l * 9;
        Wl[l]  = (const float*)d_in[base + 0];
        bl[l]  = (const float*)d_in[base + 1];
        Wr[l]  = (const float*)d_in[base + 2];
        br[l]  = (const float*)d_in[base + 3];
        We[l]  = (const float*)d_in[base + 4];
        att[l] = (const float*)d_in[base + 5];
        // base+6 = bias: per-channel constant, cancels exactly under BatchNorm
        g[l]   = (const float*)d_in[base + 7];
        be[l]  = (const float*)d_in[base + 8];
    }
    const float* W1 = (const float*)d_in[21];
    const float* b1 = (const float*)d_in[22];
    const float* gf = (const float*)d_in[23];
    const float* bf = (const float*)d_in[24];
    const float* W2 = (const float*)d_in[25];
    const float* b2 = (const float*)d_in[26];

    const int N = in_sizes[0] / 128;
    const int E = in_sizes[1] / 2;
    const int* src = eidx;
    const int* dst = eidx + E;
    const int nbk = (N + 127) >> 7;            // 128-node buckets

    // workspace (4-byte units)
    float* ws = (float*)d_ws;
    size_t o = 0;
    uint2* eat = (uint2*)(ws + o); o += (size_t)E * 2;
    uint*  epk = (uint*)(ws + o);  o += (size_t)E;
    bf16*  xl  = (bf16*)(ws + o);  o += (size_t)N * 32;   // N*64 bf16
    bf16*  xr  = (bf16*)(ws + o);  o += (size_t)N * 32;
    float* h0  = ws + o; o += (size_t)N * HC;
    float* h1  = ws + o; o += (size_t)N * HC;
    int*   bcnt   = (int*)(ws + o); o += 512;
    int*   bstart = (int*)(ws + o); o += 513;
    int*   bcur   = (int*)(ws + o); o += 512;
    float* stats  = ws + o; o += 6 * HC;
    float* s0 = stats,        *q0 = stats + 64;
    float* s1 = stats + 128,  *q1 = stats + 192;
    float* sf = stats + 256,  *qf = stats + 320;
    float* y = h0;  // h0 dead after lin64bn

    const int ngroups16 = (N + 15) / 16;
    const int EB = (E + 8191) / 8192;

    hipMemsetAsync(bcnt, 0, 512 * 4, stream);
    hipMemsetAsync(stats, 0, 6 * HC * 4, stream);

    // grouping (once, shared by both layers)
    bucket_hist_k<<<EB, 512, 0, stream>>>(dst, bcnt, E, nbk);
    bucket_scan_k<<<1, 512, 0, stream>>>(bcnt, bstart, bcur, nbk, E);
    bucketA_k<<<EB, 1024, 0, stream>>>(src, dst, (const float4*)eattr, bcur, epk, eat, E, nbk);

    // layer 0
    lin128_k<<<512, 256, 0, stream>>>(x0, N, Wl[0], bl[0], Wr[0], br[0], xl, xr, ngroups16);
    gat_bucket_k<<<nbk, 512, 0, stream>>>(xl, xr, We[0], att[0], bstart, epk, eat,
                                          h0, s0, q0, N);
    // layer 1 (input BN+ELU fused)
    lin64bn_k<<<512, 256, 0, stream>>>(h0, N, s0, q0, g[0], be[0],
                                       Wl[1], bl[1], Wr[1], br[1], xl, xr, ngroups16);
    gat_bucket_k<<<nbk, 512, 0, stream>>>(xl, xr, We[1], att[1], bstart, epk, eat,
                                          h1, s1, q1, N);
    // head
    lin1_k<<<512, 256, 0, stream>>>(h1, N, s1, q1, g[1], be[1], W1, b1, y, sf, qf, ngroups16);
    final_k<<<(int)(((size_t)N * 64 + 255) / 256), 256, 0, stream>>>(
        y, N, sf, qf, gf, bf, W2, b2, (float*)d_out);
}

// Round 6
// 424.762 us; speedup vs baseline: 4.3947x; 4.3947x over previous
//
#include <hip/hip_runtime.h>
#include <hip/hip_bf16.h>
#include <cmath>

#define HC 64
typedef __hip_bfloat16 bf16;
typedef unsigned int uint;

__device__ __forceinline__ uint pack_bf2(float a, float b) {
    __hip_bfloat162 h = __float22bfloat162_rn(make_float2(a, b));
    return *reinterpret_cast<uint*>(&h);
}

// ---------------- coarse bucket histogram (dst>>7), LDS-aggregated ----------------

__global__ __launch_bounds__(512) void bucket_hist_k(const int* __restrict__ dst,
                                                     int* __restrict__ bcnt, int E, int nbk) {
    __shared__ int lh[512];
    int t = threadIdx.x;
    for (int i = t; i < nbk; i += 512) lh[i] = 0;
    __syncthreads();
    int base = blockIdx.x * 8192;
#pragma unroll
    for (int k = 0; k < 16; ++k) {
        int e = base + k * 512 + t;
        if (e < E) atomicAdd(&lh[dst[e] >> 7], 1);
    }
    __syncthreads();
    for (int i = t; i < nbk; i += 512) if (lh[i]) atomicAdd(&bcnt[i], lh[i]);
}

// ---------------- scan over nbk (<=512) buckets ----------------

__global__ __launch_bounds__(512) void bucket_scan_k(const int* __restrict__ bcnt,
                                                     int* __restrict__ bstart,
                                                     int* __restrict__ bcur, int nbk, int E) {
    __shared__ int tmp[512];
    int t = threadIdx.x;
    int v = (t < nbk) ? bcnt[t] : 0;
    tmp[t] = v;
    __syncthreads();
    for (int off = 1; off < 512; off <<= 1) {
        int a = (t >= off) ? tmp[t - off] : 0;
        __syncthreads();
        tmp[t] += a;
        __syncthreads();
    }
    if (t < nbk) { int ex = tmp[t] - v; bstart[t] = ex; bcur[t] = ex; }
    if (t == 0) bstart[nbk] = E;
}

// ---------------- grouping: append 12B records into coarse bucket regions ----------------

__global__ __launch_bounds__(1024) void bucketA_k(
        const int* __restrict__ src, const int* __restrict__ dst,
        const float4* __restrict__ eattr, int* __restrict__ bcur,
        uint* __restrict__ tsd, uint2* __restrict__ tea, int E, int nbk) {
    __shared__ int lcnt[512];
    __shared__ int lbase[512];
    int t = threadIdx.x;
    for (int i = t; i < nbk; i += 1024) lcnt[i] = 0;
    __syncthreads();
    int base = blockIdx.x * 8192;
    int myb[8], mylp[8];
#pragma unroll
    for (int k = 0; k < 8; ++k) {
        int e = base + k * 1024 + t;
        if (e < E) {
            int b = dst[e] >> 7;
            myb[k] = b;
            mylp[k] = atomicAdd(&lcnt[b], 1);
        } else myb[k] = -1;
    }
    __syncthreads();
    for (int i = t; i < nbk; i += 1024) {
        int cc = lcnt[i];
        lbase[i] = cc ? atomicAdd(&bcur[i], cc) : 0;
    }
    __syncthreads();
#pragma unroll
    for (int k = 0; k < 8; ++k) {
        int e = base + k * 1024 + t;
        if (e >= E) continue;
        int pos = lbase[myb[k]] + mylp[k];
        int d = dst[e];
        tsd[pos] = (uint)src[e] | ((uint)(d & 127) << 25);
        float4 ea = eattr[e];
        tea[pos] = make_uint2(pack_bf2(ea.x, ea.y), pack_bf2(ea.z, ea.w));
    }
}

// ---------------- in-LDS counting sort per bucket -> exact CSR ----------------

__global__ __launch_bounds__(256) void bucket_sort_k(
        const uint* __restrict__ tsd, const uint2* __restrict__ tea,
        const int* __restrict__ bstart,
        uint* __restrict__ src_sorted, uint2* __restrict__ eat_sorted,
        int* __restrict__ row_start, int n) {
    __shared__ int cnt[128], pfx[128], cur[128];
    int b = blockIdx.x, t = threadIdx.x;
    int i0 = bstart[b], i1 = bstart[b + 1];
    int node0 = b << 7;
    if (t < 128) cnt[t] = 0;
    __syncthreads();
    for (int i = i0 + t; i < i1; i += 256) atomicAdd(&cnt[tsd[i] >> 25], 1);
    __syncthreads();
    if (t < 128) pfx[t] = cnt[t];
    __syncthreads();
    for (int off = 1; off < 128; off <<= 1) {
        int a = (t < 128 && t >= off) ? pfx[t - off] : 0;
        __syncthreads();
        if (t < 128) pfx[t] += a;
        __syncthreads();
    }
    if (t < 128) {
        int ex = pfx[t] - cnt[t];
        cur[t] = ex;
        if (node0 + t <= n) row_start[node0 + t] = i0 + ex;
    }
    __syncthreads();
    for (int i = i0 + t; i < i1; i += 256) {
        uint u = tsd[i];
        int dl = (int)(u >> 25);
        int pos = i0 + atomicAdd(&cur[dl], 1);
        src_sorted[pos] = u & 0x1FFFFFFu;
        eat_sorted[pos] = tea[i];
    }
}

// ---------------- layer-0 linear: din=128, 16 nodes/block (4/thread) ----------------

__global__ __launch_bounds__(256) void lin128_k(
        const float* __restrict__ x, int n,
        const float* __restrict__ Wl, const float* __restrict__ bl,
        const float* __restrict__ Wr, const float* __restrict__ br,
        bf16* __restrict__ xl, bf16* __restrict__ xr, int ngroups16) {
    __shared__ float2 sWl2[64 * 64];
    __shared__ float2 sWr2[64 * 64];
    __shared__ float sx[16 * 128];
    int t = threadIdx.x;
    for (int i = t; i < 64 * 64; i += 256) {
        int k2 = i >> 6, c = i & 63;
        sWl2[i] = make_float2(Wl[(2 * k2) * 64 + c], Wl[(2 * k2 + 1) * 64 + c]);
        sWr2[i] = make_float2(Wr[(2 * k2) * 64 + c], Wr[(2 * k2 + 1) * 64 + c]);
    }
    int c = t & 63, w = t >> 6;
    float blc = bl[c], brc = br[c];
    for (int gidx = blockIdx.x; gidx < ngroups16; gidx += gridDim.x) {
        int node0 = gidx * 16;
        __syncthreads();
        for (int i = t; i < 16 * 128; i += 256) {
            int r = node0 + (i >> 7);
            sx[i] = (r < n) ? x[(size_t)r * 128 + (i & 127)] : 0.f;
        }
        __syncthreads();
        float al0 = blc, al1 = blc, al2 = blc, al3 = blc;
        float ar0 = brc, ar1 = brc, ar2 = brc, ar3 = brc;
        const float* sx0 = sx + w * 4 * 128;
#pragma unroll 8
        for (int k2 = 0; k2 < 64; ++k2) {
            float2 wl = sWl2[k2 * 64 + c], wr = sWr2[k2 * 64 + c];
            float2 xa = *(const float2*)&sx0[k2 * 2];
            float2 xb = *(const float2*)&sx0[128 + k2 * 2];
            float2 xc = *(const float2*)&sx0[256 + k2 * 2];
            float2 xd = *(const float2*)&sx0[384 + k2 * 2];
            al0 = fmaf(xa.x, wl.x, al0); al0 = fmaf(xa.y, wl.y, al0);
            ar0 = fmaf(xa.x, wr.x, ar0); ar0 = fmaf(xa.y, wr.y, ar0);
            al1 = fmaf(xb.x, wl.x, al1); al1 = fmaf(xb.y, wl.y, al1);
            ar1 = fmaf(xb.x, wr.x, ar1); ar1 = fmaf(xb.y, wr.y, ar1);
            al2 = fmaf(xc.x, wl.x, al2); al2 = fmaf(xc.y, wl.y, al2);
            ar2 = fmaf(xc.x, wr.x, ar2); ar2 = fmaf(xc.y, wr.y, ar2);
            al3 = fmaf(xd.x, wl.x, al3); al3 = fmaf(xd.y, wl.y, al3);
            ar3 = fmaf(xd.x, wr.x, ar3); ar3 = fmaf(xd.y, wr.y, ar3);
        }
        int nb_ = node0 + w * 4;
        if (nb_ + 0 < n) { xl[(size_t)(nb_ + 0) * 64 + c] = __float2bfloat16(al0); xr[(size_t)(nb_ + 0) * 64 + c] = __float2bfloat16(ar0); }
        if (nb_ + 1 < n) { xl[(size_t)(nb_ + 1) * 64 + c] = __float2bfloat16(al1); xr[(size_t)(nb_ + 1) * 64 + c] = __float2bfloat16(ar1); }
        if (nb_ + 2 < n) { xl[(size_t)(nb_ + 2) * 64 + c] = __float2bfloat16(al2); xr[(size_t)(nb_ + 2) * 64 + c] = __float2bfloat16(ar2); }
        if (nb_ + 3 < n) { xl[(size_t)(nb_ + 3) * 64 + c] = __float2bfloat16(al3); xr[(size_t)(nb_ + 3) * 64 + c] = __float2bfloat16(ar3); }
    }
}

// ---------------- layer-1 linear: din=64, fused input BN+ELU ----------------

__global__ __launch_bounds__(256) void lin64bn_k(
        const float* __restrict__ x, int n,
        const float* __restrict__ sums, const float* __restrict__ sqs,
        const float* __restrict__ g, const float* __restrict__ be,
        const float* __restrict__ Wl, const float* __restrict__ bl,
        const float* __restrict__ Wr, const float* __restrict__ br,
        bf16* __restrict__ xl, bf16* __restrict__ xr, int ngroups16) {
    __shared__ float2 sWl2[32 * 64];
    __shared__ float2 sWr2[32 * 64];
    __shared__ float sx[16 * 64];
    __shared__ float ssc[64], ssh[64];
    int t = threadIdx.x;
    if (t < 64) {
        float inv_n = 1.f / n;
        float mu = sums[t] * inv_n;
        float var = sqs[t] * inv_n - mu * mu;
        float sc = rsqrtf(var + 1e-5f) * g[t];
        ssc[t] = sc; ssh[t] = be[t] - mu * sc;
    }
    for (int i = t; i < 32 * 64; i += 256) {
        int k2 = i >> 6, c = i & 63;
        sWl2[i] = make_float2(Wl[(2 * k2) * 64 + c], Wl[(2 * k2 + 1) * 64 + c]);
        sWr2[i] = make_float2(Wr[(2 * k2) * 64 + c], Wr[(2 * k2 + 1) * 64 + c]);
    }
    int c = t & 63, w = t >> 6;
    float blc = bl[c], brc = br[c];
    for (int gidx = blockIdx.x; gidx < ngroups16; gidx += gridDim.x) {
        int node0 = gidx * 16;
        __syncthreads();
        for (int i = t; i < 16 * 64; i += 256) {
            int r = node0 + (i >> 6);
            float v = (r < n) ? x[(size_t)r * 64 + (i & 63)] : 0.f;
            v = v * ssc[i & 63] + ssh[i & 63];
            sx[i] = v > 0.f ? v : __expf(v) - 1.f;
        }
        __syncthreads();
        float al0 = blc, al1 = blc, al2 = blc, al3 = blc;
        float ar0 = brc, ar1 = brc, ar2 = brc, ar3 = brc;
        const float* sx0 = sx + w * 4 * 64;
#pragma unroll 8
        for (int k2 = 0; k2 < 32; ++k2) {
            float2 wl = sWl2[k2 * 64 + c], wr = sWr2[k2 * 64 + c];
            float2 xa = *(const float2*)&sx0[k2 * 2];
            float2 xb = *(const float2*)&sx0[64 + k2 * 2];
            float2 xc = *(const float2*)&sx0[128 + k2 * 2];
            float2 xd = *(const float2*)&sx0[192 + k2 * 2];
            al0 = fmaf(xa.x, wl.x, al0); al0 = fmaf(xa.y, wl.y, al0);
            ar0 = fmaf(xa.x, wr.x, ar0); ar0 = fmaf(xa.y, wr.y, ar0);
            al1 = fmaf(xb.x, wl.x, al1); al1 = fmaf(xb.y, wl.y, al1);
            ar1 = fmaf(xb.x, wr.x, ar1); ar1 = fmaf(xb.y, wr.y, ar1);
            al2 = fmaf(xc.x, wl.x, al2); al2 = fmaf(xc.y, wl.y, al2);
            ar2 = fmaf(xc.x, wr.x, ar2); ar2 = fmaf(xc.y, wr.y, ar2);
            al3 = fmaf(xd.x, wl.x, al3); al3 = fmaf(xd.y, wl.y, al3);
            ar3 = fmaf(xd.x, wr.x, ar3); ar3 = fmaf(xd.y, wr.y, ar3);
        }
        int nb_ = node0 + w * 4;
        if (nb_ + 0 < n) { xl[(size_t)(nb_ + 0) * 64 + c] = __float2bfloat16(al0); xr[(size_t)(nb_ + 0) * 64 + c] = __float2bfloat16(ar0); }
        if (nb_ + 1 < n) { xl[(size_t)(nb_ + 1) * 64 + c] = __float2bfloat16(al1); xr[(size_t)(nb_ + 1) * 64 + c] = __float2bfloat16(ar1); }
        if (nb_ + 2 < n) { xl[(size_t)(nb_ + 2) * 64 + c] = __float2bfloat16(al2); xr[(size_t)(nb_ + 2) * 64 + c] = __float2bfloat16(ar2); }
        if (nb_ + 3 < n) { xl[(size_t)(nb_ + 3) * 64 + c] = __float2bfloat16(al3); xr[(size_t)(nb_ + 3) * 64 + c] = __float2bfloat16(ar3); }
    }
}

// ---------------- fused GAT: wave per destination node (CSR), unroll-4 ----------------

__global__ void gat_node_k(const bf16* __restrict__ xl, const bf16* __restrict__ xr,
                           const float* __restrict__ We, const float* __restrict__ att,
                           const int* __restrict__ row_start, const uint* __restrict__ src_sorted,
                           const uint2* __restrict__ eat,
                           float* __restrict__ out, int n) {
    int t = threadIdx.x;
    int c = t & 63;
    int node = blockIdx.x * 4 + (t >> 6);
    if (node >= n) return;
    float w0 = We[c], w1 = We[64 + c], w2 = We[128 + c], w3 = We[192 + c];
    float ratt = att[c] * 1.44269504f;   // exp(a) = exp2(a*log2e)
    float xrd = __bfloat162float(xr[((size_t)node << 6) + c]);
    int rs = row_start[node], re = row_start[node + 1];
    float srun = 0.f, acc = 0.f;

#define EDGE(U, EA, XV, M) { \
        float2 e01 = __bfloat1622float2(*reinterpret_cast<const __hip_bfloat162*>(&(EA).x)); \
        float2 e23 = __bfloat1622float2(*reinterpret_cast<const __hip_bfloat162*>(&(EA).y)); \
        float M = (XV) + xrd; \
        M = fmaf(e01.x, w0, M); M = fmaf(e01.y, w1, M); \
        M = fmaf(e23.x, w2, M); M = fmaf(e23.y, w3, M); \
        M = fmaxf(M, 0.2f * M); \
        M *= ratt; \
        M += __shfl_xor(M, 1); M += __shfl_xor(M, 2); \
        M += __shfl_xor(M, 4); M += __shfl_xor(M, 8); \
        float p = exp2f(M); \
        srun += p; \
        acc = fmaf(p, (XV), acc); \
    }

    int i = rs;
    for (; i + 4 <= re; i += 4) {
        uint u0 = src_sorted[i],     u1 = src_sorted[i + 1];
        uint u2 = src_sorted[i + 2], u3 = src_sorted[i + 3];
        uint2 e0 = eat[i],     e1 = eat[i + 1];
        uint2 e2 = eat[i + 2], e3 = eat[i + 3];
        float x0 = __bfloat162float(xl[((size_t)u0 << 6) + c]);
        float x1 = __bfloat162float(xl[((size_t)u1 << 6) + c]);
        float x2 = __bfloat162float(xl[((size_t)u2 << 6) + c]);
        float x3 = __bfloat162float(xl[((size_t)u3 << 6) + c]);
        EDGE(u0, e0, x0, m0); EDGE(u1, e1, x1, m1);
        EDGE(u2, e2, x2, m2); EDGE(u3, e3, x3, m3);
    }
    for (; i < re; ++i) {
        uint u0 = src_sorted[i];
        uint2 e0 = eat[i];
        float x0 = __bfloat162float(xl[((size_t)u0 << 6) + c]);
        EDGE(u0, e0, x0, m0);
    }
#undef EDGE

    out[((size_t)node << 6) + c] = acc / (srun + 1e-16f);
}

// ---------------- BN stats ----------------

__global__ void bn_stats_k(const float* __restrict__ x, float* __restrict__ sums,
                           float* __restrict__ sqs, int n) {
    __shared__ float ls[256], lq[256];
    int t = threadIdx.x;
    int c = t & 63, sub = t >> 6;
    float s = 0.f, q = 0.f;
    for (int r = blockIdx.x * 4 + sub; r < n; r += gridDim.x * 4) {
        float v = x[(size_t)r * 64 + c];
        s += v;
        q = fmaf(v, v, q);
    }
    ls[t] = s; lq[t] = q;
    __syncthreads();
    if (t < 128) { ls[t] += ls[t + 128]; lq[t] += lq[t + 128]; }
    __syncthreads();
    if (t < 64) {
        atomicAdd(&sums[c], ls[t] + ls[t + 64]);
        atomicAdd(&sqs[c], lq[t] + lq[t + 64]);
    }
}

// ---------------- head fc 64->64 (fused input BN+ELU, fused output stats) ----------------

__global__ __launch_bounds__(256) void lin1_k(
        const float* __restrict__ x, int n,
        const float* __restrict__ sums, const float* __restrict__ sqs,
        const float* __restrict__ g, const float* __restrict__ be,
        const float* __restrict__ W, const float* __restrict__ b,
        float* __restrict__ y, float* __restrict__ sums_o, float* __restrict__ sqs_o,
        int ngroups16) {
    __shared__ float2 sW2[32 * 64];
    __shared__ float sx[16 * 64];
    __shared__ float ssc[64], ssh[64];
    __shared__ float ls[256], lq[256];
    int t = threadIdx.x;
    if (t < 64) {
        float inv_n = 1.f / n;
        float mu = sums[t] * inv_n;
        float var = sqs[t] * inv_n - mu * mu;
        float sc = rsqrtf(var + 1e-5f) * g[t];
        ssc[t] = sc; ssh[t] = be[t] - mu * sc;
    }
    for (int i = t; i < 32 * 64; i += 256) {
        int k2 = i >> 6, c = i & 63;
        sW2[i] = make_float2(W[(2 * k2) * 64 + c], W[(2 * k2 + 1) * 64 + c]);
    }
    int c = t & 63, w = t >> 6;
    float bc = b[c];
    float s = 0.f, q = 0.f;
    for (int gidx = blockIdx.x; gidx < ngroups16; gidx += gridDim.x) {
        int node0 = gidx * 16;
        __syncthreads();
        for (int i = t; i < 16 * 64; i += 256) {
            int r = node0 + (i >> 6);
            float v = (r < n) ? x[(size_t)r * 64 + (i & 63)] : 0.f;
            v = v * ssc[i & 63] + ssh[i & 63];
            sx[i] = v > 0.f ? v : __expf(v) - 1.f;
        }
        __syncthreads();
        float a0 = bc, a1 = bc, a2 = bc, a3 = bc;
        const float* sx0 = sx + w * 4 * 64;
#pragma unroll 8
        for (int k2 = 0; k2 < 32; ++k2) {
            float2 wv = sW2[k2 * 64 + c];
            float2 xa = *(const float2*)&sx0[k2 * 2];
            float2 xb = *(const float2*)&sx0[64 + k2 * 2];
            float2 xc = *(const float2*)&sx0[128 + k2 * 2];
            float2 xd = *(const float2*)&sx0[192 + k2 * 2];
            a0 = fmaf(xa.x, wv.x, a0); a0 = fmaf(xa.y, wv.y, a0);
            a1 = fmaf(xb.x, wv.x, a1); a1 = fmaf(xb.y, wv.y, a1);
            a2 = fmaf(xc.x, wv.x, a2); a2 = fmaf(xc.y, wv.y, a2);
            a3 = fmaf(xd.x, wv.x, a3); a3 = fmaf(xd.y, wv.y, a3);
        }
        int nb_ = node0 + w * 4;
        if (nb_ + 0 < n) { y[(size_t)(nb_ + 0) * 64 + c] = a0; s += a0; q = fmaf(a0, a0, q); }
        if (nb_ + 1 < n) { y[(size_t)(nb_ + 1) * 64 + c] = a1; s += a1; q = fmaf(a1, a1, q); }
        if (nb_ + 2 < n) { y[(size_t)(nb_ + 2) * 64 + c] = a2; s += a2; q = fmaf(a2, a2, q); }
        if (nb_ + 3 < n) { y[(size_t)(nb_ + 3) * 64 + c] = a3; s += a3; q = fmaf(a3, a3, q); }
    }
    __syncthreads();
    ls[t] = s; lq[t] = q;
    __syncthreads();
    if (t < 64) {
        float ss = ls[t] + ls[t + 64] + ls[t + 128] + ls[t + 192];
        float qq = lq[t] + lq[t + 64] + lq[t + 128] + lq[t + 192];
        atomicAdd(&sums_o[t], ss);
        atomicAdd(&sqs_o[t], qq);
    }
}

// ---------------- final: fused BN+ELU + dot(64) + 5*tanh ----------------

__global__ void final_k(const float* __restrict__ z, int n,
                        const float* __restrict__ sums, const float* __restrict__ sqs,
                        const float* __restrict__ g, const float* __restrict__ be,
                        const float* __restrict__ W2, const float* __restrict__ b2,
                        float* __restrict__ out) {
    int t = blockIdx.x * blockDim.x + threadIdx.x;
    int node = t >> 6, c = t & 63;
    if (node >= n) return;
    float inv_n = 1.f / n;
    float mu = sums[c] * inv_n;
    float var = sqs[c] * inv_n - mu * mu;
    float scc = rsqrtf(var + 1e-5f) * g[c];
    float sh = be[c] - mu * scc;
    float v = z[(size_t)node * 64 + c] * scc + sh;
    v = v > 0.f ? v : __expf(v) - 1.f;
    v *= W2[c];
    v += __shfl_xor(v, 1);
    v += __shfl_xor(v, 2);
    v += __shfl_xor(v, 4);
    v += __shfl_xor(v, 8);
    v += __shfl_xor(v, 16);
    v += __shfl_xor(v, 32);
    if (c == 0) out[node] = 5.0f * tanhf(v + b2[0]);
}

// ---------------- launch ----------------

extern "C" void kernel_launch(void* const* d_in, const int* in_sizes, int n_in,
                              void* d_out, int out_size, void* d_ws, size_t ws_size,
                              hipStream_t stream) {
    const float* x0    = (const float*)d_in[0];
    const int*   eidx  = (const int*)d_in[1];
    const float* eattr = (const float*)d_in[2];

    const float* Wl[2]; const float* bl[2]; const float* Wr[2]; const float* br[2];
    const float* We[2]; const float* att[2]; const float* g[2]; const float* be[2];
    for (int l = 0; l < 2; ++l) {
        int base = 3 + l * 9;
        Wl[l]  = (const float*)d_in[base + 0];
        bl[l]  = (const float*)d_in[base + 1];
        Wr[l]  = (const float*)d_in[base + 2];
        br[l]  = (const float*)d_in[base + 3];
        We[l]  = (const float*)d_in[base + 4];
        att[l] = (const float*)d_in[base + 5];
        // base+6 = bias: per-channel constant, cancels exactly under BatchNorm
        g[l]   = (const float*)d_in[base + 7];
        be[l]  = (const float*)d_in[base + 8];
    }
    const float* W1 = (const float*)d_in[21];
    const float* b1 = (const float*)d_in[22];
    const float* gf = (const float*)d_in[23];
    const float* bf = (const float*)d_in[24];
    const float* W2 = (const float*)d_in[25];
    const float* b2 = (const float*)d_in[26];

    const int N = in_sizes[0] / 128;
    const int E = in_sizes[1] / 2;
    const int* src = eidx;
    const int* dst = eidx + E;
    const int nbk = (N + 127) >> 7;

    // workspace (4-byte units).  Region A is shared: (tea,tsd) then (h0,h1).
    float* ws = (float*)d_ws;
    size_t o = 0;
    float* regionA = ws + o; o += (size_t)2 * N * HC;         // 2*N*64 floats >= E*3 units
    uint2* tea = (uint2*)regionA;                              // E*2 units
    uint*  tsd = (uint*)(regionA + (size_t)2 * E);             // E units
    float* h0  = regionA;                                      // N*64
    float* h1  = regionA + (size_t)N * HC;                     // N*64
    uint2* eat_sorted = (uint2*)(ws + o); o += (size_t)E * 2;
    uint*  src_sorted = (uint*)(ws + o);  o += (size_t)E;
    bf16*  xl  = (bf16*)(ws + o);  o += (size_t)N * 32;
    bf16*  xr  = (bf16*)(ws + o);  o += (size_t)N * 32;
    int*   row_start = (int*)(ws + o); o += (size_t)N + 1;
    int*   bcnt   = (int*)(ws + o); o += 512;
    int*   bstart = (int*)(ws + o); o += 513;
    int*   bcur   = (int*)(ws + o); o += 512;
    float* stats  = ws + o; o += 6 * HC;
    float* s0 = stats,        *q0 = stats + 64;
    float* s1 = stats + 128,  *q1 = stats + 192;
    float* sf = stats + 256,  *qf = stats + 320;

    const int ngroups4  = (N + 3) / 4;
    const int ngroups16 = (N + 15) / 16;
    const int EB = (E + 8191) / 8192;

    hipMemsetAsync(bcnt, 0, 512 * 4, stream);
    hipMemsetAsync(stats, 0, 6 * HC * 4, stream);

    // CSR build: coarse bucket + in-LDS counting sort (shared by both layers)
    bucket_hist_k<<<EB, 512, 0, stream>>>(dst, bcnt, E, nbk);
    bucket_scan_k<<<1, 512, 0, stream>>>(bcnt, bstart, bcur, nbk, E);
    bucketA_k<<<EB, 1024, 0, stream>>>(src, dst, (const float4*)eattr, bcur, tsd, tea, E, nbk);
    bucket_sort_k<<<nbk, 256, 0, stream>>>(tsd, tea, bstart, src_sorted, eat_sorted,
                                           row_start, N);

    // layer 0  (h0 overwrites regionA only after tsd/tea are consumed)
    lin128_k<<<512, 256, 0, stream>>>(x0, N, Wl[0], bl[0], Wr[0], br[0], xl, xr, ngroups16);
    gat_node_k<<<ngroups4, 256, 0, stream>>>(xl, xr, We[0], att[0], row_start,
                                             src_sorted, eat_sorted, h0, N);
    bn_stats_k<<<256, 256, 0, stream>>>(h0, s0, q0, N);

    // layer 1 (input BN+ELU fused)
    lin64bn_k<<<512, 256, 0, stream>>>(h0, N, s0, q0, g[0], be[0],
                                       Wl[1], bl[1], Wr[1], br[1], xl, xr, ngroups16);
    gat_node_k<<<ngroups4, 256, 0, stream>>>(xl, xr, We[1], att[1], row_start,
                                             src_sorted, eat_sorted, h1, N);
    bn_stats_k<<<256, 256, 0, stream>>>(h1, s1, q1, N);

    // head
    float* y = h0;  // h0 dead after lin64bn
    lin1_k<<<512, 256, 0, stream>>>(h1, N, s1, q1, g[1], be[1], W1, b1, y, sf, qf, ngroups16);
    final_k<<<(int)(((size_t)N * 64 + 255) / 256), 256, 0, stream>>>(
        y, N, sf, qf, gf, bf, W2, b2, (float*)d_out);
}

// Round 7
// 397.757 us; speedup vs baseline: 4.6931x; 1.0679x over previous
//
#include <hip/hip_runtime.h>
#include <hip/hip_bf16.h>
#include <cmath>

#define HC 64
typedef __hip_bfloat16 bf16;
typedef unsigned int uint;
typedef float v2f __attribute__((ext_vector_type(2)));

__device__ __forceinline__ uint pack_bf2(float a, float b) {
    __hip_bfloat162 h = __float22bfloat162_rn(make_float2(a, b));
    return *reinterpret_cast<uint*>(&h);
}
__device__ __forceinline__ float bfl(uint u) { return __uint_as_float(u << 16); }
__device__ __forceinline__ float bfh(uint u) { return __uint_as_float(u & 0xffff0000u); }

// ---------------- coarse bucket histogram (dst>>7), LDS-aggregated ----------------

__global__ __launch_bounds__(512) void bucket_hist_k(const int* __restrict__ dst,
                                                     int* __restrict__ bcnt, int E, int nbk) {
    __shared__ int lh[512];
    int t = threadIdx.x;
    for (int i = t; i < nbk; i += 512) lh[i] = 0;
    __syncthreads();
    int base = blockIdx.x * 8192;
#pragma unroll
    for (int k = 0; k < 16; ++k) {
        int e = base + k * 512 + t;
        if (e < E) atomicAdd(&lh[dst[e] >> 7], 1);
    }
    __syncthreads();
    for (int i = t; i < nbk; i += 512) if (lh[i]) atomicAdd(&bcnt[i], lh[i]);
}

// ---------------- scan over nbk (<=512) buckets ----------------

__global__ __launch_bounds__(512) void bucket_scan_k(const int* __restrict__ bcnt,
                                                     int* __restrict__ bstart,
                                                     int* __restrict__ bcur, int nbk, int E) {
    __shared__ int tmp[512];
    int t = threadIdx.x;
    int v = (t < nbk) ? bcnt[t] : 0;
    tmp[t] = v;
    __syncthreads();
    for (int off = 1; off < 512; off <<= 1) {
        int a = (t >= off) ? tmp[t - off] : 0;
        __syncthreads();
        tmp[t] += a;
        __syncthreads();
    }
    if (t < nbk) { int ex = tmp[t] - v; bstart[t] = ex; bcur[t] = ex; }
    if (t == 0) bstart[nbk] = E;
}

// ---------------- grouping: append 12B records into coarse bucket regions ----------------

__global__ __launch_bounds__(1024) void bucketA_k(
        const int* __restrict__ src, const int* __restrict__ dst,
        const float4* __restrict__ eattr, int* __restrict__ bcur,
        uint* __restrict__ tsd, uint2* __restrict__ tea, int E, int nbk) {
    __shared__ int lcnt[512];
    __shared__ int lbase[512];
    int t = threadIdx.x;
    for (int i = t; i < nbk; i += 1024) lcnt[i] = 0;
    __syncthreads();
    int base = blockIdx.x * 8192;
    int myb[8], mylp[8];
#pragma unroll
    for (int k = 0; k < 8; ++k) {
        int e = base + k * 1024 + t;
        if (e < E) {
            int b = dst[e] >> 7;
            myb[k] = b;
            mylp[k] = atomicAdd(&lcnt[b], 1);
        } else myb[k] = -1;
    }
    __syncthreads();
    for (int i = t; i < nbk; i += 1024) {
        int cc = lcnt[i];
        lbase[i] = cc ? atomicAdd(&bcur[i], cc) : 0;
    }
    __syncthreads();
#pragma unroll
    for (int k = 0; k < 8; ++k) {
        int e = base + k * 1024 + t;
        if (e >= E) continue;
        int pos = lbase[myb[k]] + mylp[k];
        int d = dst[e];
        tsd[pos] = (uint)src[e] | ((uint)(d & 127) << 25);
        float4 ea = eattr[e];
        tea[pos] = make_uint2(pack_bf2(ea.x, ea.y), pack_bf2(ea.z, ea.w));
    }
}

// ---------------- in-LDS counting sort per bucket -> exact CSR ----------------
// emits spre = src byte-offset into xl (src*128)

__global__ __launch_bounds__(256) void bucket_sort_k(
        const uint* __restrict__ tsd, const uint2* __restrict__ tea,
        const int* __restrict__ bstart,
        uint* __restrict__ spre_sorted, uint2* __restrict__ eat_sorted,
        int* __restrict__ row_start, int n) {
    __shared__ int cnt[128], pfx[128], cur[128];
    int b = blockIdx.x, t = threadIdx.x;
    int i0 = bstart[b], i1 = bstart[b + 1];
    int node0 = b << 7;
    if (t < 128) cnt[t] = 0;
    __syncthreads();
    for (int i = i0 + t; i < i1; i += 256) atomicAdd(&cnt[tsd[i] >> 25], 1);
    __syncthreads();
    if (t < 128) pfx[t] = cnt[t];
    __syncthreads();
    for (int off = 1; off < 128; off <<= 1) {
        int a = (t < 128 && t >= off) ? pfx[t - off] : 0;
        __syncthreads();
        if (t < 128) pfx[t] += a;
        __syncthreads();
    }
    if (t < 128) {
        int ex = pfx[t] - cnt[t];
        cur[t] = ex;
        if (node0 + t <= n) row_start[node0 + t] = i0 + ex;
    }
    __syncthreads();
    for (int i = i0 + t; i < i1; i += 256) {
        uint u = tsd[i];
        int dl = (int)(u >> 25);
        int pos = i0 + atomicAdd(&cur[dl], 1);
        spre_sorted[pos] = (u & 0x1FFFFFFu) << 7;   // byte offset into xl rows (64ch * 2B)
        eat_sorted[pos] = tea[i];
    }
}

// ---------------- layer-0 linear: din=128, 16 nodes/block (4/thread) ----------------

__global__ __launch_bounds__(256) void lin128_k(
        const float* __restrict__ x, int n,
        const float* __restrict__ Wl, const float* __restrict__ bl,
        const float* __restrict__ Wr, const float* __restrict__ br,
        bf16* __restrict__ xl, bf16* __restrict__ xr, int ngroups16) {
    __shared__ float2 sWl2[64 * 64];
    __shared__ float2 sWr2[64 * 64];
    __shared__ float sx[16 * 128];
    int t = threadIdx.x;
    for (int i = t; i < 64 * 64; i += 256) {
        int k2 = i >> 6, c = i & 63;
        sWl2[i] = make_float2(Wl[(2 * k2) * 64 + c], Wl[(2 * k2 + 1) * 64 + c]);
        sWr2[i] = make_float2(Wr[(2 * k2) * 64 + c], Wr[(2 * k2 + 1) * 64 + c]);
    }
    int c = t & 63, w = t >> 6;
    float blc = bl[c], brc = br[c];
    for (int gidx = blockIdx.x; gidx < ngroups16; gidx += gridDim.x) {
        int node0 = gidx * 16;
        __syncthreads();
        for (int i = t; i < 16 * 128; i += 256) {
            int r = node0 + (i >> 7);
            sx[i] = (r < n) ? x[(size_t)r * 128 + (i & 127)] : 0.f;
        }
        __syncthreads();
        float al0 = blc, al1 = blc, al2 = blc, al3 = blc;
        float ar0 = brc, ar1 = brc, ar2 = brc, ar3 = brc;
        const float* sx0 = sx + w * 4 * 128;
#pragma unroll 8
        for (int k2 = 0; k2 < 64; ++k2) {
            float2 wl = sWl2[k2 * 64 + c], wr = sWr2[k2 * 64 + c];
            float2 xa = *(const float2*)&sx0[k2 * 2];
            float2 xb = *(const float2*)&sx0[128 + k2 * 2];
            float2 xc = *(const float2*)&sx0[256 + k2 * 2];
            float2 xd = *(const float2*)&sx0[384 + k2 * 2];
            al0 = fmaf(xa.x, wl.x, al0); al0 = fmaf(xa.y, wl.y, al0);
            ar0 = fmaf(xa.x, wr.x, ar0); ar0 = fmaf(xa.y, wr.y, ar0);
            al1 = fmaf(xb.x, wl.x, al1); al1 = fmaf(xb.y, wl.y, al1);
            ar1 = fmaf(xb.x, wr.x, ar1); ar1 = fmaf(xb.y, wr.y, ar1);
            al2 = fmaf(xc.x, wl.x, al2); al2 = fmaf(xc.y, wl.y, al2);
            ar2 = fmaf(xc.x, wr.x, ar2); ar2 = fmaf(xc.y, wr.y, ar2);
            al3 = fmaf(xd.x, wl.x, al3); al3 = fmaf(xd.y, wl.y, al3);
            ar3 = fmaf(xd.x, wr.x, ar3); ar3 = fmaf(xd.y, wr.y, ar3);
        }
        int nb_ = node0 + w * 4;
        if (nb_ + 0 < n) { xl[(size_t)(nb_ + 0) * 64 + c] = __float2bfloat16(al0); xr[(size_t)(nb_ + 0) * 64 + c] = __float2bfloat16(ar0); }
        if (nb_ + 1 < n) { xl[(size_t)(nb_ + 1) * 64 + c] = __float2bfloat16(al1); xr[(size_t)(nb_ + 1) * 64 + c] = __float2bfloat16(ar1); }
        if (nb_ + 2 < n) { xl[(size_t)(nb_ + 2) * 64 + c] = __float2bfloat16(al2); xr[(size_t)(nb_ + 2) * 64 + c] = __float2bfloat16(ar2); }
        if (nb_ + 3 < n) { xl[(size_t)(nb_ + 3) * 64 + c] = __float2bfloat16(al3); xr[(size_t)(nb_ + 3) * 64 + c] = __float2bfloat16(ar3); }
    }
}

// ---------------- layer-1 linear: din=64, fused input BN+ELU ----------------

__global__ __launch_bounds__(256) void lin64bn_k(
        const float* __restrict__ x, int n,
        const float* __restrict__ sums, const float* __restrict__ sqs,
        const float* __restrict__ g, const float* __restrict__ be,
        const float* __restrict__ Wl, const float* __restrict__ bl,
        const float* __restrict__ Wr, const float* __restrict__ br,
        bf16* __restrict__ xl, bf16* __restrict__ xr, int ngroups16) {
    __shared__ float2 sWl2[32 * 64];
    __shared__ float2 sWr2[32 * 64];
    __shared__ float sx[16 * 64];
    __shared__ float ssc[64], ssh[64];
    int t = threadIdx.x;
    if (t < 64) {
        float inv_n = 1.f / n;
        float mu = sums[t] * inv_n;
        float var = sqs[t] * inv_n - mu * mu;
        float sc = rsqrtf(var + 1e-5f) * g[t];
        ssc[t] = sc; ssh[t] = be[t] - mu * sc;
    }
    for (int i = t; i < 32 * 64; i += 256) {
        int k2 = i >> 6, c = i & 63;
        sWl2[i] = make_float2(Wl[(2 * k2) * 64 + c], Wl[(2 * k2 + 1) * 64 + c]);
        sWr2[i] = make_float2(Wr[(2 * k2) * 64 + c], Wr[(2 * k2 + 1) * 64 + c]);
    }
    int c = t & 63, w = t >> 6;
    float blc = bl[c], brc = br[c];
    for (int gidx = blockIdx.x; gidx < ngroups16; gidx += gridDim.x) {
        int node0 = gidx * 16;
        __syncthreads();
        for (int i = t; i < 16 * 64; i += 256) {
            int r = node0 + (i >> 6);
            float v = (r < n) ? x[(size_t)r * 64 + (i & 63)] : 0.f;
            v = v * ssc[i & 63] + ssh[i & 63];
            sx[i] = v > 0.f ? v : __expf(v) - 1.f;
        }
        __syncthreads();
        float al0 = blc, al1 = blc, al2 = blc, al3 = blc;
        float ar0 = brc, ar1 = brc, ar2 = brc, ar3 = brc;
        const float* sx0 = sx + w * 4 * 64;
#pragma unroll 8
        for (int k2 = 0; k2 < 32; ++k2) {
            float2 wl = sWl2[k2 * 64 + c], wr = sWr2[k2 * 64 + c];
            float2 xa = *(const float2*)&sx0[k2 * 2];
            float2 xb = *(const float2*)&sx0[64 + k2 * 2];
            float2 xc = *(const float2*)&sx0[128 + k2 * 2];
            float2 xd = *(const float2*)&sx0[192 + k2 * 2];
            al0 = fmaf(xa.x, wl.x, al0); al0 = fmaf(xa.y, wl.y, al0);
            ar0 = fmaf(xa.x, wr.x, ar0); ar0 = fmaf(xa.y, wr.y, ar0);
            al1 = fmaf(xb.x, wl.x, al1); al1 = fmaf(xb.y, wl.y, al1);
            ar1 = fmaf(xb.x, wr.x, ar1); ar1 = fmaf(xb.y, wr.y, ar1);
            al2 = fmaf(xc.x, wl.x, al2); al2 = fmaf(xc.y, wl.y, al2);
            ar2 = fmaf(xc.x, wr.x, ar2); ar2 = fmaf(xc.y, wr.y, ar2);
            al3 = fmaf(xd.x, wl.x, al3); al3 = fmaf(xd.y, wl.y, al3);
            ar3 = fmaf(xd.x, wr.x, ar3); ar3 = fmaf(xd.y, wr.y, ar3);
        }
        int nb_ = node0 + w * 4;
        if (nb_ + 0 < n) { xl[(size_t)(nb_ + 0) * 64 + c] = __float2bfloat16(al0); xr[(size_t)(nb_ + 0) * 64 + c] = __float2bfloat16(ar0); }
        if (nb_ + 1 < n) { xl[(size_t)(nb_ + 1) * 64 + c] = __float2bfloat16(al1); xr[(size_t)(nb_ + 1) * 64 + c] = __float2bfloat16(ar1); }
        if (nb_ + 2 < n) { xl[(size_t)(nb_ + 2) * 64 + c] = __float2bfloat16(al2); xr[(size_t)(nb_ + 2) * 64 + c] = __float2bfloat16(ar2); }
        if (nb_ + 3 < n) { xl[(size_t)(nb_ + 3) * 64 + c] = __float2bfloat16(al3); xr[(size_t)(nb_ + 3) * 64 + c] = __float2bfloat16(ar3); }
    }
}

// ---------------- fused GAT: wave per node, 2 channels/lane, 2 edges/wave ----------------

__global__ __launch_bounds__(256) void gat_node_k(
        const bf16* __restrict__ xl, const bf16* __restrict__ xr,
        const float* __restrict__ We, const float* __restrict__ att,
        const int* __restrict__ row_start, const uint* __restrict__ spre,
        const uint2* __restrict__ eat,
        float* __restrict__ out, int n) {
    int t = threadIdx.x;
    int lane = t & 63;
    int half = lane >> 5;          // 0 = even edge of pair, 1 = odd
    int c2 = lane & 31;            // channel pair index: channels 2*c2, 2*c2+1
    int node = blockIdx.x * 4 + (t >> 6);
    if (node >= n) return;
    int c0 = c2 << 1;
    v2f w0 = {We[c0], We[c0 + 1]};
    v2f w1 = {We[64 + c0], We[64 + c0 + 1]};
    v2f w2 = {We[128 + c0], We[128 + c0 + 1]};
    v2f w3 = {We[192 + c0], We[192 + c0 + 1]};
    v2f ratt = {att[c0] * 1.44269504f, att[c0 + 1] * 1.44269504f};
    const char* xlb = (const char*)xl;
    uint xru = *(const uint*)((const char*)xr + ((size_t)node << 7) + ((uint)c0 << 1));
    v2f xrd = {bfl(xru), bfh(xru)};
    int rs = row_start[node], re = row_start[node + 1];
    v2f acc = {0.f, 0.f};
    float srun = 0.f;
    uint coff = (uint)c2 << 2;

#define PROC(EA, XU, P) { \
        v2f xv = {bfl(XU), bfh(XU)}; \
        v2f z = xv + xrd; \
        float e0 = bfl((EA).x), e1 = bfh((EA).x); \
        float e2 = bfl((EA).y), e3 = bfh((EA).y); \
        z.x = fmaf(e0, w0.x, z.x); z.y = fmaf(e0, w0.y, z.y); \
        z.x = fmaf(e1, w1.x, z.x); z.y = fmaf(e1, w1.y, z.y); \
        z.x = fmaf(e2, w2.x, z.x); z.y = fmaf(e2, w2.y, z.y); \
        z.x = fmaf(e3, w3.x, z.x); z.y = fmaf(e3, w3.y, z.y); \
        z = __builtin_elementwise_max(z, 0.2f * z); \
        float v = fmaf(z.y, ratt.y, z.x * ratt.x); \
        v += __shfl_xor(v, 1); v += __shfl_xor(v, 2); v += __shfl_xor(v, 4); \
        float P = exp2f(v); \
        srun += P; \
        acc.x = fmaf(P, xv.x, acc.x); \
        acc.y = fmaf(P, xv.y, acc.y); \
    }

    int i = rs;
    for (; i + 4 <= re; i += 4) {
        uint spA = spre[i + half], spB = spre[i + 2 + half];
        uint2 eaA = eat[i + half], eaB = eat[i + 2 + half];
        uint xuA = *(const uint*)(xlb + spA + coff);
        uint xuB = *(const uint*)(xlb + spB + coff);
        PROC(eaA, xuA, pA);
        PROC(eaB, xuB, pB);
    }
    for (; i < re; i += 2) {
        int ei = i + half;
        bool ok = ei < re;
        int eic = ok ? ei : i;
        uint sp = spre[eic];
        uint2 ea = eat[eic];
        uint xu = *(const uint*)(xlb + sp + coff);
        v2f xv = {bfl(xu), bfh(xu)};
        v2f z = xv + xrd;
        float e0 = bfl(ea.x), e1 = bfh(ea.x);
        float e2 = bfl(ea.y), e3 = bfh(ea.y);
        z.x = fmaf(e0, w0.x, z.x); z.y = fmaf(e0, w0.y, z.y);
        z.x = fmaf(e1, w1.x, z.x); z.y = fmaf(e1, w1.y, z.y);
        z.x = fmaf(e2, w2.x, z.x); z.y = fmaf(e2, w2.y, z.y);
        z.x = fmaf(e3, w3.x, z.x); z.y = fmaf(e3, w3.y, z.y);
        z = __builtin_elementwise_max(z, 0.2f * z);
        float v = fmaf(z.y, ratt.y, z.x * ratt.x);
        v += __shfl_xor(v, 1); v += __shfl_xor(v, 2); v += __shfl_xor(v, 4);
        float p = ok ? exp2f(v) : 0.f;
        srun += p;
        acc.x = fmaf(p, xv.x, acc.x);
        acc.y = fmaf(p, xv.y, acc.y);
    }
#undef PROC

    // merge even/odd halves
    srun += __shfl_xor(srun, 32);
    acc.x += __shfl_xor(acc.x, 32);
    acc.y += __shfl_xor(acc.y, 32);
    if (half == 0) {
        float inv = 1.f / (srun + 1e-16f);
        float2 o = make_float2(acc.x * inv, acc.y * inv);
        *(float2*)&out[((size_t)node << 6) + (uint)c0] = o;
    }
}

// ---------------- BN stats ----------------

__global__ void bn_stats_k(const float* __restrict__ x, float* __restrict__ sums,
                           float* __restrict__ sqs, int n) {
    __shared__ float ls[256], lq[256];
    int t = threadIdx.x;
    int c = t & 63, sub = t >> 6;
    float s = 0.f, q = 0.f;
    for (int r = blockIdx.x * 4 + sub; r < n; r += gridDim.x * 4) {
        float v = x[(size_t)r * 64 + c];
        s += v;
        q = fmaf(v, v, q);
    }
    ls[t] = s; lq[t] = q;
    __syncthreads();
    if (t < 128) { ls[t] += ls[t + 128]; lq[t] += lq[t + 128]; }
    __syncthreads();
    if (t < 64) {
        atomicAdd(&sums[c], ls[t] + ls[t + 64]);
        atomicAdd(&sqs[c], lq[t] + lq[t + 64]);
    }
}

// ---------------- head fc 64->64 (fused input BN+ELU, fused output stats) ----------------

__global__ __launch_bounds__(256) void lin1_k(
        const float* __restrict__ x, int n,
        const float* __restrict__ sums, const float* __restrict__ sqs,
        const float* __restrict__ g, const float* __restrict__ be,
        const float* __restrict__ W, const float* __restrict__ b,
        float* __restrict__ y, float* __restrict__ sums_o, float* __restrict__ sqs_o,
        int ngroups16) {
    __shared__ float2 sW2[32 * 64];
    __shared__ float sx[16 * 64];
    __shared__ float ssc[64], ssh[64];
    __shared__ float ls[256], lq[256];
    int t = threadIdx.x;
    if (t < 64) {
        float inv_n = 1.f / n;
        float mu = sums[t] * inv_n;
        float var = sqs[t] * inv_n - mu * mu;
        float sc = rsqrtf(var + 1e-5f) * g[t];
        ssc[t] = sc; ssh[t] = be[t] - mu * sc;
    }
    for (int i = t; i < 32 * 64; i += 256) {
        int k2 = i >> 6, c = i & 63;
        sW2[i] = make_float2(W[(2 * k2) * 64 + c], W[(2 * k2 + 1) * 64 + c]);
    }
    int c = t & 63, w = t >> 6;
    float bc = b[c];
    float s = 0.f, q = 0.f;
    for (int gidx = blockIdx.x; gidx < ngroups16; gidx += gridDim.x) {
        int node0 = gidx * 16;
        __syncthreads();
        for (int i = t; i < 16 * 64; i += 256) {
            int r = node0 + (i >> 6);
            float v = (r < n) ? x[(size_t)r * 64 + (i & 63)] : 0.f;
            v = v * ssc[i & 63] + ssh[i & 63];
            sx[i] = v > 0.f ? v : __expf(v) - 1.f;
        }
        __syncthreads();
        float a0 = bc, a1 = bc, a2 = bc, a3 = bc;
        const float* sx0 = sx + w * 4 * 64;
#pragma unroll 8
        for (int k2 = 0; k2 < 32; ++k2) {
            float2 wv = sW2[k2 * 64 + c];
            float2 xa = *(const float2*)&sx0[k2 * 2];
            float2 xb = *(const float2*)&sx0[64 + k2 * 2];
            float2 xc = *(const float2*)&sx0[128 + k2 * 2];
            float2 xd = *(const float2*)&sx0[192 + k2 * 2];
            a0 = fmaf(xa.x, wv.x, a0); a0 = fmaf(xa.y, wv.y, a0);
            a1 = fmaf(xb.x, wv.x, a1); a1 = fmaf(xb.y, wv.y, a1);
            a2 = fmaf(xc.x, wv.x, a2); a2 = fmaf(xc.y, wv.y, a2);
            a3 = fmaf(xd.x, wv.x, a3); a3 = fmaf(xd.y, wv.y, a3);
        }
        int nb_ = node0 + w * 4;
        if (nb_ + 0 < n) { y[(size_t)(nb_ + 0) * 64 + c] = a0; s += a0; q = fmaf(a0, a0, q); }
        if (nb_ + 1 < n) { y[(size_t)(nb_ + 1) * 64 + c] = a1; s += a1; q = fmaf(a1, a1, q); }
        if (nb_ + 2 < n) { y[(size_t)(nb_ + 2) * 64 + c] = a2; s += a2; q = fmaf(a2, a2, q); }
        if (nb_ + 3 < n) { y[(size_t)(nb_ + 3) * 64 + c] = a3; s += a3; q = fmaf(a3, a3, q); }
    }
    __syncthreads();
    ls[t] = s; lq[t] = q;
    __syncthreads();
    if (t < 64) {
        float ss = ls[t] + ls[t + 64] + ls[t + 128] + ls[t + 192];
        float qq = lq[t] + lq[t + 64] + lq[t + 128] + lq[t + 192];
        atomicAdd(&sums_o[t], ss);
        atomicAdd(&sqs_o[t], qq);
    }
}

// ---------------- final: fused BN+ELU + dot(64) + 5*tanh ----------------

__global__ void final_k(const float* __restrict__ z, int n,
                        const float* __restrict__ sums, const float* __restrict__ sqs,
                        const float* __restrict__ g, const float* __restrict__ be,
                        const float* __restrict__ W2, const float* __restrict__ b2,
                        float* __restrict__ out) {
    int t = blockIdx.x * blockDim.x + threadIdx.x;
    int node = t >> 6, c = t & 63;
    if (node >= n) return;
    float inv_n = 1.f / n;
    float mu = sums[c] * inv_n;
    float var = sqs[c] * inv_n - mu * mu;
    float scc = rsqrtf(var + 1e-5f) * g[c];
    float sh = be[c] - mu * scc;
    float v = z[(size_t)node * 64 + c] * scc + sh;
    v = v > 0.f ? v : __expf(v) - 1.f;
    v *= W2[c];
    v += __shfl_xor(v, 1);
    v += __shfl_xor(v, 2);
    v += __shfl_xor(v, 4);
    v += __shfl_xor(v, 8);
    v += __shfl_xor(v, 16);
    v += __shfl_xor(v, 32);
    if (c == 0) out[node] = 5.0f * tanhf(v + b2[0]);
}

// ---------------- launch ----------------

extern "C" void kernel_launch(void* const* d_in, const int* in_sizes, int n_in,
                              void* d_out, int out_size, void* d_ws, size_t ws_size,
                              hipStream_t stream) {
    const float* x0    = (const float*)d_in[0];
    const int*   eidx  = (const int*)d_in[1];
    const float* eattr = (const float*)d_in[2];

    const float* Wl[2]; const float* bl[2]; const float* Wr[2]; const float* br[2];
    const float* We[2]; const float* att[2]; const float* g[2]; const float* be[2];
    for (int l = 0; l < 2; ++l) {
        int base = 3 + l * 9;
        Wl[l]  = (const float*)d_in[base + 0];
        bl[l]  = (const float*)d_in[base + 1];
        Wr[l]  = (const float*)d_in[base + 2];
        br[l]  = (const float*)d_in[base + 3];
        We[l]  = (const float*)d_in[base + 4];
        att[l] = (const float*)d_in[base + 5];
        // base+6 = bias: per-channel constant, cancels exactly under BatchNorm
        g[l]   = (const float*)d_in[base + 7];
        be[l]  = (const float*)d_in[base + 8];
    }
    const float* W1 = (const float*)d_in[21];
    const float* b1 = (const float*)d_in[22];
    const float* gf = (const float*)d_in[23];
    const float* bf = (const float*)d_in[24];
    const float* W2 = (const float*)d_in[25];
    const float* b2 = (const float*)d_in[26];

    const int N = in_sizes[0] / 128;
    const int E = in_sizes[1] / 2;
    const int* src = eidx;
    const int* dst = eidx + E;
    const int nbk = (N + 127) >> 7;

    // workspace (4-byte units).  Region A is shared: (tea,tsd) then (h0,h1).
    float* ws = (float*)d_ws;
    size_t o = 0;
    float* regionA = ws + o; o += (size_t)2 * N * HC;         // 2*N*64 floats >= E*3 units
    uint2* tea = (uint2*)regionA;                              // E*2 units
    uint*  tsd = (uint*)(regionA + (size_t)2 * E);             // E units
    float* h0  = regionA;                                      // N*64
    float* h1  = regionA + (size_t)N * HC;                     // N*64
    uint2* eat_sorted = (uint2*)(ws + o); o += (size_t)E * 2;
    uint*  spre_sorted = (uint*)(ws + o);  o += (size_t)E;
    bf16*  xl  = (bf16*)(ws + o);  o += (size_t)N * 32;
    bf16*  xr  = (bf16*)(ws + o);  o += (size_t)N * 32;
    int*   row_start = (int*)(ws + o); o += (size_t)N + 1;
    int*   bcnt   = (int*)(ws + o); o += 512;
    int*   bstart = (int*)(ws + o); o += 513;
    int*   bcur   = (int*)(ws + o); o += 512;
    float* stats  = ws + o; o += 6 * HC;
    float* s0 = stats,        *q0 = stats + 64;
    float* s1 = stats + 128,  *q1 = stats + 192;
    float* sf = stats + 256,  *qf = stats + 320;

    const int ngroups4  = (N + 3) / 4;
    const int ngroups16 = (N + 15) / 16;
    const int EB = (E + 8191) / 8192;

    hipMemsetAsync(bcnt, 0, 512 * 4, stream);
    hipMemsetAsync(stats, 0, 6 * HC * 4, stream);

    // CSR build: coarse bucket + in-LDS counting sort (shared by both layers)
    bucket_hist_k<<<EB, 512, 0, stream>>>(dst, bcnt, E, nbk);
    bucket_scan_k<<<1, 512, 0, stream>>>(bcnt, bstart, bcur, nbk, E);
    bucketA_k<<<EB, 1024, 0, stream>>>(src, dst, (const float4*)eattr, bcur, tsd, tea, E, nbk);
    bucket_sort_k<<<nbk, 256, 0, stream>>>(tsd, tea, bstart, spre_sorted, eat_sorted,
                                           row_start, N);

    // layer 0  (h0 overwrites regionA only after tsd/tea are consumed)
    lin128_k<<<512, 256, 0, stream>>>(x0, N, Wl[0], bl[0], Wr[0], br[0], xl, xr, ngroups16);
    gat_node_k<<<ngroups4, 256, 0, stream>>>(xl, xr, We[0], att[0], row_start,
                                             spre_sorted, eat_sorted, h0, N);
    bn_stats_k<<<256, 256, 0, stream>>>(h0, s0, q0, N);

    // layer 1 (input BN+ELU fused)
    lin64bn_k<<<512, 256, 0, stream>>>(h0, N, s0, q0, g[0], be[0],
                                       Wl[1], bl[1], Wr[1], br[1], xl, xr, ngroups16);
    gat_node_k<<<ngroups4, 256, 0, stream>>>(xl, xr, We[1], att[1], row_start,
                                             spre_sorted, eat_sorted, h1, N);
    bn_stats_k<<<256, 256, 0, stream>>>(h1, s1, q1, N);

    // head
    float* y = h0;  // h0 dead after lin64bn
    lin1_k<<<512, 256, 0, stream>>>(h1, N, s1, q1, g[1], be[1], W1, b1, y, sf, qf, ngroups16);
    final_k<<<(int)(((size_t)N * 64 + 255) / 256), 256, 0, stream>>>(
        y, N, sf, qf, gf, bf, W2, b2, (float*)d_out);
}

// Round 8
// 394.956 us; speedup vs baseline: 4.7264x; 1.0071x over previous
//
#include <hip/hip_runtime.h>
#include <hip/hip_bf16.h>
#include <cmath>

#define HC 64
typedef __hip_bfloat16 bf16;
typedef unsigned int uint;
typedef float v4f __attribute__((ext_vector_type(4)));

__device__ __forceinline__ uint pack_bf2(float a, float b) {
    __hip_bfloat162 h = __float22bfloat162_rn(make_float2(a, b));
    return *reinterpret_cast<uint*>(&h);
}
__device__ __forceinline__ float bfl(uint u) { return __uint_as_float(u << 16); }
__device__ __forceinline__ float bfh(uint u) { return __uint_as_float(u & 0xffff0000u); }

// ---------------- coarse bucket histogram (dst>>7), LDS-aggregated ----------------

__global__ __launch_bounds__(512) void bucket_hist_k(const int* __restrict__ dst,
                                                     int* __restrict__ bcnt, int E, int nbk) {
    __shared__ int lh[512];
    int t = threadIdx.x;
    for (int i = t; i < nbk; i += 512) lh[i] = 0;
    __syncthreads();
    int base = blockIdx.x * 8192;
#pragma unroll
    for (int k = 0; k < 16; ++k) {
        int e = base + k * 512 + t;
        if (e < E) atomicAdd(&lh[dst[e] >> 7], 1);
    }
    __syncthreads();
    for (int i = t; i < nbk; i += 512) if (lh[i]) atomicAdd(&bcnt[i], lh[i]);
}

// ---------------- scan over nbk (<=512) buckets ----------------

__global__ __launch_bounds__(512) void bucket_scan_k(const int* __restrict__ bcnt,
                                                     int* __restrict__ bstart,
                                                     int* __restrict__ bcur, int nbk, int E) {
    __shared__ int tmp[512];
    int t = threadIdx.x;
    int v = (t < nbk) ? bcnt[t] : 0;
    tmp[t] = v;
    __syncthreads();
    for (int off = 1; off < 512; off <<= 1) {
        int a = (t >= off) ? tmp[t - off] : 0;
        __syncthreads();
        tmp[t] += a;
        __syncthreads();
    }
    if (t < nbk) { int ex = tmp[t] - v; bstart[t] = ex; bcur[t] = ex; }
    if (t == 0) bstart[nbk] = E;
}

// ---------------- grouping: append 12B records into coarse bucket regions ----------------

__global__ __launch_bounds__(1024) void bucketA_k(
        const int* __restrict__ src, const int* __restrict__ dst,
        const float4* __restrict__ eattr, int* __restrict__ bcur,
        uint* __restrict__ tsd, uint2* __restrict__ tea, int E, int nbk) {
    __shared__ int lcnt[512];
    __shared__ int lbase[512];
    int t = threadIdx.x;
    for (int i = t; i < nbk; i += 1024) lcnt[i] = 0;
    __syncthreads();
    int base = blockIdx.x * 8192;
    int myb[8], mylp[8];
#pragma unroll
    for (int k = 0; k < 8; ++k) {
        int e = base + k * 1024 + t;
        if (e < E) {
            int b = dst[e] >> 7;
            myb[k] = b;
            mylp[k] = atomicAdd(&lcnt[b], 1);
        } else myb[k] = -1;
    }
    __syncthreads();
    for (int i = t; i < nbk; i += 1024) {
        int cc = lcnt[i];
        lbase[i] = cc ? atomicAdd(&bcur[i], cc) : 0;
    }
    __syncthreads();
#pragma unroll
    for (int k = 0; k < 8; ++k) {
        int e = base + k * 1024 + t;
        if (e >= E) continue;
        int pos = lbase[myb[k]] + mylp[k];
        int d = dst[e];
        tsd[pos] = (uint)src[e] | ((uint)(d & 127) << 25);
        float4 ea = eattr[e];
        tea[pos] = make_uint2(pack_bf2(ea.x, ea.y), pack_bf2(ea.z, ea.w));
    }
}

// ---------------- in-LDS counting sort per bucket -> exact CSR ----------------

__global__ __launch_bounds__(256) void bucket_sort_k(
        const uint* __restrict__ tsd, const uint2* __restrict__ tea,
        const int* __restrict__ bstart,
        uint* __restrict__ spre_sorted, uint2* __restrict__ eat_sorted,
        int* __restrict__ row_start, int n) {
    __shared__ int cnt[128], pfx[128], cur[128];
    int b = blockIdx.x, t = threadIdx.x;
    int i0 = bstart[b], i1 = bstart[b + 1];
    int node0 = b << 7;
    if (t < 128) cnt[t] = 0;
    __syncthreads();
    for (int i = i0 + t; i < i1; i += 256) atomicAdd(&cnt[tsd[i] >> 25], 1);
    __syncthreads();
    if (t < 128) pfx[t] = cnt[t];
    __syncthreads();
    for (int off = 1; off < 128; off <<= 1) {
        int a = (t < 128 && t >= off) ? pfx[t - off] : 0;
        __syncthreads();
        if (t < 128) pfx[t] += a;
        __syncthreads();
    }
    if (t < 128) {
        int ex = pfx[t] - cnt[t];
        cur[t] = ex;
        if (node0 + t <= n) row_start[node0 + t] = i0 + ex;
    }
    __syncthreads();
    for (int i = i0 + t; i < i1; i += 256) {
        uint u = tsd[i];
        int dl = (int)(u >> 25);
        int pos = i0 + atomicAdd(&cur[dl], 1);
        spre_sorted[pos] = (u & 0x1FFFFFFu) << 7;   // byte offset into xl rows
        eat_sorted[pos] = tea[i];
    }
}

// ---------------- layer-0 linear: din=128, 16 nodes/block (4/thread) ----------------

__global__ __launch_bounds__(256) void lin128_k(
        const float* __restrict__ x, int n,
        const float* __restrict__ Wl, const float* __restrict__ bl,
        const float* __restrict__ Wr, const float* __restrict__ br,
        bf16* __restrict__ xl, bf16* __restrict__ xr, int ngroups16) {
    __shared__ float2 sWl2[64 * 64];
    __shared__ float2 sWr2[64 * 64];
    __shared__ float sx[16 * 128];
    int t = threadIdx.x;
    for (int i = t; i < 64 * 64; i += 256) {
        int k2 = i >> 6, c = i & 63;
        sWl2[i] = make_float2(Wl[(2 * k2) * 64 + c], Wl[(2 * k2 + 1) * 64 + c]);
        sWr2[i] = make_float2(Wr[(2 * k2) * 64 + c], Wr[(2 * k2 + 1) * 64 + c]);
    }
    int c = t & 63, w = t >> 6;
    float blc = bl[c], brc = br[c];
    for (int gidx = blockIdx.x; gidx < ngroups16; gidx += gridDim.x) {
        int node0 = gidx * 16;
        __syncthreads();
        for (int i = t; i < 16 * 128; i += 256) {
            int r = node0 + (i >> 7);
            sx[i] = (r < n) ? x[(size_t)r * 128 + (i & 127)] : 0.f;
        }
        __syncthreads();
        float al0 = blc, al1 = blc, al2 = blc, al3 = blc;
        float ar0 = brc, ar1 = brc, ar2 = brc, ar3 = brc;
        const float* sx0 = sx + w * 4 * 128;
#pragma unroll 8
        for (int k2 = 0; k2 < 64; ++k2) {
            float2 wl = sWl2[k2 * 64 + c], wr = sWr2[k2 * 64 + c];
            float2 xa = *(const float2*)&sx0[k2 * 2];
            float2 xb = *(const float2*)&sx0[128 + k2 * 2];
            float2 xc = *(const float2*)&sx0[256 + k2 * 2];
            float2 xd = *(const float2*)&sx0[384 + k2 * 2];
            al0 = fmaf(xa.x, wl.x, al0); al0 = fmaf(xa.y, wl.y, al0);
            ar0 = fmaf(xa.x, wr.x, ar0); ar0 = fmaf(xa.y, wr.y, ar0);
            al1 = fmaf(xb.x, wl.x, al1); al1 = fmaf(xb.y, wl.y, al1);
            ar1 = fmaf(xb.x, wr.x, ar1); ar1 = fmaf(xb.y, wr.y, ar1);
            al2 = fmaf(xc.x, wl.x, al2); al2 = fmaf(xc.y, wl.y, al2);
            ar2 = fmaf(xc.x, wr.x, ar2); ar2 = fmaf(xc.y, wr.y, ar2);
            al3 = fmaf(xd.x, wl.x, al3); al3 = fmaf(xd.y, wl.y, al3);
            ar3 = fmaf(xd.x, wr.x, ar3); ar3 = fmaf(xd.y, wr.y, ar3);
        }
        int nb_ = node0 + w * 4;
        if (nb_ + 0 < n) { xl[(size_t)(nb_ + 0) * 64 + c] = __float2bfloat16(al0); xr[(size_t)(nb_ + 0) * 64 + c] = __float2bfloat16(ar0); }
        if (nb_ + 1 < n) { xl[(size_t)(nb_ + 1) * 64 + c] = __float2bfloat16(al1); xr[(size_t)(nb_ + 1) * 64 + c] = __float2bfloat16(ar1); }
        if (nb_ + 2 < n) { xl[(size_t)(nb_ + 2) * 64 + c] = __float2bfloat16(al2); xr[(size_t)(nb_ + 2) * 64 + c] = __float2bfloat16(ar2); }
        if (nb_ + 3 < n) { xl[(size_t)(nb_ + 3) * 64 + c] = __float2bfloat16(al3); xr[(size_t)(nb_ + 3) * 64 + c] = __float2bfloat16(ar3); }
    }
}

// ---------------- layer-1 linear: din=64, fused input BN+ELU ----------------

__global__ __launch_bounds__(256) void lin64bn_k(
        const float* __restrict__ x, int n,
        const float* __restrict__ sums, const float* __restrict__ sqs,
        const float* __restrict__ g, const float* __restrict__ be,
        const float* __restrict__ Wl, const float* __restrict__ bl,
        const float* __restrict__ Wr, const float* __restrict__ br,
        bf16* __restrict__ xl, bf16* __restrict__ xr, int ngroups16) {
    __shared__ float2 sWl2[32 * 64];
    __shared__ float2 sWr2[32 * 64];
    __shared__ float sx[16 * 64];
    __shared__ float ssc[64], ssh[64];
    int t = threadIdx.x;
    if (t < 64) {
        float inv_n = 1.f / n;
        float mu = sums[t] * inv_n;
        float var = sqs[t] * inv_n - mu * mu;
        float sc = rsqrtf(var + 1e-5f) * g[t];
        ssc[t] = sc; ssh[t] = be[t] - mu * sc;
    }
    for (int i = t; i < 32 * 64; i += 256) {
        int k2 = i >> 6, c = i & 63;
        sWl2[i] = make_float2(Wl[(2 * k2) * 64 + c], Wl[(2 * k2 + 1) * 64 + c]);
        sWr2[i] = make_float2(Wr[(2 * k2) * 64 + c], Wr[(2 * k2 + 1) * 64 + c]);
    }
    int c = t & 63, w = t >> 6;
    float blc = bl[c], brc = br[c];
    for (int gidx = blockIdx.x; gidx < ngroups16; gidx += gridDim.x) {
        int node0 = gidx * 16;
        __syncthreads();
        for (int i = t; i < 16 * 64; i += 256) {
            int r = node0 + (i >> 6);
            float v = (r < n) ? x[(size_t)r * 64 + (i & 63)] : 0.f;
            v = v * ssc[i & 63] + ssh[i & 63];
            sx[i] = v > 0.f ? v : __expf(v) - 1.f;
        }
        __syncthreads();
        float al0 = blc, al1 = blc, al2 = blc, al3 = blc;
        float ar0 = brc, ar1 = brc, ar2 = brc, ar3 = brc;
        const float* sx0 = sx + w * 4 * 64;
#pragma unroll 8
        for (int k2 = 0; k2 < 32; ++k2) {
            float2 wl = sWl2[k2 * 64 + c], wr = sWr2[k2 * 64 + c];
            float2 xa = *(const float2*)&sx0[k2 * 2];
            float2 xb = *(const float2*)&sx0[64 + k2 * 2];
            float2 xc = *(const float2*)&sx0[128 + k2 * 2];
            float2 xd = *(const float2*)&sx0[192 + k2 * 2];
            al0 = fmaf(xa.x, wl.x, al0); al0 = fmaf(xa.y, wl.y, al0);
            ar0 = fmaf(xa.x, wr.x, ar0); ar0 = fmaf(xa.y, wr.y, ar0);
            al1 = fmaf(xb.x, wl.x, al1); al1 = fmaf(xb.y, wl.y, al1);
            ar1 = fmaf(xb.x, wr.x, ar1); ar1 = fmaf(xb.y, wr.y, ar1);
            al2 = fmaf(xc.x, wl.x, al2); al2 = fmaf(xc.y, wl.y, al2);
            ar2 = fmaf(xc.x, wr.x, ar2); ar2 = fmaf(xc.y, wr.y, ar2);
            al3 = fmaf(xd.x, wl.x, al3); al3 = fmaf(xd.y, wl.y, al3);
            ar3 = fmaf(xd.x, wr.x, ar3); ar3 = fmaf(xd.y, wr.y, ar3);
        }
        int nb_ = node0 + w * 4;
        if (nb_ + 0 < n) { xl[(size_t)(nb_ + 0) * 64 + c] = __float2bfloat16(al0); xr[(size_t)(nb_ + 0) * 64 + c] = __float2bfloat16(ar0); }
        if (nb_ + 1 < n) { xl[(size_t)(nb_ + 1) * 64 + c] = __float2bfloat16(al1); xr[(size_t)(nb_ + 1) * 64 + c] = __float2bfloat16(ar1); }
        if (nb_ + 2 < n) { xl[(size_t)(nb_ + 2) * 64 + c] = __float2bfloat16(al2); xr[(size_t)(nb_ + 2) * 64 + c] = __float2bfloat16(ar2); }
        if (nb_ + 3 < n) { xl[(size_t)(nb_ + 3) * 64 + c] = __float2bfloat16(al3); xr[(size_t)(nb_ + 3) * 64 + c] = __float2bfloat16(ar3); }
    }
}

// ---------------- fused GAT: wave per node, 4 channels/lane, 4 edges/wave ----------------

__global__ __launch_bounds__(256) void gat_node_k(
        const bf16* __restrict__ xl, const bf16* __restrict__ xr,
        const float* __restrict__ We, const float* __restrict__ att,
        const int* __restrict__ row_start, const uint* __restrict__ spre,
        const uint2* __restrict__ eat,
        float* __restrict__ out, int n) {
    int t = threadIdx.x;
    int lane = t & 63;
    int quad = lane >> 4;          // edge slot 0..3
    int c4 = lane & 15;            // channel group: channels 4*c4 .. 4*c4+3
    int node = blockIdx.x * 4 + (t >> 6);
    if (node >= n) return;
    int c0 = c4 << 2;
    v4f w0 = {We[c0], We[c0 + 1], We[c0 + 2], We[c0 + 3]};
    v4f w1 = {We[64 + c0], We[64 + c0 + 1], We[64 + c0 + 2], We[64 + c0 + 3]};
    v4f w2 = {We[128 + c0], We[128 + c0 + 1], We[128 + c0 + 2], We[128 + c0 + 3]};
    v4f w3 = {We[192 + c0], We[192 + c0 + 1], We[192 + c0 + 2], We[192 + c0 + 3]};
    v4f ratt = {att[c0] * 1.44269504f, att[c0 + 1] * 1.44269504f,
                att[c0 + 2] * 1.44269504f, att[c0 + 3] * 1.44269504f};
    const char* xlb = (const char*)xl;
    uint2 xru = *(const uint2*)((const char*)xr + ((size_t)node << 7) + ((uint)c0 << 1));
    v4f xrd = {bfl(xru.x), bfh(xru.x), bfl(xru.y), bfh(xru.y)};
    int rs = row_start[node], re = row_start[node + 1];
    v4f acc = {0.f, 0.f, 0.f, 0.f};
    float srun = 0.f;
    uint coff = (uint)c4 << 3;   // 4 channels * 2B

#define PROC(EA, XU) { \
        v4f xv = {bfl((XU).x), bfh((XU).x), bfl((XU).y), bfh((XU).y)}; \
        v4f z = xv + xrd; \
        float e0 = bfl((EA).x), e1 = bfh((EA).x); \
        float e2 = bfl((EA).y), e3 = bfh((EA).y); \
        z += e0 * w0; z += e1 * w1; z += e2 * w2; z += e3 * w3; \
        z = __builtin_elementwise_max(z, 0.2f * z); \
        v4f zr = z * ratt; \
        float v = (zr.x + zr.y) + (zr.z + zr.w); \
        v += __shfl_xor(v, 1); v += __shfl_xor(v, 2); \
        float p = exp2f(v); \
        srun += p; \
        acc += p * xv; \
    }

    int i = rs;
    for (; i + 8 <= re; i += 8) {
        uint spA = spre[i + quad], spB = spre[i + 4 + quad];
        uint2 eaA = eat[i + quad], eaB = eat[i + 4 + quad];
        uint2 xuA = *(const uint2*)(xlb + spA + coff);
        uint2 xuB = *(const uint2*)(xlb + spB + coff);
        PROC(eaA, xuA);
        PROC(eaB, xuB);
    }
    for (; i < re; i += 4) {
        int ei = i + quad;
        bool ok = ei < re;
        int eic = ok ? ei : i;
        uint sp = spre[eic];
        uint2 ea = eat[eic];
        uint2 xu = *(const uint2*)(xlb + sp + coff);
        v4f xv = {bfl(xu.x), bfh(xu.x), bfl(xu.y), bfh(xu.y)};
        v4f z = xv + xrd;
        float e0 = bfl(ea.x), e1 = bfh(ea.x);
        float e2 = bfl(ea.y), e3 = bfh(ea.y);
        z += e0 * w0; z += e1 * w1; z += e2 * w2; z += e3 * w3;
        z = __builtin_elementwise_max(z, 0.2f * z);
        v4f zr = z * ratt;
        float v = (zr.x + zr.y) + (zr.z + zr.w);
        v += __shfl_xor(v, 1); v += __shfl_xor(v, 2);
        float p = ok ? exp2f(v) : 0.f;
        srun += p;
        acc += p * xv;
    }
#undef PROC

    // merge the 4 quads
    srun += __shfl_xor(srun, 16);  srun += __shfl_xor(srun, 32);
    acc.x += __shfl_xor(acc.x, 16); acc.x += __shfl_xor(acc.x, 32);
    acc.y += __shfl_xor(acc.y, 16); acc.y += __shfl_xor(acc.y, 32);
    acc.z += __shfl_xor(acc.z, 16); acc.z += __shfl_xor(acc.z, 32);
    acc.w += __shfl_xor(acc.w, 16); acc.w += __shfl_xor(acc.w, 32);
    if (quad == 0) {
        float inv = 1.f / (srun + 1e-16f);
        v4f o = acc * inv;
        *(v4f*)&out[((size_t)node << 6) + (uint)c0] = o;
    }
}

// ---------------- BN stats ----------------

__global__ void bn_stats_k(const float* __restrict__ x, float* __restrict__ sums,
                           float* __restrict__ sqs, int n) {
    __shared__ float ls[256], lq[256];
    int t = threadIdx.x;
    int c = t & 63, sub = t >> 6;
    float s = 0.f, q = 0.f;
    for (int r = blockIdx.x * 4 + sub; r < n; r += gridDim.x * 4) {
        float v = x[(size_t)r * 64 + c];
        s += v;
        q = fmaf(v, v, q);
    }
    ls[t] = s; lq[t] = q;
    __syncthreads();
    if (t < 128) { ls[t] += ls[t + 128]; lq[t] += lq[t + 128]; }
    __syncthreads();
    if (t < 64) {
        atomicAdd(&sums[c], ls[t] + ls[t + 64]);
        atomicAdd(&sqs[c], lq[t] + lq[t + 64]);
    }
}

// ---------------- head fc 64->64 (fused input BN+ELU, fused output stats) ----------------

__global__ __launch_bounds__(256) void lin1_k(
        const float* __restrict__ x, int n,
        const float* __restrict__ sums, const float* __restrict__ sqs,
        const float* __restrict__ g, const float* __restrict__ be,
        const float* __restrict__ W, const float* __restrict__ b,
        float* __restrict__ y, float* __restrict__ sums_o, float* __restrict__ sqs_o,
        int ngroups16) {
    __shared__ float2 sW2[32 * 64];
    __shared__ float sx[16 * 64];
    __shared__ float ssc[64], ssh[64];
    __shared__ float ls[256], lq[256];
    int t = threadIdx.x;
    if (t < 64) {
        float inv_n = 1.f / n;
        float mu = sums[t] * inv_n;
        float var = sqs[t] * inv_n - mu * mu;
        float sc = rsqrtf(var + 1e-5f) * g[t];
        ssc[t] = sc; ssh[t] = be[t] - mu * sc;
    }
    for (int i = t; i < 32 * 64; i += 256) {
        int k2 = i >> 6, c = i & 63;
        sW2[i] = make_float2(W[(2 * k2) * 64 + c], W[(2 * k2 + 1) * 64 + c]);
    }
    int c = t & 63, w = t >> 6;
    float bc = b[c];
    float s = 0.f, q = 0.f;
    for (int gidx = blockIdx.x; gidx < ngroups16; gidx += gridDim.x) {
        int node0 = gidx * 16;
        __syncthreads();
        for (int i = t; i < 16 * 64; i += 256) {
            int r = node0 + (i >> 6);
            float v = (r < n) ? x[(size_t)r * 64 + (i & 63)] : 0.f;
            v = v * ssc[i & 63] + ssh[i & 63];
            sx[i] = v > 0.f ? v : __expf(v) - 1.f;
        }
        __syncthreads();
        float a0 = bc, a1 = bc, a2 = bc, a3 = bc;
        const float* sx0 = sx + w * 4 * 64;
#pragma unroll 8
        for (int k2 = 0; k2 < 32; ++k2) {
            float2 wv = sW2[k2 * 64 + c];
            float2 xa = *(const float2*)&sx0[k2 * 2];
            float2 xb = *(const float2*)&sx0[64 + k2 * 2];
            float2 xc = *(const float2*)&sx0[128 + k2 * 2];
            float2 xd = *(const float2*)&sx0[192 + k2 * 2];
            a0 = fmaf(xa.x, wv.x, a0); a0 = fmaf(xa.y, wv.y, a0);
            a1 = fmaf(xb.x, wv.x, a1); a1 = fmaf(xb.y, wv.y, a1);
            a2 = fmaf(xc.x, wv.x, a2); a2 = fmaf(xc.y, wv.y, a2);
            a3 = fmaf(xd.x, wv.x, a3); a3 = fmaf(xd.y, wv.y, a3);
        }
        int nb_ = node0 + w * 4;
        if (nb_ + 0 < n) { y[(size_t)(nb_ + 0) * 64 + c] = a0; s += a0; q = fmaf(a0, a0, q); }
        if (nb_ + 1 < n) { y[(size_t)(nb_ + 1) * 64 + c] = a1; s += a1; q = fmaf(a1, a1, q); }
        if (nb_ + 2 < n) { y[(size_t)(nb_ + 2) * 64 + c] = a2; s += a2; q = fmaf(a2, a2, q); }
        if (nb_ + 3 < n) { y[(size_t)(nb_ + 3) * 64 + c] = a3; s += a3; q = fmaf(a3, a3, q); }
    }
    __syncthreads();
    ls[t] = s; lq[t] = q;
    __syncthreads();
    if (t < 64) {
        float ss = ls[t] + ls[t + 64] + ls[t + 128] + ls[t + 192];
        float qq = lq[t] + lq[t + 64] + lq[t + 128] + lq[t + 192];
        atomicAdd(&sums_o[t], ss);
        atomicAdd(&sqs_o[t], qq);
    }
}

// ---------------- final: fused BN+ELU + dot(64) + 5*tanh ----------------

__global__ void final_k(const float* __restrict__ z, int n,
                        const float* __restrict__ sums, const float* __restrict__ sqs,
                        const float* __restrict__ g, const float* __restrict__ be,
                        const float* __restrict__ W2, const float* __restrict__ b2,
                        float* __restrict__ out) {
    int t = blockIdx.x * blockDim.x + threadIdx.x;
    int node = t >> 6, c = t & 63;
    if (node >= n) return;
    float inv_n = 1.f / n;
    float mu = sums[c] * inv_n;
    float var = sqs[c] * inv_n - mu * mu;
    float scc = rsqrtf(var + 1e-5f) * g[c];
    float sh = be[c] - mu * scc;
    float v = z[(size_t)node * 64 + c] * scc + sh;
    v = v > 0.f ? v : __expf(v) - 1.f;
    v *= W2[c];
    v += __shfl_xor(v, 1);
    v += __shfl_xor(v, 2);
    v += __shfl_xor(v, 4);
    v += __shfl_xor(v, 8);
    v += __shfl_xor(v, 16);
    v += __shfl_xor(v, 32);
    if (c == 0) out[node] = 5.0f * tanhf(v + b2[0]);
}

// ---------------- launch ----------------

extern "C" void kernel_launch(void* const* d_in, const int* in_sizes, int n_in,
                              void* d_out, int out_size, void* d_ws, size_t ws_size,
                              hipStream_t stream) {
    const float* x0    = (const float*)d_in[0];
    const int*   eidx  = (const int*)d_in[1];
    const float* eattr = (const float*)d_in[2];

    const float* Wl[2]; const float* bl[2]; const float* Wr[2]; const float* br[2];
    const float* We[2]; const float* att[2]; const float* g[2]; const float* be[2];
    for (int l = 0; l < 2; ++l) {
        int base = 3 + l * 9;
        Wl[l]  = (const float*)d_in[base + 0];
        bl[l]  = (const float*)d_in[base + 1];
        Wr[l]  = (const float*)d_in[base + 2];
        br[l]  = (const float*)d_in[base + 3];
        We[l]  = (const float*)d_in[base + 4];
        att[l] = (const float*)d_in[base + 5];
        // base+6 = bias: per-channel constant, cancels exactly under BatchNorm
        g[l]   = (const float*)d_in[base + 7];
        be[l]  = (const float*)d_in[base + 8];
    }
    const float* W1 = (const float*)d_in[21];
    const float* b1 = (const float*)d_in[22];
    const float* gf = (const float*)d_in[23];
    const float* bf = (const float*)d_in[24];
    const float* W2 = (const float*)d_in[25];
    const float* b2 = (const float*)d_in[26];

    const int N = in_sizes[0] / 128;
    const int E = in_sizes[1] / 2;
    const int* src = eidx;
    const int* dst = eidx + E;
    const int nbk = (N + 127) >> 7;

    // workspace (4-byte units).  Region A shared: (tea,tsd) then (h0,h1).
    float* ws = (float*)d_ws;
    size_t o = 0;
    float* regionA = ws + o; o += (size_t)2 * N * HC;         // >= E*3 units
    uint2* tea = (uint2*)regionA;
    uint*  tsd = (uint*)(regionA + (size_t)2 * E);
    float* h0  = regionA;
    float* h1  = regionA + (size_t)N * HC;
    uint2* eat_sorted = (uint2*)(ws + o); o += (size_t)E * 2;
    uint*  spre_sorted = (uint*)(ws + o);  o += (size_t)E;
    bf16*  xl  = (bf16*)(ws + o);  o += (size_t)N * 32;
    bf16*  xr  = (bf16*)(ws + o);  o += (size_t)N * 32;
    int*   row_start = (int*)(ws + o); o += (size_t)N + 1;
    // bcnt and stats adjacent -> single memset
    int*   bcnt   = (int*)(ws + o); o += 512;
    float* stats  = ws + o; o += 6 * HC;
    int*   bstart = (int*)(ws + o); o += 513;
    int*   bcur   = (int*)(ws + o); o += 512;
    float* s0 = stats,        *q0 = stats + 64;
    float* s1 = stats + 128,  *q1 = stats + 192;
    float* sf = stats + 256,  *qf = stats + 320;

    const int ngroups4  = (N + 3) / 4;
    const int ngroups16 = (N + 15) / 16;
    const int EB = (E + 8191) / 8192;

    hipMemsetAsync(bcnt, 0, (512 + 6 * HC) * 4, stream);

    // CSR build: coarse bucket + in-LDS counting sort (shared by both layers)
    bucket_hist_k<<<EB, 512, 0, stream>>>(dst, bcnt, E, nbk);
    bucket_scan_k<<<1, 512, 0, stream>>>(bcnt, bstart, bcur, nbk, E);
    bucketA_k<<<EB, 1024, 0, stream>>>(src, dst, (const float4*)eattr, bcur, tsd, tea, E, nbk);
    bucket_sort_k<<<nbk, 256, 0, stream>>>(tsd, tea, bstart, spre_sorted, eat_sorted,
                                           row_start, N);

    // layer 0  (h0 overwrites regionA only after tsd/tea are consumed)
    lin128_k<<<512, 256, 0, stream>>>(x0, N, Wl[0], bl[0], Wr[0], br[0], xl, xr, ngroups16);
    gat_node_k<<<ngroups4, 256, 0, stream>>>(xl, xr, We[0], att[0], row_start,
                                             spre_sorted, eat_sorted, h0, N);
    bn_stats_k<<<256, 256, 0, stream>>>(h0, s0, q0, N);

    // layer 1 (input BN+ELU fused)
    lin64bn_k<<<512, 256, 0, stream>>>(h0, N, s0, q0, g[0], be[0],
                                       Wl[1], bl[1], Wr[1], br[1], xl, xr, ngroups16);
    gat_node_k<<<ngroups4, 256, 0, stream>>>(xl, xr, We[1], att[1], row_start,
                                             spre_sorted, eat_sorted, h1, N);
    bn_stats_k<<<256, 256, 0, stream>>>(h1, s1, q1, N);

    // head
    float* y = h0;  // h0 dead after lin64bn
    lin1_k<<<512, 256, 0, stream>>>(h1, N, s1, q1, g[1], be[1], W1, b1, y, sf, qf, ngroups16);
    final_k<<<(int)(((size_t)N * 64 + 255) / 256), 256, 0, stream>>>(
        y, N, sf, qf, gf, bf, W2, b2, (float*)d_out);
}

// Round 9
// 370.332 us; speedup vs baseline: 5.0407x; 1.0665x over previous
//
#include <hip/hip_runtime.h>
#include <hip/hip_bf16.h>
#include <cmath>

#define HC 64
typedef __hip_bfloat16 bf16;
typedef unsigned int uint;
typedef float v4f __attribute__((ext_vector_type(4)));

__device__ __forceinline__ uint pack_bf2(float a, float b) {
    __hip_bfloat162 h = __float22bfloat162_rn(make_float2(a, b));
    return *reinterpret_cast<uint*>(&h);
}
__device__ __forceinline__ float bfl(uint u) { return __uint_as_float(u << 16); }
__device__ __forceinline__ float bfh(uint u) { return __uint_as_float(u & 0xffff0000u); }

// ---------------- coarse bucket histogram (dst>>7), LDS-aggregated ----------------

__global__ __launch_bounds__(512) void bucket_hist_k(const int* __restrict__ dst,
                                                     int* __restrict__ bcnt, int E, int nbk) {
    __shared__ int lh[512];
    int t = threadIdx.x;
    for (int i = t; i < nbk; i += 512) lh[i] = 0;
    __syncthreads();
    int base = blockIdx.x * 8192;
#pragma unroll
    for (int k = 0; k < 16; ++k) {
        int e = base + k * 512 + t;
        if (e < E) atomicAdd(&lh[dst[e] >> 7], 1);
    }
    __syncthreads();
    for (int i = t; i < nbk; i += 512) if (lh[i]) atomicAdd(&bcnt[i], lh[i]);
}

// ---------------- scan over nbk (<=512) buckets ----------------

__global__ __launch_bounds__(512) void bucket_scan_k(const int* __restrict__ bcnt,
                                                     int* __restrict__ bstart,
                                                     int* __restrict__ bcur, int nbk, int E) {
    __shared__ int tmp[512];
    int t = threadIdx.x;
    int v = (t < nbk) ? bcnt[t] : 0;
    tmp[t] = v;
    __syncthreads();
    for (int off = 1; off < 512; off <<= 1) {
        int a = (t >= off) ? tmp[t - off] : 0;
        __syncthreads();
        tmp[t] += a;
        __syncthreads();
    }
    if (t < nbk) { int ex = tmp[t] - v; bstart[t] = ex; bcur[t] = ex; }
    if (t == 0) bstart[nbk] = E;
}

// ---------------- grouping: append 12B records into coarse bucket regions ----------------

__global__ __launch_bounds__(1024) void bucketA_k(
        const int* __restrict__ src, const int* __restrict__ dst,
        const float4* __restrict__ eattr, int* __restrict__ bcur,
        uint* __restrict__ tsd, uint2* __restrict__ tea, int E, int nbk) {
    __shared__ int lcnt[512];
    __shared__ int lbase[512];
    int t = threadIdx.x;
    for (int i = t; i < nbk; i += 1024) lcnt[i] = 0;
    __syncthreads();
    int base = blockIdx.x * 8192;
    int myb[8], mylp[8];
#pragma unroll
    for (int k = 0; k < 8; ++k) {
        int e = base + k * 1024 + t;
        if (e < E) {
            int b = dst[e] >> 7;
            myb[k] = b;
            mylp[k] = atomicAdd(&lcnt[b], 1);
        } else myb[k] = -1;
    }
    __syncthreads();
    for (int i = t; i < nbk; i += 1024) {
        int cc = lcnt[i];
        lbase[i] = cc ? atomicAdd(&bcur[i], cc) : 0;
    }
    __syncthreads();
#pragma unroll
    for (int k = 0; k < 8; ++k) {
        int e = base + k * 1024 + t;
        if (e >= E) continue;
        int pos = lbase[myb[k]] + mylp[k];
        int d = dst[e];
        tsd[pos] = (uint)src[e] | ((uint)(d & 127) << 25);
        float4 ea = eattr[e];
        tea[pos] = make_uint2(pack_bf2(ea.x, ea.y), pack_bf2(ea.z, ea.w));
    }
}

// ---------------- in-LDS counting sort per bucket -> exact CSR ----------------

__global__ __launch_bounds__(256) void bucket_sort_k(
        const uint* __restrict__ tsd, const uint2* __restrict__ tea,
        const int* __restrict__ bstart,
        uint* __restrict__ spre_sorted, uint2* __restrict__ eat_sorted,
        int* __restrict__ row_start, int n) {
    __shared__ int cnt[128], pfx[128], cur[128];
    int b = blockIdx.x, t = threadIdx.x;
    int i0 = bstart[b], i1 = bstart[b + 1];
    int node0 = b << 7;
    if (t < 128) cnt[t] = 0;
    __syncthreads();
    for (int i = i0 + t; i < i1; i += 256) atomicAdd(&cnt[tsd[i] >> 25], 1);
    __syncthreads();
    if (t < 128) pfx[t] = cnt[t];
    __syncthreads();
    for (int off = 1; off < 128; off <<= 1) {
        int a = (t < 128 && t >= off) ? pfx[t - off] : 0;
        __syncthreads();
        if (t < 128) pfx[t] += a;
        __syncthreads();
    }
    if (t < 128) {
        int ex = pfx[t] - cnt[t];
        cur[t] = ex;
        if (node0 + t <= n) row_start[node0 + t] = i0 + ex;
    }
    __syncthreads();
    for (int i = i0 + t; i < i1; i += 256) {
        uint u = tsd[i];
        int dl = (int)(u >> 25);
        int pos = i0 + atomicAdd(&cur[dl], 1);
        spre_sorted[pos] = (u & 0x1FFFFFFu) << 7;   // byte offset into xl rows
        eat_sorted[pos] = tea[i];
    }
}

// ---------------- layer-0 linear: din=128, 16 nodes/block (4/thread) ----------------

__global__ __launch_bounds__(256) void lin128_k(
        const float* __restrict__ x, int n,
        const float* __restrict__ Wl, const float* __restrict__ bl,
        const float* __restrict__ Wr, const float* __restrict__ br,
        bf16* __restrict__ xl, bf16* __restrict__ xr, int ngroups16) {
    __shared__ float2 sWl2[64 * 64];
    __shared__ float2 sWr2[64 * 64];
    __shared__ float sx[16 * 128];
    int t = threadIdx.x;
    for (int i = t; i < 64 * 64; i += 256) {
        int k2 = i >> 6, c = i & 63;
        sWl2[i] = make_float2(Wl[(2 * k2) * 64 + c], Wl[(2 * k2 + 1) * 64 + c]);
        sWr2[i] = make_float2(Wr[(2 * k2) * 64 + c], Wr[(2 * k2 + 1) * 64 + c]);
    }
    int c = t & 63, w = t >> 6;
    float blc = bl[c], brc = br[c];
    for (int gidx = blockIdx.x; gidx < ngroups16; gidx += gridDim.x) {
        int node0 = gidx * 16;
        __syncthreads();
        for (int i = t; i < 16 * 128; i += 256) {
            int r = node0 + (i >> 7);
            sx[i] = (r < n) ? x[(size_t)r * 128 + (i & 127)] : 0.f;
        }
        __syncthreads();
        float al0 = blc, al1 = blc, al2 = blc, al3 = blc;
        float ar0 = brc, ar1 = brc, ar2 = brc, ar3 = brc;
        const float* sx0 = sx + w * 4 * 128;
#pragma unroll 8
        for (int k2 = 0; k2 < 64; ++k2) {
            float2 wl = sWl2[k2 * 64 + c], wr = sWr2[k2 * 64 + c];
            float2 xa = *(const float2*)&sx0[k2 * 2];
            float2 xb = *(const float2*)&sx0[128 + k2 * 2];
            float2 xc = *(const float2*)&sx0[256 + k2 * 2];
            float2 xd = *(const float2*)&sx0[384 + k2 * 2];
            al0 = fmaf(xa.x, wl.x, al0); al0 = fmaf(xa.y, wl.y, al0);
            ar0 = fmaf(xa.x, wr.x, ar0); ar0 = fmaf(xa.y, wr.y, ar0);
            al1 = fmaf(xb.x, wl.x, al1); al1 = fmaf(xb.y, wl.y, al1);
            ar1 = fmaf(xb.x, wr.x, ar1); ar1 = fmaf(xb.y, wr.y, ar1);
            al2 = fmaf(xc.x, wl.x, al2); al2 = fmaf(xc.y, wl.y, al2);
            ar2 = fmaf(xc.x, wr.x, ar2); ar2 = fmaf(xc.y, wr.y, ar2);
            al3 = fmaf(xd.x, wl.x, al3); al3 = fmaf(xd.y, wl.y, al3);
            ar3 = fmaf(xd.x, wr.x, ar3); ar3 = fmaf(xd.y, wr.y, ar3);
        }
        int nb_ = node0 + w * 4;
        if (nb_ + 0 < n) { xl[(size_t)(nb_ + 0) * 64 + c] = __float2bfloat16(al0); xr[(size_t)(nb_ + 0) * 64 + c] = __float2bfloat16(ar0); }
        if (nb_ + 1 < n) { xl[(size_t)(nb_ + 1) * 64 + c] = __float2bfloat16(al1); xr[(size_t)(nb_ + 1) * 64 + c] = __float2bfloat16(ar1); }
        if (nb_ + 2 < n) { xl[(size_t)(nb_ + 2) * 64 + c] = __float2bfloat16(al2); xr[(size_t)(nb_ + 2) * 64 + c] = __float2bfloat16(ar2); }
        if (nb_ + 3 < n) { xl[(size_t)(nb_ + 3) * 64 + c] = __float2bfloat16(al3); xr[(size_t)(nb_ + 3) * 64 + c] = __float2bfloat16(ar3); }
    }
}

// ---------------- layer-1 linear: din=64, fused input BN+ELU ----------------

__global__ __launch_bounds__(256) void lin64bn_k(
        const float* __restrict__ x, int n,
        const float* __restrict__ sums, const float* __restrict__ sqs,
        const float* __restrict__ g, const float* __restrict__ be,
        const float* __restrict__ Wl, const float* __restrict__ bl,
        const float* __restrict__ Wr, const float* __restrict__ br,
        bf16* __restrict__ xl, bf16* __restrict__ xr, int ngroups16) {
    __shared__ float2 sWl2[32 * 64];
    __shared__ float2 sWr2[32 * 64];
    __shared__ float sx[16 * 64];
    __shared__ float ssc[64], ssh[64];
    int t = threadIdx.x;
    if (t < 64) {
        float inv_n = 1.f / n;
        float mu = sums[t] * inv_n;
        float var = sqs[t] * inv_n - mu * mu;
        float sc = rsqrtf(var + 1e-5f) * g[t];
        ssc[t] = sc; ssh[t] = be[t] - mu * sc;
    }
    for (int i = t; i < 32 * 64; i += 256) {
        int k2 = i >> 6, c = i & 63;
        sWl2[i] = make_float2(Wl[(2 * k2) * 64 + c], Wl[(2 * k2 + 1) * 64 + c]);
        sWr2[i] = make_float2(Wr[(2 * k2) * 64 + c], Wr[(2 * k2 + 1) * 64 + c]);
    }
    int c = t & 63, w = t >> 6;
    float blc = bl[c], brc = br[c];
    for (int gidx = blockIdx.x; gidx < ngroups16; gidx += gridDim.x) {
        int node0 = gidx * 16;
        __syncthreads();
        for (int i = t; i < 16 * 64; i += 256) {
            int r = node0 + (i >> 6);
            float v = (r < n) ? x[(size_t)r * 64 + (i & 63)] : 0.f;
            v = v * ssc[i & 63] + ssh[i & 63];
            sx[i] = v > 0.f ? v : __expf(v) - 1.f;
        }
        __syncthreads();
        float al0 = blc, al1 = blc, al2 = blc, al3 = blc;
        float ar0 = brc, ar1 = brc, ar2 = brc, ar3 = brc;
        const float* sx0 = sx + w * 4 * 64;
#pragma unroll 8
        for (int k2 = 0; k2 < 32; ++k2) {
            float2 wl = sWl2[k2 * 64 + c], wr = sWr2[k2 * 64 + c];
            float2 xa = *(const float2*)&sx0[k2 * 2];
            float2 xb = *(const float2*)&sx0[64 + k2 * 2];
            float2 xc = *(const float2*)&sx0[128 + k2 * 2];
            float2 xd = *(const float2*)&sx0[192 + k2 * 2];
            al0 = fmaf(xa.x, wl.x, al0); al0 = fmaf(xa.y, wl.y, al0);
            ar0 = fmaf(xa.x, wr.x, ar0); ar0 = fmaf(xa.y, wr.y, ar0);
            al1 = fmaf(xb.x, wl.x, al1); al1 = fmaf(xb.y, wl.y, al1);
            ar1 = fmaf(xb.x, wr.x, ar1); ar1 = fmaf(xb.y, wr.y, ar1);
            al2 = fmaf(xc.x, wl.x, al2); al2 = fmaf(xc.y, wl.y, al2);
            ar2 = fmaf(xc.x, wr.x, ar2); ar2 = fmaf(xc.y, wr.y, ar2);
            al3 = fmaf(xd.x, wl.x, al3); al3 = fmaf(xd.y, wl.y, al3);
            ar3 = fmaf(xd.x, wr.x, ar3); ar3 = fmaf(xd.y, wr.y, ar3);
        }
        int nb_ = node0 + w * 4;
        if (nb_ + 0 < n) { xl[(size_t)(nb_ + 0) * 64 + c] = __float2bfloat16(al0); xr[(size_t)(nb_ + 0) * 64 + c] = __float2bfloat16(ar0); }
        if (nb_ + 1 < n) { xl[(size_t)(nb_ + 1) * 64 + c] = __float2bfloat16(al1); xr[(size_t)(nb_ + 1) * 64 + c] = __float2bfloat16(ar1); }
        if (nb_ + 2 < n) { xl[(size_t)(nb_ + 2) * 64 + c] = __float2bfloat16(al2); xr[(size_t)(nb_ + 2) * 64 + c] = __float2bfloat16(ar2); }
        if (nb_ + 3 < n) { xl[(size_t)(nb_ + 3) * 64 + c] = __float2bfloat16(al3); xr[(size_t)(nb_ + 3) * 64 + c] = __float2bfloat16(ar3); }
    }
}

// ---------------- fused GAT: wave per node, 4 ch/lane, 4 edges/wave, 4-deep MLP ----------------

__global__ __launch_bounds__(256) void gat_node_k(
        const bf16* __restrict__ xl, const bf16* __restrict__ xr,
        const float* __restrict__ We, const float* __restrict__ att,
        const int* __restrict__ row_start, const uint* __restrict__ spre,
        const uint2* __restrict__ eat,
        float* __restrict__ out, int n) {
    int t = threadIdx.x;
    int lane = t & 63;
    int quad = lane >> 4;          // edge slot 0..3
    int c4 = lane & 15;            // channel group: channels 4*c4 .. 4*c4+3
    int node = blockIdx.x * 4 + (t >> 6);
    if (node >= n) return;
    int c0 = c4 << 2;
    v4f w0 = {We[c0], We[c0 + 1], We[c0 + 2], We[c0 + 3]};
    v4f w1 = {We[64 + c0], We[64 + c0 + 1], We[64 + c0 + 2], We[64 + c0 + 3]};
    v4f w2 = {We[128 + c0], We[128 + c0 + 1], We[128 + c0 + 2], We[128 + c0 + 3]};
    v4f w3 = {We[192 + c0], We[192 + c0 + 1], We[192 + c0 + 2], We[192 + c0 + 3]};
    v4f ratt = {att[c0] * 1.44269504f, att[c0 + 1] * 1.44269504f,
                att[c0 + 2] * 1.44269504f, att[c0 + 3] * 1.44269504f};
    const char* xlb = (const char*)xl;
    uint2 xru = *(const uint2*)((const char*)xr + ((size_t)node << 7) + ((uint)c0 << 1));
    v4f xrd = {bfl(xru.x), bfh(xru.x), bfl(xru.y), bfh(xru.y)};
    int rs = row_start[node], re = row_start[node + 1];
    v4f acc = {0.f, 0.f, 0.f, 0.f};
    float srun = 0.f;
    uint coff = (uint)c4 << 3;   // 4 channels * 2B

#define PROC(EA, XU) { \
        v4f xv = {bfl((XU).x), bfh((XU).x), bfl((XU).y), bfh((XU).y)}; \
        v4f z = xv + xrd; \
        float e0 = bfl((EA).x), e1 = bfh((EA).x); \
        float e2 = bfl((EA).y), e3 = bfh((EA).y); \
        z += e0 * w0; z += e1 * w1; z += e2 * w2; z += e3 * w3; \
        z = __builtin_elementwise_max(z, 0.2f * z); \
        v4f zr = z * ratt; \
        float v = (zr.x + zr.y) + (zr.z + zr.w); \
        v += __shfl_xor(v, 1); v += __shfl_xor(v, 2); \
        float p = exp2f(v); \
        srun += p; \
        acc += p * xv; \
    }

    int i = rs;
    // 4-deep software pipeline: 4 gathers + 4 metadata loads in flight
    for (; i + 16 <= re; i += 16) {
        uint sp0 = spre[i + quad],      sp1 = spre[i + 4 + quad];
        uint sp2 = spre[i + 8 + quad],  sp3 = spre[i + 12 + quad];
        uint2 ea0 = eat[i + quad],      ea1 = eat[i + 4 + quad];
        uint2 ea2 = eat[i + 8 + quad],  ea3 = eat[i + 12 + quad];
        uint2 xu0 = *(const uint2*)(xlb + sp0 + coff);
        uint2 xu1 = *(const uint2*)(xlb + sp1 + coff);
        uint2 xu2 = *(const uint2*)(xlb + sp2 + coff);
        uint2 xu3 = *(const uint2*)(xlb + sp3 + coff);
        PROC(ea0, xu0);
        PROC(ea1, xu1);
        PROC(ea2, xu2);
        PROC(ea3, xu3);
    }
    for (; i + 8 <= re; i += 8) {
        uint spA = spre[i + quad], spB = spre[i + 4 + quad];
        uint2 eaA = eat[i + quad], eaB = eat[i + 4 + quad];
        uint2 xuA = *(const uint2*)(xlb + spA + coff);
        uint2 xuB = *(const uint2*)(xlb + spB + coff);
        PROC(eaA, xuA);
        PROC(eaB, xuB);
    }
    for (; i < re; i += 4) {
        int ei = i + quad;
        bool ok = ei < re;
        int eic = ok ? ei : i;
        uint sp = spre[eic];
        uint2 ea = eat[eic];
        uint2 xu = *(const uint2*)(xlb + sp + coff);
        v4f xv = {bfl(xu.x), bfh(xu.x), bfl(xu.y), bfh(xu.y)};
        v4f z = xv + xrd;
        float e0 = bfl(ea.x), e1 = bfh(ea.x);
        float e2 = bfl(ea.y), e3 = bfh(ea.y);
        z += e0 * w0; z += e1 * w1; z += e2 * w2; z += e3 * w3;
        z = __builtin_elementwise_max(z, 0.2f * z);
        v4f zr = z * ratt;
        float v = (zr.x + zr.y) + (zr.z + zr.w);
        v += __shfl_xor(v, 1); v += __shfl_xor(v, 2);
        float p = ok ? exp2f(v) : 0.f;
        srun += p;
        acc += p * xv;
    }
#undef PROC

    // merge the 4 quads
    srun += __shfl_xor(srun, 16);  srun += __shfl_xor(srun, 32);
    acc.x += __shfl_xor(acc.x, 16); acc.x += __shfl_xor(acc.x, 32);
    acc.y += __shfl_xor(acc.y, 16); acc.y += __shfl_xor(acc.y, 32);
    acc.z += __shfl_xor(acc.z, 16); acc.z += __shfl_xor(acc.z, 32);
    acc.w += __shfl_xor(acc.w, 16); acc.w += __shfl_xor(acc.w, 32);
    if (quad == 0) {
        float inv = 1.f / (srun + 1e-16f);
        v4f o = acc * inv;
        *(v4f*)&out[((size_t)node << 6) + (uint)c0] = o;
    }
}

// ---------------- BN stats ----------------

__global__ void bn_stats_k(const float* __restrict__ x, float* __restrict__ sums,
                           float* __restrict__ sqs, int n) {
    __shared__ float ls[256], lq[256];
    int t = threadIdx.x;
    int c = t & 63, sub = t >> 6;
    float s = 0.f, q = 0.f;
    for (int r = blockIdx.x * 4 + sub; r < n; r += gridDim.x * 4) {
        float v = x[(size_t)r * 64 + c];
        s += v;
        q = fmaf(v, v, q);
    }
    ls[t] = s; lq[t] = q;
    __syncthreads();
    if (t < 128) { ls[t] += ls[t + 128]; lq[t] += lq[t + 128]; }
    __syncthreads();
    if (t < 64) {
        atomicAdd(&sums[c], ls[t] + ls[t + 64]);
        atomicAdd(&sqs[c], lq[t] + lq[t + 64]);
    }
}

// ---------------- head fc 64->64 (fused input BN+ELU, fused output stats) ----------------

__global__ __launch_bounds__(256) void lin1_k(
        const float* __restrict__ x, int n,
        const float* __restrict__ sums, const float* __restrict__ sqs,
        const float* __restrict__ g, const float* __restrict__ be,
        const float* __restrict__ W, const float* __restrict__ b,
        float* __restrict__ y, float* __restrict__ sums_o, float* __restrict__ sqs_o,
        int ngroups16) {
    __shared__ float2 sW2[32 * 64];
    __shared__ float sx[16 * 64];
    __shared__ float ssc[64], ssh[64];
    __shared__ float ls[256], lq[256];
    int t = threadIdx.x;
    if (t < 64) {
        float inv_n = 1.f / n;
        float mu = sums[t] * inv_n;
        float var = sqs[t] * inv_n - mu * mu;
        float sc = rsqrtf(var + 1e-5f) * g[t];
        ssc[t] = sc; ssh[t] = be[t] - mu * sc;
    }
    for (int i = t; i < 32 * 64; i += 256) {
        int k2 = i >> 6, c = i & 63;
        sW2[i] = make_float2(W[(2 * k2) * 64 + c], W[(2 * k2 + 1) * 64 + c]);
    }
    int c = t & 63, w = t >> 6;
    float bc = b[c];
    float s = 0.f, q = 0.f;
    for (int gidx = blockIdx.x; gidx < ngroups16; gidx += gridDim.x) {
        int node0 = gidx * 16;
        __syncthreads();
        for (int i = t; i < 16 * 64; i += 256) {
            int r = node0 + (i >> 6);
            float v = (r < n) ? x[(size_t)r * 64 + (i & 63)] : 0.f;
            v = v * ssc[i & 63] + ssh[i & 63];
            sx[i] = v > 0.f ? v : __expf(v) - 1.f;
        }
        __syncthreads();
        float a0 = bc, a1 = bc, a2 = bc, a3 = bc;
        const float* sx0 = sx + w * 4 * 64;
#pragma unroll 8
        for (int k2 = 0; k2 < 32; ++k2) {
            float2 wv = sW2[k2 * 64 + c];
            float2 xa = *(const float2*)&sx0[k2 * 2];
            float2 xb = *(const float2*)&sx0[64 + k2 * 2];
            float2 xc = *(const float2*)&sx0[128 + k2 * 2];
            float2 xd = *(const float2*)&sx0[192 + k2 * 2];
            a0 = fmaf(xa.x, wv.x, a0); a0 = fmaf(xa.y, wv.y, a0);
            a1 = fmaf(xb.x, wv.x, a1); a1 = fmaf(xb.y, wv.y, a1);
            a2 = fmaf(xc.x, wv.x, a2); a2 = fmaf(xc.y, wv.y, a2);
            a3 = fmaf(xd.x, wv.x, a3); a3 = fmaf(xd.y, wv.y, a3);
        }
        int nb_ = node0 + w * 4;
        if (nb_ + 0 < n) { y[(size_t)(nb_ + 0) * 64 + c] = a0; s += a0; q = fmaf(a0, a0, q); }
        if (nb_ + 1 < n) { y[(size_t)(nb_ + 1) * 64 + c] = a1; s += a1; q = fmaf(a1, a1, q); }
        if (nb_ + 2 < n) { y[(size_t)(nb_ + 2) * 64 + c] = a2; s += a2; q = fmaf(a2, a2, q); }
        if (nb_ + 3 < n) { y[(size_t)(nb_ + 3) * 64 + c] = a3; s += a3; q = fmaf(a3, a3, q); }
    }
    __syncthreads();
    ls[t] = s; lq[t] = q;
    __syncthreads();
    if (t < 64) {
        float ss = ls[t] + ls[t + 64] + ls[t + 128] + ls[t + 192];
        float qq = lq[t] + lq[t + 64] + lq[t + 128] + lq[t + 192];
        atomicAdd(&sums_o[t], ss);
        atomicAdd(&sqs_o[t], qq);
    }
}

// ---------------- final: fused BN+ELU + dot(64) + 5*tanh ----------------

__global__ void final_k(const float* __restrict__ z, int n,
                        const float* __restrict__ sums, const float* __restrict__ sqs,
                        const float* __restrict__ g, const float* __restrict__ be,
                        const float* __restrict__ W2, const float* __restrict__ b2,
                        float* __restrict__ out) {
    int t = blockIdx.x * blockDim.x + threadIdx.x;
    int node = t >> 6, c = t & 63;
    if (node >= n) return;
    float inv_n = 1.f / n;
    float mu = sums[c] * inv_n;
    float var = sqs[c] * inv_n - mu * mu;
    float scc = rsqrtf(var + 1e-5f) * g[c];
    float sh = be[c] - mu * scc;
    float v = z[(size_t)node * 64 + c] * scc + sh;
    v = v > 0.f ? v : __expf(v) - 1.f;
    v *= W2[c];
    v += __shfl_xor(v, 1);
    v += __shfl_xor(v, 2);
    v += __shfl_xor(v, 4);
    v += __shfl_xor(v, 8);
    v += __shfl_xor(v, 16);
    v += __shfl_xor(v, 32);
    if (c == 0) out[node] = 5.0f * tanhf(v + b2[0]);
}

// ---------------- launch ----------------

extern "C" void kernel_launch(void* const* d_in, const int* in_sizes, int n_in,
                              void* d_out, int out_size, void* d_ws, size_t ws_size,
                              hipStream_t stream) {
    const float* x0    = (const float*)d_in[0];
    const int*   eidx  = (const int*)d_in[1];
    const float* eattr = (const float*)d_in[2];

    const float* Wl[2]; const float* bl[2]; const float* Wr[2]; const float* br[2];
    const float* We[2]; const float* att[2]; const float* g[2]; const float* be[2];
    for (int l = 0; l < 2; ++l) {
        int base = 3 + l * 9;
        Wl[l]  = (const float*)d_in[base + 0];
        bl[l]  = (const float*)d_in[base + 1];
        Wr[l]  = (const float*)d_in[base + 2];
        br[l]  = (const float*)d_in[base + 3];
        We[l]  = (const float*)d_in[base + 4];
        att[l] = (const float*)d_in[base + 5];
        // base+6 = bias: per-channel constant, cancels exactly under BatchNorm
        g[l]   = (const float*)d_in[base + 7];
        be[l]  = (const float*)d_in[base + 8];
    }
    const float* W1 = (const float*)d_in[21];
    const float* b1 = (const float*)d_in[22];
    const float* gf = (const float*)d_in[23];
    const float* bf = (const float*)d_in[24];
    const float* W2 = (const float*)d_in[25];
    const float* b2 = (const float*)d_in[26];

    const int N = in_sizes[0] / 128;
    const int E = in_sizes[1] / 2;
    const int* src = eidx;
    const int* dst = eidx + E;
    const int nbk = (N + 127) >> 7;

    // workspace (4-byte units).  Region A shared: (tea,tsd) then (h0,h1).
    float* ws = (float*)d_ws;
    size_t o = 0;
    float* regionA = ws + o; o += (size_t)2 * N * HC;         // >= E*3 units
    uint2* tea = (uint2*)regionA;
    uint*  tsd = (uint*)(regionA + (size_t)2 * E);
    float* h0  = regionA;
    float* h1  = regionA + (size_t)N * HC;
    uint2* eat_sorted = (uint2*)(ws + o); o += (size_t)E * 2;
    uint*  spre_sorted = (uint*)(ws + o);  o += (size_t)E;
    bf16*  xl  = (bf16*)(ws + o);  o += (size_t)N * 32;
    bf16*  xr  = (bf16*)(ws + o);  o += (size_t)N * 32;
    int*   row_start = (int*)(ws + o); o += (size_t)N + 1;
    int*   bcnt   = (int*)(ws + o); o += 512;
    float* stats  = ws + o; o += 6 * HC;
    int*   bstart = (int*)(ws + o); o += 513;
    int*   bcur   = (int*)(ws + o); o += 512;
    float* s0 = stats,        *q0 = stats + 64;
    float* s1 = stats + 128,  *q1 = stats + 192;
    float* sf = stats + 256,  *qf = stats + 320;

    const int ngroups4  = (N + 3) / 4;
    const int ngroups16 = (N + 15) / 16;
    const int EB = (E + 8191) / 8192;

    hipMemsetAsync(bcnt, 0, (512 + 6 * HC) * 4, stream);

    // CSR build: coarse bucket + in-LDS counting sort (shared by both layers)
    bucket_hist_k<<<EB, 512, 0, stream>>>(dst, bcnt, E, nbk);
    bucket_scan_k<<<1, 512, 0, stream>>>(bcnt, bstart, bcur, nbk, E);
    bucketA_k<<<EB, 1024, 0, stream>>>(src, dst, (const float4*)eattr, bcur, tsd, tea, E, nbk);
    bucket_sort_k<<<nbk, 256, 0, stream>>>(tsd, tea, bstart, spre_sorted, eat_sorted,
                                           row_start, N);

    // layer 0  (h0 overwrites regionA only after tsd/tea are consumed)
    lin128_k<<<512, 256, 0, stream>>>(x0, N, Wl[0], bl[0], Wr[0], br[0], xl, xr, ngroups16);
    gat_node_k<<<ngroups4, 256, 0, stream>>>(xl, xr, We[0], att[0], row_start,
                                             spre_sorted, eat_sorted, h0, N);
    bn_stats_k<<<256, 256, 0, stream>>>(h0, s0, q0, N);

    // layer 1 (input BN+ELU fused)
    lin64bn_k<<<512, 256, 0, stream>>>(h0, N, s0, q0, g[0], be[0],
                                       Wl[1], bl[1], Wr[1], br[1], xl, xr, ngroups16);
    gat_node_k<<<ngroups4, 256, 0, stream>>>(xl, xr, We[1], att[1], row_start,
                                             spre_sorted, eat_sorted, h1, N);
    bn_stats_k<<<256, 256, 0, stream>>>(h1, s1, q1, N);

    // head
    float* y = h0;  // h0 dead after lin64bn
    lin1_k<<<512, 256, 0, stream>>>(h1, N, s1, q1, g[1], be[1], W1, b1, y, sf, qf, ngroups16);
    final_k<<<(int)(((size_t)N * 64 + 255) / 256), 256, 0, stream>>>(
        y, N, sf, qf, gf, bf, W2, b2, (float*)d_out);
}

// Round 10
// 368.886 us; speedup vs baseline: 5.0604x; 1.0039x over previous
//
#include <hip/hip_runtime.h>
#include <hip/hip_bf16.h>
#include <cmath>

#define HC 64
typedef __hip_bfloat16 bf16;
typedef unsigned int uint;
typedef float v4f __attribute__((ext_vector_type(4)));

__device__ __forceinline__ uint pack_bf2(float a, float b) {
    __hip_bfloat162 h = __float22bfloat162_rn(make_float2(a, b));
    return *reinterpret_cast<uint*>(&h);
}
__device__ __forceinline__ float bfl(uint u) { return __uint_as_float(u << 16); }
__device__ __forceinline__ float bfh(uint u) { return __uint_as_float(u & 0xffff0000u); }

// ---------------- coarse bucket histogram (dst>>7), LDS-aggregated ----------------

__global__ __launch_bounds__(512) void bucket_hist_k(const int* __restrict__ dst,
                                                     int* __restrict__ bcnt, int E, int nbk) {
    __shared__ int lh[512];
    int t = threadIdx.x;
    for (int i = t; i < nbk; i += 512) lh[i] = 0;
    __syncthreads();
    int base = blockIdx.x * 8192;
#pragma unroll
    for (int k = 0; k < 16; ++k) {
        int e = base + k * 512 + t;
        if (e < E) atomicAdd(&lh[dst[e] >> 7], 1);
    }
    __syncthreads();
    for (int i = t; i < nbk; i += 512) if (lh[i]) atomicAdd(&bcnt[i], lh[i]);
}

// ---------------- scan over nbk (<=512) buckets ----------------

__global__ __launch_bounds__(512) void bucket_scan_k(const int* __restrict__ bcnt,
                                                     int* __restrict__ bstart,
                                                     int* __restrict__ bcur, int nbk, int E) {
    __shared__ int tmp[512];
    int t = threadIdx.x;
    int v = (t < nbk) ? bcnt[t] : 0;
    tmp[t] = v;
    __syncthreads();
    for (int off = 1; off < 512; off <<= 1) {
        int a = (t >= off) ? tmp[t - off] : 0;
        __syncthreads();
        tmp[t] += a;
        __syncthreads();
    }
    if (t < nbk) { int ex = tmp[t] - v; bstart[t] = ex; bcur[t] = ex; }
    if (t == 0) bstart[nbk] = E;
}

// ---------------- grouping: append 12B records into coarse bucket regions ----------------

__global__ __launch_bounds__(1024) void bucketA_k(
        const int* __restrict__ src, const int* __restrict__ dst,
        const float4* __restrict__ eattr, int* __restrict__ bcur,
        uint* __restrict__ tsd, uint2* __restrict__ tea, int E, int nbk) {
    __shared__ int lcnt[512];
    __shared__ int lbase[512];
    int t = threadIdx.x;
    for (int i = t; i < nbk; i += 1024) lcnt[i] = 0;
    __syncthreads();
    int base = blockIdx.x * 8192;
    int myb[8], mylp[8];
#pragma unroll
    for (int k = 0; k < 8; ++k) {
        int e = base + k * 1024 + t;
        if (e < E) {
            int b = dst[e] >> 7;
            myb[k] = b;
            mylp[k] = atomicAdd(&lcnt[b], 1);
        } else myb[k] = -1;
    }
    __syncthreads();
    for (int i = t; i < nbk; i += 1024) {
        int cc = lcnt[i];
        lbase[i] = cc ? atomicAdd(&bcur[i], cc) : 0;
    }
    __syncthreads();
#pragma unroll
    for (int k = 0; k < 8; ++k) {
        int e = base + k * 1024 + t;
        if (e >= E) continue;
        int pos = lbase[myb[k]] + mylp[k];
        int d = dst[e];
        tsd[pos] = (uint)src[e] | ((uint)(d & 127) << 25);
        float4 ea = eattr[e];
        tea[pos] = make_uint2(pack_bf2(ea.x, ea.y), pack_bf2(ea.z, ea.w));
    }
}

// ---------------- in-LDS counting sort per bucket -> exact CSR ----------------

__global__ __launch_bounds__(256) void bucket_sort_k(
        const uint* __restrict__ tsd, const uint2* __restrict__ tea,
        const int* __restrict__ bstart,
        uint* __restrict__ spre_sorted, uint2* __restrict__ eat_sorted,
        int* __restrict__ row_start, int n) {
    __shared__ int cnt[128], pfx[128], cur[128];
    int b = blockIdx.x, t = threadIdx.x;
    int i0 = bstart[b], i1 = bstart[b + 1];
    int node0 = b << 7;
    if (t < 128) cnt[t] = 0;
    __syncthreads();
    for (int i = i0 + t; i < i1; i += 256) atomicAdd(&cnt[tsd[i] >> 25], 1);
    __syncthreads();
    if (t < 128) pfx[t] = cnt[t];
    __syncthreads();
    for (int off = 1; off < 128; off <<= 1) {
        int a = (t < 128 && t >= off) ? pfx[t - off] : 0;
        __syncthreads();
        if (t < 128) pfx[t] += a;
        __syncthreads();
    }
    if (t < 128) {
        int ex = pfx[t] - cnt[t];
        cur[t] = ex;
        if (node0 + t <= n) row_start[node0 + t] = i0 + ex;
    }
    __syncthreads();
    for (int i = i0 + t; i < i1; i += 256) {
        uint u = tsd[i];
        int dl = (int)(u >> 25);
        int pos = i0 + atomicAdd(&cur[dl], 1);
        spre_sorted[pos] = (u & 0x1FFFFFFu) << 7;   // byte offset into xl rows
        eat_sorted[pos] = tea[i];
    }
}

// ---------------- layer-0 linear: din=128, bf16-packed W in LDS (40 KB) ----------------

__global__ __launch_bounds__(256) void lin128_k(
        const float* __restrict__ x, int n,
        const float* __restrict__ Wl, const float* __restrict__ bl,
        const float* __restrict__ Wr, const float* __restrict__ br,
        bf16* __restrict__ xl, bf16* __restrict__ xr, int ngroups16) {
    __shared__ uint sWl2[64 * 64];   // [k2][c] = bf16(W[2k2][c]) | bf16(W[2k2+1][c])<<16
    __shared__ uint sWr2[64 * 64];
    __shared__ float sx[16 * 128];
    int t = threadIdx.x;
    for (int i = t; i < 64 * 64; i += 256) {
        int k2 = i >> 6, c = i & 63;
        sWl2[i] = pack_bf2(Wl[(2 * k2) * 64 + c], Wl[(2 * k2 + 1) * 64 + c]);
        sWr2[i] = pack_bf2(Wr[(2 * k2) * 64 + c], Wr[(2 * k2 + 1) * 64 + c]);
    }
    int c = t & 63, w = t >> 6;
    float blc = bl[c], brc = br[c];
    for (int gidx = blockIdx.x; gidx < ngroups16; gidx += gridDim.x) {
        int node0 = gidx * 16;
        __syncthreads();
        for (int i = t; i < 16 * 128; i += 256) {
            int r = node0 + (i >> 7);
            sx[i] = (r < n) ? x[(size_t)r * 128 + (i & 127)] : 0.f;
        }
        __syncthreads();
        float al0 = blc, al1 = blc, al2 = blc, al3 = blc;
        float ar0 = brc, ar1 = brc, ar2 = brc, ar3 = brc;
        const float* sx0 = sx + w * 4 * 128;
#pragma unroll 8
        for (int k2 = 0; k2 < 64; ++k2) {
            uint wlu = sWl2[k2 * 64 + c], wru = sWr2[k2 * 64 + c];
            float wlx = bfl(wlu), wly = bfh(wlu);
            float wrx = bfl(wru), wry = bfh(wru);
            float2 xa = *(const float2*)&sx0[k2 * 2];
            float2 xb = *(const float2*)&sx0[128 + k2 * 2];
            float2 xc = *(const float2*)&sx0[256 + k2 * 2];
            float2 xd = *(const float2*)&sx0[384 + k2 * 2];
            al0 = fmaf(xa.x, wlx, al0); al0 = fmaf(xa.y, wly, al0);
            ar0 = fmaf(xa.x, wrx, ar0); ar0 = fmaf(xa.y, wry, ar0);
            al1 = fmaf(xb.x, wlx, al1); al1 = fmaf(xb.y, wly, al1);
            ar1 = fmaf(xb.x, wrx, ar1); ar1 = fmaf(xb.y, wry, ar1);
            al2 = fmaf(xc.x, wlx, al2); al2 = fmaf(xc.y, wly, al2);
            ar2 = fmaf(xc.x, wrx, ar2); ar2 = fmaf(xc.y, wry, ar2);
            al3 = fmaf(xd.x, wlx, al3); al3 = fmaf(xd.y, wly, al3);
            ar3 = fmaf(xd.x, wrx, ar3); ar3 = fmaf(xd.y, wry, ar3);
        }
        int nb_ = node0 + w * 4;
        if (nb_ + 0 < n) { xl[(size_t)(nb_ + 0) * 64 + c] = __float2bfloat16(al0); xr[(size_t)(nb_ + 0) * 64 + c] = __float2bfloat16(ar0); }
        if (nb_ + 1 < n) { xl[(size_t)(nb_ + 1) * 64 + c] = __float2bfloat16(al1); xr[(size_t)(nb_ + 1) * 64 + c] = __float2bfloat16(ar1); }
        if (nb_ + 2 < n) { xl[(size_t)(nb_ + 2) * 64 + c] = __float2bfloat16(al2); xr[(size_t)(nb_ + 2) * 64 + c] = __float2bfloat16(ar2); }
        if (nb_ + 3 < n) { xl[(size_t)(nb_ + 3) * 64 + c] = __float2bfloat16(al3); xr[(size_t)(nb_ + 3) * 64 + c] = __float2bfloat16(ar3); }
    }
}

// ---------------- layer-1 linear: din=64, fused input BN+ELU, bf16-packed W ----------------

__global__ __launch_bounds__(256) void lin64bn_k(
        const float* __restrict__ x, int n,
        const float* __restrict__ sums, const float* __restrict__ sqs,
        const float* __restrict__ g, const float* __restrict__ be,
        const float* __restrict__ Wl, const float* __restrict__ bl,
        const float* __restrict__ Wr, const float* __restrict__ br,
        bf16* __restrict__ xl, bf16* __restrict__ xr, int ngroups16) {
    __shared__ uint sWl2[32 * 64];
    __shared__ uint sWr2[32 * 64];
    __shared__ float sx[16 * 64];
    __shared__ float ssc[64], ssh[64];
    int t = threadIdx.x;
    if (t < 64) {
        float inv_n = 1.f / n;
        float mu = sums[t] * inv_n;
        float var = sqs[t] * inv_n - mu * mu;
        float sc = rsqrtf(var + 1e-5f) * g[t];
        ssc[t] = sc; ssh[t] = be[t] - mu * sc;
    }
    for (int i = t; i < 32 * 64; i += 256) {
        int k2 = i >> 6, c = i & 63;
        sWl2[i] = pack_bf2(Wl[(2 * k2) * 64 + c], Wl[(2 * k2 + 1) * 64 + c]);
        sWr2[i] = pack_bf2(Wr[(2 * k2) * 64 + c], Wr[(2 * k2 + 1) * 64 + c]);
    }
    int c = t & 63, w = t >> 6;
    float blc = bl[c], brc = br[c];
    for (int gidx = blockIdx.x; gidx < ngroups16; gidx += gridDim.x) {
        int node0 = gidx * 16;
        __syncthreads();
        for (int i = t; i < 16 * 64; i += 256) {
            int r = node0 + (i >> 6);
            float v = (r < n) ? x[(size_t)r * 64 + (i & 63)] : 0.f;
            v = v * ssc[i & 63] + ssh[i & 63];
            sx[i] = v > 0.f ? v : __expf(v) - 1.f;
        }
        __syncthreads();
        float al0 = blc, al1 = blc, al2 = blc, al3 = blc;
        float ar0 = brc, ar1 = brc, ar2 = brc, ar3 = brc;
        const float* sx0 = sx + w * 4 * 64;
#pragma unroll 8
        for (int k2 = 0; k2 < 32; ++k2) {
            uint wlu = sWl2[k2 * 64 + c], wru = sWr2[k2 * 64 + c];
            float wlx = bfl(wlu), wly = bfh(wlu);
            float wrx = bfl(wru), wry = bfh(wru);
            float2 xa = *(const float2*)&sx0[k2 * 2];
            float2 xb = *(const float2*)&sx0[64 + k2 * 2];
            float2 xc = *(const float2*)&sx0[128 + k2 * 2];
            float2 xd = *(const float2*)&sx0[192 + k2 * 2];
            al0 = fmaf(xa.x, wlx, al0); al0 = fmaf(xa.y, wly, al0);
            ar0 = fmaf(xa.x, wrx, ar0); ar0 = fmaf(xa.y, wry, ar0);
            al1 = fmaf(xb.x, wlx, al1); al1 = fmaf(xb.y, wly, al1);
            ar1 = fmaf(xb.x, wrx, ar1); ar1 = fmaf(xb.y, wry, ar1);
            al2 = fmaf(xc.x, wlx, al2); al2 = fmaf(xc.y, wly, al2);
            ar2 = fmaf(xc.x, wrx, ar2); ar2 = fmaf(xc.y, wry, ar2);
            al3 = fmaf(xd.x, wlx, al3); al3 = fmaf(xd.y, wly, al3);
            ar3 = fmaf(xd.x, wrx, ar3); ar3 = fmaf(xd.y, wry, ar3);
        }
        int nb_ = node0 + w * 4;
        if (nb_ + 0 < n) { xl[(size_t)(nb_ + 0) * 64 + c] = __float2bfloat16(al0); xr[(size_t)(nb_ + 0) * 64 + c] = __float2bfloat16(ar0); }
        if (nb_ + 1 < n) { xl[(size_t)(nb_ + 1) * 64 + c] = __float2bfloat16(al1); xr[(size_t)(nb_ + 1) * 64 + c] = __float2bfloat16(ar1); }
        if (nb_ + 2 < n) { xl[(size_t)(nb_ + 2) * 64 + c] = __float2bfloat16(al2); xr[(size_t)(nb_ + 2) * 64 + c] = __float2bfloat16(ar2); }
        if (nb_ + 3 < n) { xl[(size_t)(nb_ + 3) * 64 + c] = __float2bfloat16(al3); xr[(size_t)(nb_ + 3) * 64 + c] = __float2bfloat16(ar3); }
    }
}

// ---------------- fused GAT: wave per node, 4 ch/lane, 4 edges/wave, 4-deep MLP ----------------

__global__ __launch_bounds__(256) void gat_node_k(
        const bf16* __restrict__ xl, const bf16* __restrict__ xr,
        const float* __restrict__ We, const float* __restrict__ att,
        const int* __restrict__ row_start, const uint* __restrict__ spre,
        const uint2* __restrict__ eat,
        float* __restrict__ out, int n) {
    int t = threadIdx.x;
    int lane = t & 63;
    int quad = lane >> 4;          // edge slot 0..3
    int c4 = lane & 15;            // channel group: channels 4*c4 .. 4*c4+3
    int node = blockIdx.x * 4 + (t >> 6);
    if (node >= n) return;
    int c0 = c4 << 2;
    v4f w0 = {We[c0], We[c0 + 1], We[c0 + 2], We[c0 + 3]};
    v4f w1 = {We[64 + c0], We[64 + c0 + 1], We[64 + c0 + 2], We[64 + c0 + 3]};
    v4f w2 = {We[128 + c0], We[128 + c0 + 1], We[128 + c0 + 2], We[128 + c0 + 3]};
    v4f w3 = {We[192 + c0], We[192 + c0 + 1], We[192 + c0 + 2], We[192 + c0 + 3]};
    v4f ratt = {att[c0] * 1.44269504f, att[c0 + 1] * 1.44269504f,
                att[c0 + 2] * 1.44269504f, att[c0 + 3] * 1.44269504f};
    const char* xlb = (const char*)xl;
    uint2 xru = *(const uint2*)((const char*)xr + ((size_t)node << 7) + ((uint)c0 << 1));
    v4f xrd = {bfl(xru.x), bfh(xru.x), bfl(xru.y), bfh(xru.y)};
    int rs = row_start[node], re = row_start[node + 1];
    v4f acc = {0.f, 0.f, 0.f, 0.f};
    float srun = 0.f;
    uint coff = (uint)c4 << 3;   // 4 channels * 2B

#define PROC(EA, XU) { \
        v4f xv = {bfl((XU).x), bfh((XU).x), bfl((XU).y), bfh((XU).y)}; \
        v4f z = xv + xrd; \
        float e0 = bfl((EA).x), e1 = bfh((EA).x); \
        float e2 = bfl((EA).y), e3 = bfh((EA).y); \
        z += e0 * w0; z += e1 * w1; z += e2 * w2; z += e3 * w3; \
        z = __builtin_elementwise_max(z, 0.2f * z); \
        v4f zr = z * ratt; \
        float v = (zr.x + zr.y) + (zr.z + zr.w); \
        v += __shfl_xor(v, 1); v += __shfl_xor(v, 2); \
        float p = exp2f(v); \
        srun += p; \
        acc += p * xv; \
    }

    int i = rs;
    for (; i + 16 <= re; i += 16) {
        uint sp0 = spre[i + quad],      sp1 = spre[i + 4 + quad];
        uint sp2 = spre[i + 8 + quad],  sp3 = spre[i + 12 + quad];
        uint2 ea0 = eat[i + quad],      ea1 = eat[i + 4 + quad];
        uint2 ea2 = eat[i + 8 + quad],  ea3 = eat[i + 12 + quad];
        uint2 xu0 = *(const uint2*)(xlb + sp0 + coff);
        uint2 xu1 = *(const uint2*)(xlb + sp1 + coff);
        uint2 xu2 = *(const uint2*)(xlb + sp2 + coff);
        uint2 xu3 = *(const uint2*)(xlb + sp3 + coff);
        PROC(ea0, xu0);
        PROC(ea1, xu1);
        PROC(ea2, xu2);
        PROC(ea3, xu3);
    }
    for (; i + 8 <= re; i += 8) {
        uint spA = spre[i + quad], spB = spre[i + 4 + quad];
        uint2 eaA = eat[i + quad], eaB = eat[i + 4 + quad];
        uint2 xuA = *(const uint2*)(xlb + spA + coff);
        uint2 xuB = *(const uint2*)(xlb + spB + coff);
        PROC(eaA, xuA);
        PROC(eaB, xuB);
    }
    for (; i < re; i += 4) {
        int ei = i + quad;
        bool ok = ei < re;
        int eic = ok ? ei : i;
        uint sp = spre[eic];
        uint2 ea = eat[eic];
        uint2 xu = *(const uint2*)(xlb + sp + coff);
        v4f xv = {bfl(xu.x), bfh(xu.x), bfl(xu.y), bfh(xu.y)};
        v4f z = xv + xrd;
        float e0 = bfl(ea.x), e1 = bfh(ea.x);
        float e2 = bfl(ea.y), e3 = bfh(ea.y);
        z += e0 * w0; z += e1 * w1; z += e2 * w2; z += e3 * w3;
        z = __builtin_elementwise_max(z, 0.2f * z);
        v4f zr = z * ratt;
        float v = (zr.x + zr.y) + (zr.z + zr.w);
        v += __shfl_xor(v, 1); v += __shfl_xor(v, 2);
        float p = ok ? exp2f(v) : 0.f;
        srun += p;
        acc += p * xv;
    }
#undef PROC

    // merge the 4 quads
    srun += __shfl_xor(srun, 16);  srun += __shfl_xor(srun, 32);
    acc.x += __shfl_xor(acc.x, 16); acc.x += __shfl_xor(acc.x, 32);
    acc.y += __shfl_xor(acc.y, 16); acc.y += __shfl_xor(acc.y, 32);
    acc.z += __shfl_xor(acc.z, 16); acc.z += __shfl_xor(acc.z, 32);
    acc.w += __shfl_xor(acc.w, 16); acc.w += __shfl_xor(acc.w, 32);
    if (quad == 0) {
        float inv = 1.f / (srun + 1e-16f);
        v4f o = acc * inv;
        *(v4f*)&out[((size_t)node << 6) + (uint)c0] = o;
    }
}

// ---------------- BN stats ----------------

__global__ void bn_stats_k(const float* __restrict__ x, float* __restrict__ sums,
                           float* __restrict__ sqs, int n) {
    __shared__ float ls[256], lq[256];
    int t = threadIdx.x;
    int c = t & 63, sub = t >> 6;
    float s = 0.f, q = 0.f;
    for (int r = blockIdx.x * 4 + sub; r < n; r += gridDim.x * 4) {
        float v = x[(size_t)r * 64 + c];
        s += v;
        q = fmaf(v, v, q);
    }
    ls[t] = s; lq[t] = q;
    __syncthreads();
    if (t < 128) { ls[t] += ls[t + 128]; lq[t] += lq[t + 128]; }
    __syncthreads();
    if (t < 64) {
        atomicAdd(&sums[c], ls[t] + ls[t + 64]);
        atomicAdd(&sqs[c], lq[t] + lq[t + 64]);
    }
}

// ---------------- head fc 64->64 (fused input BN+ELU, fused output stats) ----------------

__global__ __launch_bounds__(256) void lin1_k(
        const float* __restrict__ x, int n,
        const float* __restrict__ sums, const float* __restrict__ sqs,
        const float* __restrict__ g, const float* __restrict__ be,
        const float* __restrict__ W, const float* __restrict__ b,
        float* __restrict__ y, float* __restrict__ sums_o, float* __restrict__ sqs_o,
        int ngroups16) {
    __shared__ uint sW2[32 * 64];
    __shared__ float sx[16 * 64];
    __shared__ float ssc[64], ssh[64];
    __shared__ float ls[256], lq[256];
    int t = threadIdx.x;
    if (t < 64) {
        float inv_n = 1.f / n;
        float mu = sums[t] * inv_n;
        float var = sqs[t] * inv_n - mu * mu;
        float sc = rsqrtf(var + 1e-5f) * g[t];
        ssc[t] = sc; ssh[t] = be[t] - mu * sc;
    }
    for (int i = t; i < 32 * 64; i += 256) {
        int k2 = i >> 6, c = i & 63;
        sW2[i] = pack_bf2(W[(2 * k2) * 64 + c], W[(2 * k2 + 1) * 64 + c]);
    }
    int c = t & 63, w = t >> 6;
    float bc = b[c];
    float s = 0.f, q = 0.f;
    for (int gidx = blockIdx.x; gidx < ngroups16; gidx += gridDim.x) {
        int node0 = gidx * 16;
        __syncthreads();
        for (int i = t; i < 16 * 64; i += 256) {
            int r = node0 + (i >> 6);
            float v = (r < n) ? x[(size_t)r * 64 + (i & 63)] : 0.f;
            v = v * ssc[i & 63] + ssh[i & 63];
            sx[i] = v > 0.f ? v : __expf(v) - 1.f;
        }
        __syncthreads();
        float a0 = bc, a1 = bc, a2 = bc, a3 = bc;
        const float* sx0 = sx + w * 4 * 64;
#pragma unroll 8
        for (int k2 = 0; k2 < 32; ++k2) {
            uint wu = sW2[k2 * 64 + c];
            float wx = bfl(wu), wy = bfh(wu);
            float2 xa = *(const float2*)&sx0[k2 * 2];
            float2 xb = *(const float2*)&sx0[64 + k2 * 2];
            float2 xc = *(const float2*)&sx0[128 + k2 * 2];
            float2 xd = *(const float2*)&sx0[192 + k2 * 2];
            a0 = fmaf(xa.x, wx, a0); a0 = fmaf(xa.y, wy, a0);
            a1 = fmaf(xb.x, wx, a1); a1 = fmaf(xb.y, wy, a1);
            a2 = fmaf(xc.x, wx, a2); a2 = fmaf(xc.y, wy, a2);
            a3 = fmaf(xd.x, wx, a3); a3 = fmaf(xd.y, wy, a3);
        }
        int nb_ = node0 + w * 4;
        if (nb_ + 0 < n) { y[(size_t)(nb_ + 0) * 64 + c] = a0; s += a0; q = fmaf(a0, a0, q); }
        if (nb_ + 1 < n) { y[(size_t)(nb_ + 1) * 64 + c] = a1; s += a1; q = fmaf(a1, a1, q); }
        if (nb_ + 2 < n) { y[(size_t)(nb_ + 2) * 64 + c] = a2; s += a2; q = fmaf(a2, a2, q); }
        if (nb_ + 3 < n) { y[(size_t)(nb_ + 3) * 64 + c] = a3; s += a3; q = fmaf(a3, a3, q); }
    }
    __syncthreads();
    ls[t] = s; lq[t] = q;
    __syncthreads();
    if (t < 64) {
        float ss = ls[t] + ls[t + 64] + ls[t + 128] + ls[t + 192];
        float qq = lq[t] + lq[t + 64] + lq[t + 128] + lq[t + 192];
        atomicAdd(&sums_o[t], ss);
        atomicAdd(&sqs_o[t], qq);
    }
}

// ---------------- final: fused BN+ELU + dot(64) + 5*tanh ----------------

__global__ void final_k(const float* __restrict__ z, int n,
                        const float* __restrict__ sums, const float* __restrict__ sqs,
                        const float* __restrict__ g, const float* __restrict__ be,
                        const float* __restrict__ W2, const float* __restrict__ b2,
                        float* __restrict__ out) {
    int t = blockIdx.x * blockDim.x + threadIdx.x;
    int node = t >> 6, c = t & 63;
    if (node >= n) return;
    float inv_n = 1.f / n;
    float mu = sums[c] * inv_n;
    float var = sqs[c] * inv_n - mu * mu;
    float scc = rsqrtf(var + 1e-5f) * g[c];
    float sh = be[c] - mu * scc;
    float v = z[(size_t)node * 64 + c] * scc + sh;
    v = v > 0.f ? v : __expf(v) - 1.f;
    v *= W2[c];
    v += __shfl_xor(v, 1);
    v += __shfl_xor(v, 2);
    v += __shfl_xor(v, 4);
    v += __shfl_xor(v, 8);
    v += __shfl_xor(v, 16);
    v += __shfl_xor(v, 32);
    if (c == 0) out[node] = 5.0f * tanhf(v + b2[0]);
}

// ---------------- launch ----------------

extern "C" void kernel_launch(void* const* d_in, const int* in_sizes, int n_in,
                              void* d_out, int out_size, void* d_ws, size_t ws_size,
                              hipStream_t stream) {
    const float* x0    = (const float*)d_in[0];
    const int*   eidx  = (const int*)d_in[1];
    const float* eattr = (const float*)d_in[2];

    const float* Wl[2]; const float* bl[2]; const float* Wr[2]; const float* br[2];
    const float* We[2]; const float* att[2]; const float* g[2]; const float* be[2];
    for (int l = 0; l < 2; ++l) {
        int base = 3 + l * 9;
        Wl[l]  = (const float*)d_in[base + 0];
        bl[l]  = (const float*)d_in[base + 1];
        Wr[l]  = (const float*)d_in[base + 2];
        br[l]  = (const float*)d_in[base + 3];
        We[l]  = (const float*)d_in[base + 4];
        att[l] = (const float*)d_in[base + 5];
        // base+6 = bias: per-channel constant, cancels exactly under BatchNorm
        g[l]   = (const float*)d_in[base + 7];
        be[l]  = (const float*)d_in[base + 8];
    }
    const float* W1 = (const float*)d_in[21];
    const float* b1 = (const float*)d_in[22];
    const float* gf = (const float*)d_in[23];
    const float* bf = (const float*)d_in[24];
    const float* W2 = (const float*)d_in[25];
    const float* b2 = (const float*)d_in[26];

    const int N = in_sizes[0] / 128;
    const int E = in_sizes[1] / 2;
    const int* src = eidx;
    const int* dst = eidx + E;
    const int nbk = (N + 127) >> 7;

    // workspace (4-byte units).  Region A shared: (tea,tsd) then (h0,h1).
    float* ws = (float*)d_ws;
    size_t o = 0;
    float* regionA = ws + o; o += (size_t)2 * N * HC;         // >= E*3 units
    uint2* tea = (uint2*)regionA;
    uint*  tsd = (uint*)(regionA + (size_t)2 * E);
    float* h0  = regionA;
    float* h1  = regionA + (size_t)N * HC;
    uint2* eat_sorted = (uint2*)(ws + o); o += (size_t)E * 2;
    uint*  spre_sorted = (uint*)(ws + o);  o += (size_t)E;
    bf16*  xl  = (bf16*)(ws + o);  o += (size_t)N * 32;
    bf16*  xr  = (bf16*)(ws + o);  o += (size_t)N * 32;
    int*   row_start = (int*)(ws + o); o += (size_t)N + 1;
    int*   bcnt   = (int*)(ws + o); o += 512;
    float* stats  = ws + o; o += 6 * HC;
    int*   bstart = (int*)(ws + o); o += 513;
    int*   bcur   = (int*)(ws + o); o += 512;
    float* s0 = stats,        *q0 = stats + 64;
    float* s1 = stats + 128,  *q1 = stats + 192;
    float* sf = stats + 256,  *qf = stats + 320;

    const int ngroups4  = (N + 3) / 4;
    const int ngroups16 = (N + 15) / 16;
    const int EB = (E + 8191) / 8192;

    hipMemsetAsync(bcnt, 0, (512 + 6 * HC) * 4, stream);

    // CSR build: coarse bucket + in-LDS counting sort (shared by both layers)
    bucket_hist_k<<<EB, 512, 0, stream>>>(dst, bcnt, E, nbk);
    bucket_scan_k<<<1, 512, 0, stream>>>(bcnt, bstart, bcur, nbk, E);
    bucketA_k<<<EB, 1024, 0, stream>>>(src, dst, (const float4*)eattr, bcur, tsd, tea, E, nbk);
    bucket_sort_k<<<nbk, 256, 0, stream>>>(tsd, tea, bstart, spre_sorted, eat_sorted,
                                           row_start, N);

    // layer 0  (h0 overwrites regionA only after tsd/tea are consumed)
    lin128_k<<<512, 256, 0, stream>>>(x0, N, Wl[0], bl[0], Wr[0], br[0], xl, xr, ngroups16);
    gat_node_k<<<ngroups4, 256, 0, stream>>>(xl, xr, We[0], att[0], row_start,
                                             spre_sorted, eat_sorted, h0, N);
    bn_stats_k<<<256, 256, 0, stream>>>(h0, s0, q0, N);

    // layer 1 (input BN+ELU fused)
    lin64bn_k<<<512, 256, 0, stream>>>(h0, N, s0, q0, g[0], be[0],
                                       Wl[1], bl[1], Wr[1], br[1], xl, xr, ngroups16);
    gat_node_k<<<ngroups4, 256, 0, stream>>>(xl, xr, We[1], att[1], row_start,
                                             spre_sorted, eat_sorted, h1, N);
    bn_stats_k<<<256, 256, 0, stream>>>(h1, s1, q1, N);

    // head
    float* y = h0;  // h0 dead after lin64bn
    lin1_k<<<512, 256, 0, stream>>>(h1, N, s1, q1, g[1], be[1], W1, b1, y, sf, qf, ngroups16);
    final_k<<<(int)(((size_t)N * 64 + 255) / 256), 256, 0, stream>>>(
        y, N, sf, qf, gf, bf, W2, b2, (float*)d_out);
}

// Round 11
// 362.029 us; speedup vs baseline: 5.1563x; 1.0189x over previous
//
#include <hip/hip_runtime.h>
#include <hip/hip_bf16.h>
#include <cmath>

#define HC 64
typedef __hip_bfloat16 bf16;
typedef unsigned int uint;
typedef float v4f __attribute__((ext_vector_type(4)));

__device__ __forceinline__ uint pack_bf2(float a, float b) {
    __hip_bfloat162 h = __float22bfloat162_rn(make_float2(a, b));
    return *reinterpret_cast<uint*>(&h);
}
__device__ __forceinline__ float bfl(uint u) { return __uint_as_float(u << 16); }
__device__ __forceinline__ float bfh(uint u) { return __uint_as_float(u & 0xffff0000u); }

// ---------------- coarse bucket histogram (dst>>7), LDS-aggregated ----------------

__global__ __launch_bounds__(512) void bucket_hist_k(const int* __restrict__ dst,
                                                     int* __restrict__ bcnt, int E, int nbk) {
    __shared__ int lh[512];
    int t = threadIdx.x;
    for (int i = t; i < nbk; i += 512) lh[i] = 0;
    __syncthreads();
    int base = blockIdx.x * 8192;
#pragma unroll
    for (int k = 0; k < 16; ++k) {
        int e = base + k * 512 + t;
        if (e < E) atomicAdd(&lh[dst[e] >> 7], 1);
    }
    __syncthreads();
    for (int i = t; i < nbk; i += 512) if (lh[i]) atomicAdd(&bcnt[i], lh[i]);
}

// ---------------- scan over nbk (<=512) buckets ----------------

__global__ __launch_bounds__(512) void bucket_scan_k(const int* __restrict__ bcnt,
                                                     int* __restrict__ bstart,
                                                     int* __restrict__ bcur, int nbk, int E) {
    __shared__ int tmp[512];
    int t = threadIdx.x;
    int v = (t < nbk) ? bcnt[t] : 0;
    tmp[t] = v;
    __syncthreads();
    for (int off = 1; off < 512; off <<= 1) {
        int a = (t >= off) ? tmp[t - off] : 0;
        __syncthreads();
        tmp[t] += a;
        __syncthreads();
    }
    if (t < nbk) { int ex = tmp[t] - v; bstart[t] = ex; bcur[t] = ex; }
    if (t == 0) bstart[nbk] = E;
}

// ---------------- grouping: append 12B records into coarse bucket regions ----------------

__global__ __launch_bounds__(1024) void bucketA_k(
        const int* __restrict__ src, const int* __restrict__ dst,
        const float4* __restrict__ eattr, int* __restrict__ bcur,
        uint* __restrict__ tsd, uint2* __restrict__ tea, int E, int nbk) {
    __shared__ int lcnt[512];
    __shared__ int lbase[512];
    int t = threadIdx.x;
    for (int i = t; i < nbk; i += 1024) lcnt[i] = 0;
    __syncthreads();
    int base = blockIdx.x * 8192;
    int myb[8], mylp[8];
#pragma unroll
    for (int k = 0; k < 8; ++k) {
        int e = base + k * 1024 + t;
        if (e < E) {
            int b = dst[e] >> 7;
            myb[k] = b;
            mylp[k] = atomicAdd(&lcnt[b], 1);
        } else myb[k] = -1;
    }
    __syncthreads();
    for (int i = t; i < nbk; i += 1024) {
        int cc = lcnt[i];
        lbase[i] = cc ? atomicAdd(&bcur[i], cc) : 0;
    }
    __syncthreads();
#pragma unroll
    for (int k = 0; k < 8; ++k) {
        int e = base + k * 1024 + t;
        if (e >= E) continue;
        int pos = lbase[myb[k]] + mylp[k];
        int d = dst[e];
        tsd[pos] = (uint)src[e] | ((uint)(d & 127) << 25);
        float4 ea = eattr[e];
        tea[pos] = make_uint2(pack_bf2(ea.x, ea.y), pack_bf2(ea.z, ea.w));
    }
}

// ---------------- in-LDS counting sort per bucket -> exact CSR ----------------

__global__ __launch_bounds__(256) void bucket_sort_k(
        const uint* __restrict__ tsd, const uint2* __restrict__ tea,
        const int* __restrict__ bstart,
        uint* __restrict__ spre_sorted, uint2* __restrict__ eat_sorted,
        int* __restrict__ row_start, int n) {
    __shared__ int cnt[128], pfx[128], cur[128];
    int b = blockIdx.x, t = threadIdx.x;
    int i0 = bstart[b], i1 = bstart[b + 1];
    int node0 = b << 7;
    if (t < 128) cnt[t] = 0;
    __syncthreads();
    for (int i = i0 + t; i < i1; i += 256) atomicAdd(&cnt[tsd[i] >> 25], 1);
    __syncthreads();
    if (t < 128) pfx[t] = cnt[t];
    __syncthreads();
    for (int off = 1; off < 128; off <<= 1) {
        int a = (t < 128 && t >= off) ? pfx[t - off] : 0;
        __syncthreads();
        if (t < 128) pfx[t] += a;
        __syncthreads();
    }
    if (t < 128) {
        int ex = pfx[t] - cnt[t];
        cur[t] = ex;
        if (node0 + t <= n) row_start[node0 + t] = i0 + ex;
    }
    __syncthreads();
    for (int i = i0 + t; i < i1; i += 256) {
        uint u = tsd[i];
        int dl = (int)(u >> 25);
        int pos = i0 + atomicAdd(&cur[dl], 1);
        spre_sorted[pos] = (u & 0x1FFFFFFu) << 7;   // byte offset into xl rows
        eat_sorted[pos] = tea[i];
    }
}

// ---------------- layer-0 linear: din=128, bf16-packed W in LDS (40 KB) ----------------

__global__ __launch_bounds__(256) void lin128_k(
        const float* __restrict__ x, int n,
        const float* __restrict__ Wl, const float* __restrict__ bl,
        const float* __restrict__ Wr, const float* __restrict__ br,
        bf16* __restrict__ xl, bf16* __restrict__ xr, int ngroups16) {
    __shared__ uint sWl2[64 * 64];   // [k2][c] = bf16(W[2k2][c]) | bf16(W[2k2+1][c])<<16
    __shared__ uint sWr2[64 * 64];
    __shared__ float sx[16 * 128];
    int t = threadIdx.x;
    for (int i = t; i < 64 * 64; i += 256) {
        int k2 = i >> 6, c = i & 63;
        sWl2[i] = pack_bf2(Wl[(2 * k2) * 64 + c], Wl[(2 * k2 + 1) * 64 + c]);
        sWr2[i] = pack_bf2(Wr[(2 * k2) * 64 + c], Wr[(2 * k2 + 1) * 64 + c]);
    }
    int c = t & 63, w = t >> 6;
    float blc = bl[c], brc = br[c];
    for (int gidx = blockIdx.x; gidx < ngroups16; gidx += gridDim.x) {
        int node0 = gidx * 16;
        __syncthreads();
        for (int i = t; i < 16 * 128; i += 256) {
            int r = node0 + (i >> 7);
            sx[i] = (r < n) ? x[(size_t)r * 128 + (i & 127)] : 0.f;
        }
        __syncthreads();
        float al0 = blc, al1 = blc, al2 = blc, al3 = blc;
        float ar0 = brc, ar1 = brc, ar2 = brc, ar3 = brc;
        const float* sx0 = sx + w * 4 * 128;
#pragma unroll 8
        for (int k2 = 0; k2 < 64; ++k2) {
            uint wlu = sWl2[k2 * 64 + c], wru = sWr2[k2 * 64 + c];
            float wlx = bfl(wlu), wly = bfh(wlu);
            float wrx = bfl(wru), wry = bfh(wru);
            float2 xa = *(const float2*)&sx0[k2 * 2];
            float2 xb = *(const float2*)&sx0[128 + k2 * 2];
            float2 xc = *(const float2*)&sx0[256 + k2 * 2];
            float2 xd = *(const float2*)&sx0[384 + k2 * 2];
            al0 = fmaf(xa.x, wlx, al0); al0 = fmaf(xa.y, wly, al0);
            ar0 = fmaf(xa.x, wrx, ar0); ar0 = fmaf(xa.y, wry, ar0);
            al1 = fmaf(xb.x, wlx, al1); al1 = fmaf(xb.y, wly, al1);
            ar1 = fmaf(xb.x, wrx, ar1); ar1 = fmaf(xb.y, wry, ar1);
            al2 = fmaf(xc.x, wlx, al2); al2 = fmaf(xc.y, wly, al2);
            ar2 = fmaf(xc.x, wrx, ar2); ar2 = fmaf(xc.y, wry, ar2);
            al3 = fmaf(xd.x, wlx, al3); al3 = fmaf(xd.y, wly, al3);
            ar3 = fmaf(xd.x, wrx, ar3); ar3 = fmaf(xd.y, wry, ar3);
        }
        int nb_ = node0 + w * 4;
        if (nb_ + 0 < n) { xl[(size_t)(nb_ + 0) * 64 + c] = __float2bfloat16(al0); xr[(size_t)(nb_ + 0) * 64 + c] = __float2bfloat16(ar0); }
        if (nb_ + 1 < n) { xl[(size_t)(nb_ + 1) * 64 + c] = __float2bfloat16(al1); xr[(size_t)(nb_ + 1) * 64 + c] = __float2bfloat16(ar1); }
        if (nb_ + 2 < n) { xl[(size_t)(nb_ + 2) * 64 + c] = __float2bfloat16(al2); xr[(size_t)(nb_ + 2) * 64 + c] = __float2bfloat16(ar2); }
        if (nb_ + 3 < n) { xl[(size_t)(nb_ + 3) * 64 + c] = __float2bfloat16(al3); xr[(size_t)(nb_ + 3) * 64 + c] = __float2bfloat16(ar3); }
    }
}

// ---------------- layer-1 linear: din=64, fused input BN+ELU, bf16-packed W ----------------

__global__ __launch_bounds__(256) void lin64bn_k(
        const float* __restrict__ x, int n,
        const float* __restrict__ sums, const float* __restrict__ sqs,
        const float* __restrict__ g, const float* __restrict__ be,
        const float* __restrict__ Wl, const float* __restrict__ bl,
        const float* __restrict__ Wr, const float* __restrict__ br,
        bf16* __restrict__ xl, bf16* __restrict__ xr, int ngroups16) {
    __shared__ uint sWl2[32 * 64];
    __shared__ uint sWr2[32 * 64];
    __shared__ float sx[16 * 64];
    __shared__ float ssc[64], ssh[64];
    int t = threadIdx.x;
    if (t < 64) {
        float inv_n = 1.f / n;
        float mu = sums[t] * inv_n;
        float var = sqs[t] * inv_n - mu * mu;
        float sc = rsqrtf(var + 1e-5f) * g[t];
        ssc[t] = sc; ssh[t] = be[t] - mu * sc;
    }
    for (int i = t; i < 32 * 64; i += 256) {
        int k2 = i >> 6, c = i & 63;
        sWl2[i] = pack_bf2(Wl[(2 * k2) * 64 + c], Wl[(2 * k2 + 1) * 64 + c]);
        sWr2[i] = pack_bf2(Wr[(2 * k2) * 64 + c], Wr[(2 * k2 + 1) * 64 + c]);
    }
    int c = t & 63, w = t >> 6;
    float blc = bl[c], brc = br[c];
    for (int gidx = blockIdx.x; gidx < ngroups16; gidx += gridDim.x) {
        int node0 = gidx * 16;
        __syncthreads();
        for (int i = t; i < 16 * 64; i += 256) {
            int r = node0 + (i >> 6);
            float v = (r < n) ? x[(size_t)r * 64 + (i & 63)] : 0.f;
            v = v * ssc[i & 63] + ssh[i & 63];
            sx[i] = v > 0.f ? v : __expf(v) - 1.f;
        }
        __syncthreads();
        float al0 = blc, al1 = blc, al2 = blc, al3 = blc;
        float ar0 = brc, ar1 = brc, ar2 = brc, ar3 = brc;
        const float* sx0 = sx + w * 4 * 64;
#pragma unroll 8
        for (int k2 = 0; k2 < 32; ++k2) {
            uint wlu = sWl2[k2 * 64 + c], wru = sWr2[k2 * 64 + c];
            float wlx = bfl(wlu), wly = bfh(wlu);
            float wrx = bfl(wru), wry = bfh(wru);
            float2 xa = *(const float2*)&sx0[k2 * 2];
            float2 xb = *(const float2*)&sx0[64 + k2 * 2];
            float2 xc = *(const float2*)&sx0[128 + k2 * 2];
            float2 xd = *(const float2*)&sx0[192 + k2 * 2];
            al0 = fmaf(xa.x, wlx, al0); al0 = fmaf(xa.y, wly, al0);
            ar0 = fmaf(xa.x, wrx, ar0); ar0 = fmaf(xa.y, wry, ar0);
            al1 = fmaf(xb.x, wlx, al1); al1 = fmaf(xb.y, wly, al1);
            ar1 = fmaf(xb.x, wrx, ar1); ar1 = fmaf(xb.y, wry, ar1);
            al2 = fmaf(xc.x, wlx, al2); al2 = fmaf(xc.y, wly, al2);
            ar2 = fmaf(xc.x, wrx, ar2); ar2 = fmaf(xc.y, wry, ar2);
            al3 = fmaf(xd.x, wlx, al3); al3 = fmaf(xd.y, wly, al3);
            ar3 = fmaf(xd.x, wrx, ar3); ar3 = fmaf(xd.y, wry, ar3);
        }
        int nb_ = node0 + w * 4;
        if (nb_ + 0 < n) { xl[(size_t)(nb_ + 0) * 64 + c] = __float2bfloat16(al0); xr[(size_t)(nb_ + 0) * 64 + c] = __float2bfloat16(ar0); }
        if (nb_ + 1 < n) { xl[(size_t)(nb_ + 1) * 64 + c] = __float2bfloat16(al1); xr[(size_t)(nb_ + 1) * 64 + c] = __float2bfloat16(ar1); }
        if (nb_ + 2 < n) { xl[(size_t)(nb_ + 2) * 64 + c] = __float2bfloat16(al2); xr[(size_t)(nb_ + 2) * 64 + c] = __float2bfloat16(ar2); }
        if (nb_ + 3 < n) { xl[(size_t)(nb_ + 3) * 64 + c] = __float2bfloat16(al3); xr[(size_t)(nb_ + 3) * 64 + c] = __float2bfloat16(ar3); }
    }
}

// ---------------- fused GAT: wave per node, 4 ch/lane, 4 edges/wave, 4-deep MLP ----------------

__global__ __launch_bounds__(256) void gat_node_k(
        const bf16* __restrict__ xl, const bf16* __restrict__ xr,
        const float* __restrict__ We, const float* __restrict__ att,
        const int* __restrict__ row_start, const uint* __restrict__ spre,
        const uint2* __restrict__ eat,
        float* __restrict__ out, int n) {
    int t = threadIdx.x;
    int lane = t & 63;
    int quad = lane >> 4;          // edge slot 0..3
    int c4 = lane & 15;            // channel group: channels 4*c4 .. 4*c4+3
    int node = blockIdx.x * 4 + (t >> 6);
    if (node >= n) return;
    int c0 = c4 << 2;
    v4f w0 = {We[c0], We[c0 + 1], We[c0 + 2], We[c0 + 3]};
    v4f w1 = {We[64 + c0], We[64 + c0 + 1], We[64 + c0 + 2], We[64 + c0 + 3]};
    v4f w2 = {We[128 + c0], We[128 + c0 + 1], We[128 + c0 + 2], We[128 + c0 + 3]};
    v4f w3 = {We[192 + c0], We[192 + c0 + 1], We[192 + c0 + 2], We[192 + c0 + 3]};
    v4f ratt = {att[c0] * 1.44269504f, att[c0 + 1] * 1.44269504f,
                att[c0 + 2] * 1.44269504f, att[c0 + 3] * 1.44269504f};
    const char* xlb = (const char*)xl;
    uint2 xru = *(const uint2*)((const char*)xr + ((size_t)node << 7) + ((uint)c0 << 1));
    v4f xrd = {bfl(xru.x), bfh(xru.x), bfl(xru.y), bfh(xru.y)};
    int rs = row_start[node], re = row_start[node + 1];
    v4f acc = {0.f, 0.f, 0.f, 0.f};
    float srun = 0.f;
    uint coff = (uint)c4 << 3;   // 4 channels * 2B

#define PROC(EA, XU) { \
        v4f xv = {bfl((XU).x), bfh((XU).x), bfl((XU).y), bfh((XU).y)}; \
        v4f z = xv + xrd; \
        float e0 = bfl((EA).x), e1 = bfh((EA).x); \
        float e2 = bfl((EA).y), e3 = bfh((EA).y); \
        z += e0 * w0; z += e1 * w1; z += e2 * w2; z += e3 * w3; \
        z = __builtin_elementwise_max(z, 0.2f * z); \
        v4f zr = z * ratt; \
        float v = (zr.x + zr.y) + (zr.z + zr.w); \
        v += __shfl_xor(v, 1); v += __shfl_xor(v, 2); \
        float p = exp2f(v); \
        srun += p; \
        acc += p * xv; \
    }

    int i = rs;
    for (; i + 16 <= re; i += 16) {
        uint sp0 = spre[i + quad],      sp1 = spre[i + 4 + quad];
        uint sp2 = spre[i + 8 + quad],  sp3 = spre[i + 12 + quad];
        uint2 ea0 = eat[i + quad],      ea1 = eat[i + 4 + quad];
        uint2 ea2 = eat[i + 8 + quad],  ea3 = eat[i + 12 + quad];
        uint2 xu0 = *(const uint2*)(xlb + sp0 + coff);
        uint2 xu1 = *(const uint2*)(xlb + sp1 + coff);
        uint2 xu2 = *(const uint2*)(xlb + sp2 + coff);
        uint2 xu3 = *(const uint2*)(xlb + sp3 + coff);
        PROC(ea0, xu0);
        PROC(ea1, xu1);
        PROC(ea2, xu2);
        PROC(ea3, xu3);
    }
    for (; i + 8 <= re; i += 8) {
        uint spA = spre[i + quad], spB = spre[i + 4 + quad];
        uint2 eaA = eat[i + quad], eaB = eat[i + 4 + quad];
        uint2 xuA = *(const uint2*)(xlb + spA + coff);
        uint2 xuB = *(const uint2*)(xlb + spB + coff);
        PROC(eaA, xuA);
        PROC(eaB, xuB);
    }
    for (; i < re; i += 4) {
        int ei = i + quad;
        bool ok = ei < re;
        int eic = ok ? ei : i;
        uint sp = spre[eic];
        uint2 ea = eat[eic];
        uint2 xu = *(const uint2*)(xlb + sp + coff);
        v4f xv = {bfl(xu.x), bfh(xu.x), bfl(xu.y), bfh(xu.y)};
        v4f z = xv + xrd;
        float e0 = bfl(ea.x), e1 = bfh(ea.x);
        float e2 = bfl(ea.y), e3 = bfh(ea.y);
        z += e0 * w0; z += e1 * w1; z += e2 * w2; z += e3 * w3;
        z = __builtin_elementwise_max(z, 0.2f * z);
        v4f zr = z * ratt;
        float v = (zr.x + zr.y) + (zr.z + zr.w);
        v += __shfl_xor(v, 1); v += __shfl_xor(v, 2);
        float p = ok ? exp2f(v) : 0.f;
        srun += p;
        acc += p * xv;
    }
#undef PROC

    // merge the 4 quads
    srun += __shfl_xor(srun, 16);  srun += __shfl_xor(srun, 32);
    acc.x += __shfl_xor(acc.x, 16); acc.x += __shfl_xor(acc.x, 32);
    acc.y += __shfl_xor(acc.y, 16); acc.y += __shfl_xor(acc.y, 32);
    acc.z += __shfl_xor(acc.z, 16); acc.z += __shfl_xor(acc.z, 32);
    acc.w += __shfl_xor(acc.w, 16); acc.w += __shfl_xor(acc.w, 32);
    if (quad == 0) {
        float inv = 1.f / (srun + 1e-16f);
        v4f o = acc * inv;
        *(v4f*)&out[((size_t)node << 6) + (uint)c0] = o;
    }
}

// ---------------- BN stats ----------------

__global__ void bn_stats_k(const float* __restrict__ x, float* __restrict__ sums,
                           float* __restrict__ sqs, int n) {
    __shared__ float ls[256], lq[256];
    int t = threadIdx.x;
    int c = t & 63, sub = t >> 6;
    float s = 0.f, q = 0.f;
    for (int r = blockIdx.x * 4 + sub; r < n; r += gridDim.x * 4) {
        float v = x[(size_t)r * 64 + c];
        s += v;
        q = fmaf(v, v, q);
    }
    ls[t] = s; lq[t] = q;
    __syncthreads();
    if (t < 128) { ls[t] += ls[t + 128]; lq[t] += lq[t + 128]; }
    __syncthreads();
    if (t < 64) {
        atomicAdd(&sums[c], ls[t] + ls[t + 64]);
        atomicAdd(&sqs[c], lq[t] + lq[t + 64]);
    }
}

// ---------------- head fc 64->64 (fused input BN+ELU, fused output stats) ----------------

__global__ __launch_bounds__(256) void lin1_k(
        const float* __restrict__ x, int n,
        const float* __restrict__ sums, const float* __restrict__ sqs,
        const float* __restrict__ g, const float* __restrict__ be,
        const float* __restrict__ W, const float* __restrict__ b,
        float* __restrict__ y, float* __restrict__ sums_o, float* __restrict__ sqs_o,
        int ngroups16) {
    __shared__ uint sW2[32 * 64];
    __shared__ float sx[16 * 64];
    __shared__ float ssc[64], ssh[64];
    __shared__ float ls[256], lq[256];
    int t = threadIdx.x;
    if (t < 64) {
        float inv_n = 1.f / n;
        float mu = sums[t] * inv_n;
        float var = sqs[t] * inv_n - mu * mu;
        float sc = rsqrtf(var + 1e-5f) * g[t];
        ssc[t] = sc; ssh[t] = be[t] - mu * sc;
    }
    for (int i = t; i < 32 * 64; i += 256) {
        int k2 = i >> 6, c = i & 63;
        sW2[i] = pack_bf2(W[(2 * k2) * 64 + c], W[(2 * k2 + 1) * 64 + c]);
    }
    int c = t & 63, w = t >> 6;
    float bc = b[c];
    float s = 0.f, q = 0.f;
    for (int gidx = blockIdx.x; gidx < ngroups16; gidx += gridDim.x) {
        int node0 = gidx * 16;
        __syncthreads();
        for (int i = t; i < 16 * 64; i += 256) {
            int r = node0 + (i >> 6);
            float v = (r < n) ? x[(size_t)r * 64 + (i & 63)] : 0.f;
            v = v * ssc[i & 63] + ssh[i & 63];
            sx[i] = v > 0.f ? v : __expf(v) - 1.f;
        }
        __syncthreads();
        float a0 = bc, a1 = bc, a2 = bc, a3 = bc;
        const float* sx0 = sx + w * 4 * 64;
#pragma unroll 8
        for (int k2 = 0; k2 < 32; ++k2) {
            uint wu = sW2[k2 * 64 + c];
            float wx = bfl(wu), wy = bfh(wu);
            float2 xa = *(const float2*)&sx0[k2 * 2];
            float2 xb = *(const float2*)&sx0[64 + k2 * 2];
            float2 xc = *(const float2*)&sx0[128 + k2 * 2];
            float2 xd = *(const float2*)&sx0[192 + k2 * 2];
            a0 = fmaf(xa.x, wx, a0); a0 = fmaf(xa.y, wy, a0);
            a1 = fmaf(xb.x, wx, a1); a1 = fmaf(xb.y, wy, a1);
            a2 = fmaf(xc.x, wx, a2); a2 = fmaf(xc.y, wy, a2);
            a3 = fmaf(xd.x, wx, a3); a3 = fmaf(xd.y, wy, a3);
        }
        int nb_ = node0 + w * 4;
        if (nb_ + 0 < n) { y[(size_t)(nb_ + 0) * 64 + c] = a0; s += a0; q = fmaf(a0, a0, q); }
        if (nb_ + 1 < n) { y[(size_t)(nb_ + 1) * 64 + c] = a1; s += a1; q = fmaf(a1, a1, q); }
        if (nb_ + 2 < n) { y[(size_t)(nb_ + 2) * 64 + c] = a2; s += a2; q = fmaf(a2, a2, q); }
        if (nb_ + 3 < n) { y[(size_t)(nb_ + 3) * 64 + c] = a3; s += a3; q = fmaf(a3, a3, q); }
    }
    __syncthreads();
    ls[t] = s; lq[t] = q;
    __syncthreads();
    if (t < 64) {
        float ss = ls[t] + ls[t + 64] + ls[t + 128] + ls[t + 192];
        float qq = lq[t] + lq[t + 64] + lq[t + 128] + lq[t + 192];
        atomicAdd(&sums_o[t], ss);
        atomicAdd(&sqs_o[t], qq);
    }
}

// ---------------- final: fused BN+ELU + dot(64) + 5*tanh ----------------

__global__ void final_k(const float* __restrict__ z, int n,
                        const float* __restrict__ sums, const float* __restrict__ sqs,
                        const float* __restrict__ g, const float* __restrict__ be,
                        const float* __restrict__ W2, const float* __restrict__ b2,
                        float* __restrict__ out) {
    int t = blockIdx.x * blockDim.x + threadIdx.x;
    int node = t >> 6, c = t & 63;
    if (node >= n) return;
    float inv_n = 1.f / n;
    float mu = sums[c] * inv_n;
    float var = sqs[c] * inv_n - mu * mu;
    float scc = rsqrtf(var + 1e-5f) * g[c];
    float sh = be[c] - mu * scc;
    float v = z[(size_t)node * 64 + c] * scc + sh;
    v = v > 0.f ? v : __expf(v) - 1.f;
    v *= W2[c];
    v += __shfl_xor(v, 1);
    v += __shfl_xor(v, 2);
    v += __shfl_xor(v, 4);
    v += __shfl_xor(v, 8);
    v += __shfl_xor(v, 16);
    v += __shfl_xor(v, 32);
    if (c == 0) out[node] = 5.0f * tanhf(v + b2[0]);
}

// ---------------- launch ----------------

extern "C" void kernel_launch(void* const* d_in, const int* in_sizes, int n_in,
                              void* d_out, int out_size, void* d_ws, size_t ws_size,
                              hipStream_t stream) {
    const float* x0    = (const float*)d_in[0];
    const int*   eidx  = (const int*)d_in[1];
    const float* eattr = (const float*)d_in[2];

    const float* Wl[2]; const float* bl[2]; const float* Wr[2]; const float* br[2];
    const float* We[2]; const float* att[2]; const float* g[2]; const float* be[2];
    for (int l = 0; l < 2; ++l) {
        int base = 3 + l * 9;
        Wl[l]  = (const float*)d_in[base + 0];
        bl[l]  = (const float*)d_in[base + 1];
        Wr[l]  = (const float*)d_in[base + 2];
        br[l]  = (const float*)d_in[base + 3];
        We[l]  = (const float*)d_in[base + 4];
        att[l] = (const float*)d_in[base + 5];
        // base+6 = bias: per-channel constant, cancels exactly under BatchNorm
        g[l]   = (const float*)d_in[base + 7];
        be[l]  = (const float*)d_in[base + 8];
    }
    const float* W1 = (const float*)d_in[21];
    const float* b1 = (const float*)d_in[22];
    const float* gf = (const float*)d_in[23];
    const float* bf = (const float*)d_in[24];
    const float* W2 = (const float*)d_in[25];
    const float* b2 = (const float*)d_in[26];

    const int N = in_sizes[0] / 128;
    const int E = in_sizes[1] / 2;
    const int* src = eidx;
    const int* dst = eidx + E;
    const int nbk = (N + 127) >> 7;

    // workspace (4-byte units).  Region A shared: (tea,tsd) then (h0,h1).
    float* ws = (float*)d_ws;
    size_t o = 0;
    float* regionA = ws + o; o += (size_t)2 * N * HC;         // >= E*3 units
    uint2* tea = (uint2*)regionA;
    uint*  tsd = (uint*)(regionA + (size_t)2 * E);
    float* h0  = regionA;
    float* h1  = regionA + (size_t)N * HC;
    uint2* eat_sorted = (uint2*)(ws + o); o += (size_t)E * 2;
    uint*  spre_sorted = (uint*)(ws + o);  o += (size_t)E;
    bf16*  xl  = (bf16*)(ws + o);  o += (size_t)N * 32;
    bf16*  xr  = (bf16*)(ws + o);  o += (size_t)N * 32;
    int*   row_start = (int*)(ws + o); o += (size_t)N + 1;
    int*   bcnt   = (int*)(ws + o); o += 512;
    float* stats  = ws + o; o += 6 * HC;
    int*   bstart = (int*)(ws + o); o += 513;
    int*   bcur   = (int*)(ws + o); o += 512;
    float* s0 = stats,        *q0 = stats + 64;
    float* s1 = stats + 128,  *q1 = stats + 192;
    float* sf = stats + 256,  *qf = stats + 320;

    const int ngroups4  = (N + 3) / 4;
    const int ngroups16 = (N + 15) / 16;
    const int EB = (E + 8191) / 8192;
    const int lin_grid = ngroups16 < 1024 ? ngroups16 : 1024;

    hipMemsetAsync(bcnt, 0, (512 + 6 * HC) * 4, stream);

    // CSR build: coarse bucket + in-LDS counting sort (shared by both layers)
    bucket_hist_k<<<EB, 512, 0, stream>>>(dst, bcnt, E, nbk);
    bucket_scan_k<<<1, 512, 0, stream>>>(bcnt, bstart, bcur, nbk, E);
    bucketA_k<<<EB, 1024, 0, stream>>>(src, dst, (const float4*)eattr, bcur, tsd, tea, E, nbk);
    bucket_sort_k<<<nbk, 256, 0, stream>>>(tsd, tea, bstart, spre_sorted, eat_sorted,
                                           row_start, N);

    // layer 0  (h0 overwrites regionA only after tsd/tea are consumed)
    lin128_k<<<lin_grid, 256, 0, stream>>>(x0, N, Wl[0], bl[0], Wr[0], br[0], xl, xr, ngroups16);
    gat_node_k<<<ngroups4, 256, 0, stream>>>(xl, xr, We[0], att[0], row_start,
                                             spre_sorted, eat_sorted, h0, N);
    bn_stats_k<<<256, 256, 0, stream>>>(h0, s0, q0, N);

    // layer 1 (input BN+ELU fused)
    lin64bn_k<<<lin_grid, 256, 0, stream>>>(h0, N, s0, q0, g[0], be[0],
                                            Wl[1], bl[1], Wr[1], br[1], xl, xr, ngroups16);
    gat_node_k<<<ngroups4, 256, 0, stream>>>(xl, xr, We[1], att[1], row_start,
                                             spre_sorted, eat_sorted, h1, N);
    bn_stats_k<<<256, 256, 0, stream>>>(h1, s1, q1, N);

    // head
    float* y = h0;  // h0 dead after lin64bn
    lin1_k<<<lin_grid, 256, 0, stream>>>(h1, N, s1, q1, g[1], be[1], W1, b1, y, sf, qf, ngroups16);
    final_k<<<(int)(((size_t)N * 64 + 255) / 256), 256, 0, stream>>>(
        y, N, sf, qf, gf, bf, W2, b2, (float*)d_out);
}